// Round 4
// baseline (379.601 us; speedup 1.0000x reference)
//
#include <hip/hip_runtime.h>
#include <math.h>

// Problem constants
constexpr int Bc = 4, Sc = 1024, Dc = 2048, HDc = 128, Hc = 16;
constexpr int BSc = Bc * Sc;        // 4096 token rows
constexpr int KQKc = Bc * HDc;      // 512 = batch-concat K dim for SS GEMM
#define GN_EPS 1e-3f

typedef __bf16 bf16x8 __attribute__((ext_vector_type(8)));
typedef __bf16 bf16x4 __attribute__((ext_vector_type(4)));
typedef float f32x4 __attribute__((ext_vector_type(4)));

// Workspace layout (float units)
constexpr size_t OFF_Q   = 0;                                  // bf16 [H][S][512]
constexpr size_t OFF_K   = OFF_Q + (size_t)Hc * Sc * KQKc / 2; // bf16 same
constexpr size_t OFF_VB  = OFF_K + (size_t)Hc * Sc * KQKc / 2; // bf16 [BS][D]
constexpr size_t OFF_VT  = OFF_VB + (size_t)BSc * Dc / 2;      // bf16 [BH][128][1024]
constexpr size_t OFF_A   = OFF_VT + (size_t)BSc * Dc / 2;      // bf16 [H][S][S]
constexpr size_t OFF_O   = OFF_A + (size_t)Hc * Sc * Sc / 2;   // fp32 [BS][D]
constexpr size_t OFF_CT  = OFF_O + (size_t)BSc * Dc;           // [H][S]
constexpr size_t OFF_PN  = OFF_CT + (size_t)Hc * Sc;           // [H][S]
constexpr size_t OFF_XB  = OFF_PN + (size_t)Hc * Sc;           // bf16 [BS][D]
constexpr size_t OFF_WGT = OFF_XB + (size_t)BSc * Dc / 2;      // bf16 [D][D] T
constexpr size_t OFF_WOT = OFF_WGT + (size_t)Dc * Dc / 2;      // bf16 [D][D] T
constexpr size_t OFF_SUF = OFF_WOT + (size_t)Dc * Dc / 2;      // fp32 [64][9][128]
constexpr size_t OFF_T   = OFF_SUF + (size_t)64 * 9 * HDc;     // fp32 [64][8][128]
constexpr size_t OFF_WHT = OFF_T + (size_t)64 * 8 * HDc;       // bf16 [H][128][128]
// KB2 / VB2 (bf16 casts of raw k, v) alias the A region (dead until k_ssm).
// G (bf16 [BS][D]) reuses the Q buffer (dead after k_ssm).
constexpr size_t OFF_KB2 = OFF_A;
constexpr size_t OFF_VB2 = OFF_A + (size_t)BSc * Dc / 2;

#define GLOAD_LDS16(gp, lp)                                               \
  __builtin_amdgcn_global_load_lds(                                       \
      (const __attribute__((address_space(1))) void*)(gp),                \
      (__attribute__((address_space(3))) void*)(lp), 16, 0, 0)

// Swizzled staging: lane l stages row l>>2 (4 lanes/row -> one 64B segment,
// coalesced) at k-chunk c = (l&3) ^ key(row), key(r) = (r>>1)&3. LDS layout:
// (r,c) at chunkbase + r*32 + (c^key(r))*8 elems. Fragment read (rl,kq) ->
// 16B unit rl*4 + (kq^key(rl)): all 64 distinct, 8-lane groups hit 8 distinct
// bank quads -> conflict-free ds_read_b128 AND coalesced global fetch.

// ---------------------------------------------------------------------------
// Decay tables: Dn[h,s,t] = ct[h,t] * pn[h,s]  (t<=s), computed in double.
__global__ __launch_bounds__(256) void k_tables(float* __restrict__ ct,
                                                float* __restrict__ pn) {
  int idx = blockIdx.x * 256 + threadIdx.x;   // 0 .. H*S-1
  int h = idx >> 10, t = idx & 1023;
  double gamma = 1.0 - exp2(-(double)(5 + h));
  double l2g = log2(gamma);
  double r = 1.0 / gamma;
  double rowsum = (exp2(-(double)(t + 1) * l2g) - 1.0) / (r - 1.0);
  ct[idx] = (float)(exp2((double)t * l2g) / sqrt(rowsum));
  pn[idx] = (float)exp2(-(double)t * l2g);
}

// ---------------------------------------------------------------------------
// fp32 -> bf16 cast, 8 elems/thread; grid.y selects which tensor (fused 3x).
__global__ __launch_bounds__(256) void k_cast83(const float* __restrict__ s0,
                                                const float* __restrict__ s1,
                                                const float* __restrict__ s2,
                                                __bf16* __restrict__ d0,
                                                __bf16* __restrict__ d1,
                                                __bf16* __restrict__ d2) {
  const int y = blockIdx.y;
  const float* src = (y == 0) ? s0 : (y == 1) ? s1 : s2;
  __bf16* dst = (y == 0) ? d0 : (y == 1) ? d1 : d2;
  size_t i = ((size_t)blockIdx.x * 256 + threadIdx.x) * 8;
  float4 a = *(const float4*)(src + i);
  float4 b = *(const float4*)(src + i + 4);
  bf16x8 o;
  o[0] = (__bf16)a.x; o[1] = (__bf16)a.y; o[2] = (__bf16)a.z; o[3] = (__bf16)a.w;
  o[4] = (__bf16)b.x; o[5] = (__bf16)b.y; o[6] = (__bf16)b.z; o[7] = (__bf16)b.w;
  *(bf16x8*)(dst + i) = o;
}

// ---------------------------------------------------------------------------
// Transpose-cast: dst[n][k] = (bf16) src[k][n], 2048x2048. 32x32 LDS tile.
__global__ __launch_bounds__(256) void k_castT(const float* __restrict__ src,
                                               __bf16* __restrict__ dst) {
  __shared__ float t[32][33];
  const int bx = blockIdx.x, by = blockIdx.y;
  const int tid = threadIdx.x;
  const int lx = tid & 31, ly = tid >> 5;   // 32 x 8
  #pragma unroll
  for (int r = 0; r < 32; r += 8)
    t[ly + r][lx] = src[(size_t)(by * 32 + ly + r) * Dc + bx * 32 + lx];
  __syncthreads();
  #pragma unroll
  for (int r = 0; r < 32; r += 8)
    dst[(size_t)(bx * 32 + ly + r) * Dc + by * 32 + lx] = (__bf16)t[lx][ly + r];
}

// ---------------------------------------------------------------------------
// Per-head transpose-cast of Wh: WhT[h][e][d] = (bf16) Wh[h][d][e].
__global__ __launch_bounds__(256) void k_whT(const float* __restrict__ Wh,
                                             __bf16* __restrict__ WhT) {
  __shared__ float t[32][33];
  const int h = blockIdx.z;
  const int d0 = blockIdx.x * 32, e0 = blockIdx.y * 32;
  const int tid = threadIdx.x;
  const int lx = tid & 31, ly = tid >> 5;
  #pragma unroll
  for (int r = 0; r < 32; r += 8)
    t[ly + r][lx] = Wh[(size_t)h * HDc * HDc + (d0 + ly + r) * HDc + e0 + lx];
  __syncthreads();
  #pragma unroll
  for (int r = 0; r < 32; r += 8)
    WhT[(size_t)h * HDc * HDc + (e0 + ly + r) * HDc + d0 + lx] =
        (__bf16)t[lx][ly + r];
}

// ---------------------------------------------------------------------------
// MFMA projections: per head, C = Xin[:, h-slice] @ WhT[h]^T (K=128).
// z=0: Xb -> Q layout [h][s][b*HD]; z=1: Kb2 -> K layout; z=2: Vb2 -> Vp [BS][D].
// 8 waves, tile 128x128, wave tile 64x32, BK=32 (4 iters). Swizzled staging.
__global__ __launch_bounds__(512) void k_projm(const __bf16* __restrict__ Xb,
                                               const __bf16* __restrict__ Kb2,
                                               const __bf16* __restrict__ Vb2,
                                               const __bf16* __restrict__ WhT,
                                               __bf16* __restrict__ Qo,
                                               __bf16* __restrict__ Ko,
                                               __bf16* __restrict__ Vo) {
  const int r0 = blockIdx.x * 128;
  const int h = blockIdx.y;
  const int z = blockIdx.z;
  const __bf16* src = (z == 0) ? Xb : (z == 1) ? Kb2 : Vb2;
  __shared__ __bf16 As[128 * 32];
  __shared__ __bf16 Bs[128 * 32];
  const int tid = threadIdx.x;
  const int wave = tid >> 6, lane = tid & 63;
  const int wm = (wave >> 2) * 64, wn = (wave & 3) * 32;
  const int grow = wave * 16 + (lane >> 2);
  const int gkb = ((lane & 3) ^ ((lane >> 3) & 3)) * 8;
  const int rl = lane & 15, kq = lane >> 4;
  const int sw8 = (kq ^ ((rl >> 1) & 3)) * 8;
  const int cha = wm >> 4, chb = wn >> 4;
  const __bf16* wb = WhT + (size_t)h * HDc * HDc;
  f32x4 acc[4][2] = {{}};
  for (int k0 = 0; k0 < HDc; k0 += 32) {
    GLOAD_LDS16(src + (size_t)(r0 + grow) * Dc + h * HDc + k0 + gkb,
                As + wave * 512);
    GLOAD_LDS16(wb + (size_t)grow * HDc + k0 + gkb, Bs + wave * 512);
    __syncthreads();
    bf16x8 a[4], b[2];
    #pragma unroll
    for (int i = 0; i < 4; ++i)
      a[i] = *(const bf16x8*)&As[(cha + i) * 512 + rl * 32 + sw8];
    #pragma unroll
    for (int j = 0; j < 2; ++j)
      b[j] = *(const bf16x8*)&Bs[(chb + j) * 512 + rl * 32 + sw8];
    #pragma unroll
    for (int i = 0; i < 4; ++i)
      #pragma unroll
      for (int j = 0; j < 2; ++j)
        acc[i][j] = __builtin_amdgcn_mfma_f32_16x16x32_bf16(a[i], b[j],
                                                            acc[i][j], 0, 0, 0);
    __syncthreads();
  }
  #pragma unroll
  for (int i = 0; i < 4; ++i) {
    #pragma unroll
    for (int j = 0; j < 2; ++j) {
      const int col = wn + j * 16 + rl;
      #pragma unroll
      for (int r = 0; r < 4; ++r) {
        const int row = r0 + wm + i * 16 + kq * 4 + r;
        const __bf16 v = (__bf16)acc[i][j][r];
        if (z == 2) {
          Vo[(size_t)row * Dc + h * HDc + col] = v;
        } else {
          const int s = row & 1023, bb = row >> 10;
          __bf16* dst = (z == 0) ? Qo : Ko;
          dst[((size_t)(h * Sc + s) * Bc + bb) * HDc + col] = v;
        }
      }
    }
  }
}

// ---------------------------------------------------------------------------
// Transpose-cast V: VB[b][t][h*128+e] -> Vt[(b*16+h)][e][t]  (bf16 -> bf16)
__global__ __launch_bounds__(256) void k_vt(const __bf16* __restrict__ VB,
                                            __bf16* __restrict__ Vt) {
  __shared__ float tl[32][33];
  const int bh = blockIdx.z, bb = bh >> 4, h = bh & 15;
  const int t0 = blockIdx.x * 32, e0 = blockIdx.y * 32;
  const int tid = threadIdx.x;
  const int lx = tid & 31, ly = tid >> 5;
  #pragma unroll
  for (int r = 0; r < 32; r += 8)
    tl[ly + r][lx] =
        (float)VB[(size_t)(bb * Sc + t0 + ly + r) * Dc + h * HDc + e0 + lx];
  __syncthreads();
  #pragma unroll
  for (int r = 0; r < 32; r += 8)
    Vt[((size_t)bh * HDc + e0 + ly + r) * Sc + t0 + lx] = (__bf16)tl[lx][ly + r];
}

// ---------------------------------------------------------------------------
// Stage 1: per-(bh, 128-tile) partial sums of V along t.
__global__ __launch_bounds__(256) void k_vsum(const __bf16* __restrict__ VB,
                                              float* __restrict__ T) {
  const int jj = blockIdx.x, bh = blockIdx.y;
  const int bb = bh >> 4, h = bh & 15;
  const int tid = threadIdx.x;
  const int tp = tid >> 7, e = tid & 127;
  const __bf16* base =
      VB + (size_t)(bb * Sc + jj * 128 + tp * 64) * Dc + h * HDc + e;
  float a0 = 0.f, a1 = 0.f, a2 = 0.f, a3 = 0.f;
  float a4 = 0.f, a5 = 0.f, a6 = 0.f, a7 = 0.f;
  for (int t = 0; t < 64; t += 8) {
    a0 += (float)base[(size_t)(t + 0) * Dc];
    a1 += (float)base[(size_t)(t + 1) * Dc];
    a2 += (float)base[(size_t)(t + 2) * Dc];
    a3 += (float)base[(size_t)(t + 3) * Dc];
    a4 += (float)base[(size_t)(t + 4) * Dc];
    a5 += (float)base[(size_t)(t + 5) * Dc];
    a6 += (float)base[(size_t)(t + 6) * Dc];
    a7 += (float)base[(size_t)(t + 7) * Dc];
  }
  const float s = ((a0 + a1) + (a2 + a3)) + ((a4 + a5) + (a6 + a7));
  __shared__ float red[2][128];
  red[tp][e] = s;
  __syncthreads();
  if (tp == 0)
    T[((size_t)bh * 8 + jj) * HDc + e] = red[0][e] + red[1][e];
}

// ---------------------------------------------------------------------------
// Stage 2: suffix-scan tiles -> SufV[bh][j][e] = sum_{t >= 128*j} V[b,t,h,e].
__global__ __launch_bounds__(128) void k_vscan(const float* __restrict__ T,
                                               float* __restrict__ SufV) {
  const int bh = blockIdx.x;
  const int e = threadIdx.x;
  float acc = 0.f;
  SufV[((size_t)bh * 9 + 8) * HDc + e] = 0.f;
  for (int jj = 7; jj >= 1; --jj) {
    acc += T[((size_t)bh * 8 + jj) * HDc + e];
    SufV[((size_t)bh * 9 + jj) * HDc + e] = acc;
  }
}

// ---------------------------------------------------------------------------
// SS via MFMA: per head, A[h][s][t] = clamp(|ct[t]*pn[s]*(Q·K^T)/sqrt(128)|,1)
// for t<=s (upper tiles skipped; never read). 128x128 tiles, K=512, 8 waves.
// Swizzled conflict-free + coalesced staging.
__global__ __launch_bounds__(512) void k_ssm(const __bf16* __restrict__ Q,
                                             const __bf16* __restrict__ Kb,
                                             const float* __restrict__ ct,
                                             const float* __restrict__ pn,
                                             __bf16* __restrict__ A) {
  const int bx = blockIdx.x, by = blockIdx.y;
  if (bx > by) return;               // strictly-upper tile: skip entirely
  const int h = blockIdx.z;
  const int t0 = bx * 128, s0 = by * 128;
  const int tid = threadIdx.x;
  __bf16* Ah = A + (size_t)h * Sc * Sc;
  __shared__ __bf16 Qs[128 * 32];
  __shared__ __bf16 Ks[128 * 32];
  const int wave = tid >> 6, lane = tid & 63;
  const int wm = (wave >> 2) * 64, wn = (wave & 3) * 32;
  const int grow = wave * 16 + (lane >> 2);
  const int gkb = ((lane & 3) ^ ((lane >> 3) & 3)) * 8;
  const int rl = lane & 15, kq = lane >> 4;
  const int sw8 = (kq ^ ((rl >> 1) & 3)) * 8;
  const int cha = wm >> 4, chb = wn >> 4;
  f32x4 acc[4][2] = {{}};
  const __bf16* qbase = Q + (size_t)(h * Sc + s0) * KQKc;
  const __bf16* kbase = Kb + (size_t)(h * Sc + t0) * KQKc;
  for (int k0 = 0; k0 < KQKc; k0 += 32) {
    GLOAD_LDS16(qbase + (size_t)grow * KQKc + k0 + gkb, Qs + wave * 512);
    GLOAD_LDS16(kbase + (size_t)grow * KQKc + k0 + gkb, Ks + wave * 512);
    __syncthreads();
    bf16x8 a[4], b[2];
    #pragma unroll
    for (int i = 0; i < 4; ++i)
      a[i] = *(const bf16x8*)&Qs[(cha + i) * 512 + rl * 32 + sw8];
    #pragma unroll
    for (int j = 0; j < 2; ++j)
      b[j] = *(const bf16x8*)&Ks[(chb + j) * 512 + rl * 32 + sw8];
    #pragma unroll
    for (int i = 0; i < 4; ++i)
      #pragma unroll
      for (int j = 0; j < 2; ++j)
        acc[i][j] = __builtin_amdgcn_mfma_f32_16x16x32_bf16(a[i], b[j],
                                                            acc[i][j], 0, 0, 0);
    __syncthreads();
  }
  const float rs = 0.088388347648318447f;  // 1/sqrt(128)
  #pragma unroll
  for (int i = 0; i < 4; ++i) {
    #pragma unroll
    for (int j = 0; j < 2; ++j) {
      const int t = t0 + wn + j * 16 + rl;
      const float ctv = ct[h * Sc + t] * rs;
      #pragma unroll
      for (int r = 0; r < 4; ++r) {
        const int s = s0 + wm + i * 16 + kq * 4 + r;
        float v = 1.0f;
        if (t <= s) v = fmaxf(fabsf(ctv * pn[h * Sc + s] * acc[i][j][r]), 1.0f);
        Ah[(size_t)s * Sc + t] = (__bf16)v;
      }
    }
  }
}

// ---------------------------------------------------------------------------
// O = A @ V via MFMA, triangular; all-ones region added as fp32 SufV.
// 8 waves, tile 128(s) x 128(e). Swizzled staging.
__global__ __launch_bounds__(512) void k_avm(const __bf16* __restrict__ A,
                                             const __bf16* __restrict__ Vt,
                                             const float* __restrict__ SufV,
                                             float* __restrict__ O) {
  const int bh = blockIdx.z, bb = bh >> 4, h = bh & 15;
  const int itile = blockIdx.x;
  const int s0 = itile * 128;
  const int tid = threadIdx.x;
  __shared__ __bf16 As[128 * 32];
  __shared__ __bf16 Bs[128 * 32];
  const int wave = tid >> 6, lane = tid & 63;
  const int wm = (wave >> 2) * 64, wn = (wave & 3) * 32;
  const int grow = wave * 16 + (lane >> 2);
  const int gkb = ((lane & 3) ^ ((lane >> 3) & 3)) * 8;
  const int rl = lane & 15, kq = lane >> 4;
  const int sw8 = (kq ^ ((rl >> 1) & 3)) * 8;
  const int cha = wm >> 4, chb = wn >> 4;
  f32x4 acc[4][2] = {{}};
  const __bf16* abase = A + (size_t)(h * Sc + s0) * Sc;
  const __bf16* vbase = Vt + (size_t)bh * HDc * Sc;
  const int kmax = (itile + 1) * 128;
  for (int k0 = 0; k0 < kmax; k0 += 32) {
    GLOAD_LDS16(abase + (size_t)grow * Sc + k0 + gkb, As + wave * 512);
    GLOAD_LDS16(vbase + (size_t)grow * Sc + k0 + gkb, Bs + wave * 512);
    __syncthreads();
    bf16x8 a[4], b[2];
    #pragma unroll
    for (int i = 0; i < 4; ++i)
      a[i] = *(const bf16x8*)&As[(cha + i) * 512 + rl * 32 + sw8];
    #pragma unroll
    for (int j = 0; j < 2; ++j)
      b[j] = *(const bf16x8*)&Bs[(chb + j) * 512 + rl * 32 + sw8];
    #pragma unroll
    for (int i = 0; i < 4; ++i)
      #pragma unroll
      for (int j = 0; j < 2; ++j)
        acc[i][j] = __builtin_amdgcn_mfma_f32_16x16x32_bf16(a[i], b[j],
                                                            acc[i][j], 0, 0, 0);
    __syncthreads();
  }
  const float* sufr = SufV + ((size_t)bh * 9 + (itile + 1)) * HDc;
  #pragma unroll
  for (int i = 0; i < 4; ++i) {
    #pragma unroll
    for (int j = 0; j < 2; ++j) {
      const int e = wn + j * 16 + rl;
      const float sv = sufr[e];
      #pragma unroll
      for (int r = 0; r < 4; ++r) {
        const int s = s0 + wm + i * 16 + kq * 4 + r;
        O[(size_t)(bb * Sc + s) * Dc + h * HDc + e] = acc[i][j][r] + sv;
      }
    }
  }
}

// ---------------------------------------------------------------------------
// Per-token GroupNorm(groups=1) over 2048 channels, in place.
__global__ __launch_bounds__(256) void k_gnorm(float* __restrict__ O,
                                               const float* __restrict__ gw,
                                               const float* __restrict__ bw) {
  const int r = blockIdx.x;
  const int tid = threadIdx.x;
  float* row = O + (size_t)r * Dc;
  const int c = tid * 4;
  float4 v0 = *(const float4*)(row + c);
  float4 v1 = *(const float4*)(row + c + 1024);
  __shared__ float red[256];
  __shared__ float sh_mu, sh_inv;
  red[tid] = v0.x + v0.y + v0.z + v0.w + v1.x + v1.y + v1.z + v1.w;
  __syncthreads();
  for (int st = 128; st > 0; st >>= 1) {
    if (tid < st) red[tid] += red[tid + st];
    __syncthreads();
  }
  if (tid == 0) sh_mu = red[0] * (1.0f / Dc);
  __syncthreads();
  const float mu = sh_mu;
  float d[8] = {v0.x - mu, v0.y - mu, v0.z - mu, v0.w - mu,
                v1.x - mu, v1.y - mu, v1.z - mu, v1.w - mu};
  float ssq = 0.f;
  #pragma unroll
  for (int i = 0; i < 8; ++i) ssq += d[i] * d[i];
  red[tid] = ssq;
  __syncthreads();
  for (int st = 128; st > 0; st >>= 1) {
    if (tid < st) red[tid] += red[tid + st];
    __syncthreads();
  }
  if (tid == 0) sh_inv = rsqrtf(red[0] * (1.0f / Dc) + GN_EPS);
  __syncthreads();
  const float inv = sh_inv;
  float4 g0 = *(const float4*)(gw + c), g1 = *(const float4*)(gw + c + 1024);
  float4 b0 = *(const float4*)(bw + c), b1 = *(const float4*)(bw + c + 1024);
  float4 o0, o1;
  o0.x = d[0] * inv * g0.x + b0.x; o0.y = d[1] * inv * g0.y + b0.y;
  o0.z = d[2] * inv * g0.z + b0.z; o0.w = d[3] * inv * g0.w + b0.w;
  o1.x = d[4] * inv * g1.x + b1.x; o1.y = d[5] * inv * g1.y + b1.y;
  o1.z = d[6] * inv * g1.z + b1.z; o1.w = d[7] * inv * g1.w + b1.w;
  *(float4*)(row + c) = o0;
  *(float4*)(row + c + 1024) = o1;
}

// ---------------------------------------------------------------------------
// bf16 MFMA GEMM, relaxed-sync pipeline, 2 WGs/CU: C = A @ Bt^T.
// M=4096, N=2048, K=2048. Tile 128x128, BK=64, 4 waves (2M x 2N), per-wave
// 64x64. Grid 16(N) x 32(M) = 512 WGs = 2/CU (LDS 80 KB each); the second
// resident WG fills this WG's barrier/vmcnt drains (m114 implicit overlap;
// m102's N=2048 collapse was 1 WG/CU).
// LDS: A triple-buffered (3 x 16KB) + B double-buffered (2 x 16KB) = 80 KiB.
// Per K-tile: issue all 16 ds_reads (a01,b01,a23,b23), stage B(t+1) (4) +
// A(t+2) (4), then 4 MFMA groups gated by compiler counted lgkmcnt. Tile
// close: lgkmcnt(0) (reads long-retired; needed before buffers are re-staged
// after the barrier), counted vmcnt(4) (B(t+1) landed, A(t+2) in flight),
// ONE s_barrier.
// mode 0: Gout = bf16(relu(acc) * Y);  mode 1: Fout = acc (fp32).
constexpr int NTK = Dc / 64;          // 32 K-tiles
constexpr int ABUFE = 128 * 64;       // elems per A buffer (16 KB)
constexpr int BBUFE = 128 * 64;       // elems per B buffer (16 KB)
constexpr int MG_LDS = (3 * ABUFE + 2 * BBUFE) * 2;  // 81920 B

__global__ __launch_bounds__(256, 2) void k_mgemm(const __bf16* __restrict__ Ab,
                                                  const __bf16* __restrict__ Bt,
                                                  const float* __restrict__ Y,
                                                  __bf16* __restrict__ Gout,
                                                  float* __restrict__ Fout,
                                                  int mode) {
  extern __shared__ __bf16 lds[];
  __bf16* As = lds;                   // 3 * ABUFE
  __bf16* Bs = lds + 3 * ABUFE;       // 2 * BBUFE
  // XCD-chunked swizzle: 512 WGs, 64 consecutive work-ids per XCD ->
  // each XCD owns 4 adjacent A-panels (4 x 0.5MB) x full B sweep.
  int wid = blockIdx.y * gridDim.x + blockIdx.x;
  wid = (wid & 7) * 64 + (wid >> 3);
  const int r0 = (wid >> 4) * 128;    // M block (32)
  const int c0 = (wid & 15) * 128;    // N block (16)
  const int tid = threadIdx.x;
  const int wave = tid >> 6, lane = tid & 63;
  const int wr = wave >> 1, wc = wave & 1;          // 2(M) x 2(N) waves
  const int lr = lane >> 2;                         // staging row in chunk
  const int lkx = ((lane & 3) ^ ((lane >> 3) & 3)) * 8;  // staging k offset
  const int rl = lane & 15, kq = lane >> 4;         // frag row / k-quarter
  const int swo = rl * 32 + ((kq ^ ((rl >> 1) & 3)) * 8);
  f32x4 acc[4][4] = {{}};

  // stage call: one 16-row x 32-k chunk per wave per instruction.
  // chunks ci = 0..15 cover 128 rows x 64 k; ci = i*4 + wave, i in 0..3.
#define STAGE_A_(i, kt, bsel) do {                                          \
    const int ci_ = (i) * 4 + wave;                                         \
    GLOAD_LDS16(Ab + (size_t)(r0 + (ci_ >> 1) * 16 + lr) * Dc               \
                    + (kt) * 64 + (ci_ & 1) * 32 + lkx,                     \
                As + (bsel) * ABUFE + ci_ * 512);                           \
  } while (0)
#define STAGE_B_(j, kt, bsel) do {                                          \
    const int ci_ = (j) * 4 + wave;                                         \
    GLOAD_LDS16(Bt + (size_t)(c0 + (ci_ >> 1) * 16 + lr) * Dc               \
                    + (kt) * 64 + (ci_ & 1) * 32 + lkx,                     \
                Bs + (bsel) * BBUFE + ci_ * 512);                           \
  } while (0)

  // Prologue: A(0), B(0), A(1) = 12 loads (B(1) staged inside tile 0).
  STAGE_A_(0, 0, 0); STAGE_A_(1, 0, 0); STAGE_A_(2, 0, 0); STAGE_A_(3, 0, 0);
  STAGE_B_(0, 0, 0); STAGE_B_(1, 0, 0); STAGE_B_(2, 0, 0); STAGE_B_(3, 0, 0);
  STAGE_A_(0, 1, 1); STAGE_A_(1, 1, 1); STAGE_A_(2, 1, 1); STAGE_A_(3, 1, 1);
  __builtin_amdgcn_sched_barrier(0);
  asm volatile("s_waitcnt vmcnt(4)" ::: "memory");  // A(0)+B(0) landed
  __builtin_amdgcn_sched_barrier(0);
  __builtin_amdgcn_s_barrier();

  int cbA = 0;                         // A buffer holding tile t
  for (int t = 0; t < NTK; ++t) {
    const int sbA = (cbA + 2 >= 3) ? cbA - 1 : cbA + 2;  // (cbA+2)%3
    const __bf16* Ac = As + cbA * ABUFE;
    const __bf16* Bc = Bs + (t & 1) * BBUFE;
    bf16x8 a[4][2], b[4][2];
    // --- issue all 16 ds_reads, order a01, b01, a23, b23 ---
    #pragma unroll
    for (int m = 0; m < 2; ++m)
      #pragma unroll
      for (int kc = 0; kc < 2; ++kc)
        a[m][kc] = *(const bf16x8*)&Ac[((wr * 4 + m) * 2 + kc) * 512 + swo];
    #pragma unroll
    for (int n = 0; n < 2; ++n)
      #pragma unroll
      for (int kc = 0; kc < 2; ++kc)
        b[n][kc] = *(const bf16x8*)&Bc[((wc * 4 + n) * 2 + kc) * 512 + swo];
    #pragma unroll
    for (int m = 2; m < 4; ++m)
      #pragma unroll
      for (int kc = 0; kc < 2; ++kc)
        a[m][kc] = *(const bf16x8*)&Ac[((wr * 4 + m) * 2 + kc) * 512 + swo];
    #pragma unroll
    for (int n = 2; n < 4; ++n)
      #pragma unroll
      for (int kc = 0; kc < 2; ++kc)
        b[n][kc] = *(const bf16x8*)&Bc[((wc * 4 + n) * 2 + kc) * 512 + swo];
    // --- issue staging: B for t+1, A for t+2 (order matters for vmcnt) ---
    if (t + 1 < NTK) {
      STAGE_B_(0, t + 1, (t + 1) & 1); STAGE_B_(1, t + 1, (t + 1) & 1);
      STAGE_B_(2, t + 1, (t + 1) & 1); STAGE_B_(3, t + 1, (t + 1) & 1);
    }
    if (t + 2 < NTK) {
      STAGE_A_(0, t + 2, sbA); STAGE_A_(1, t + 2, sbA);
      STAGE_A_(2, t + 2, sbA); STAGE_A_(3, t + 2, sbA);
    }
    __builtin_amdgcn_sched_barrier(0);
    // --- G1: m01 x n01 (compiler counted lgkmcnt gates on a01,b01) ---
    __builtin_amdgcn_s_setprio(1);
    #pragma unroll
    for (int kc = 0; kc < 2; ++kc)
      #pragma unroll
      for (int m = 0; m < 2; ++m)
        #pragma unroll
        for (int n = 0; n < 2; ++n)
          acc[m][n] = __builtin_amdgcn_mfma_f32_16x16x32_bf16(
              a[m][kc], b[n][kc], acc[m][n], 0, 0, 0);
    __builtin_amdgcn_s_setprio(0);
    __builtin_amdgcn_sched_barrier(0);
    // --- G2: m23 x n01 ---
    __builtin_amdgcn_s_setprio(1);
    #pragma unroll
    for (int kc = 0; kc < 2; ++kc)
      #pragma unroll
      for (int m = 2; m < 4; ++m)
        #pragma unroll
        for (int n = 0; n < 2; ++n)
          acc[m][n] = __builtin_amdgcn_mfma_f32_16x16x32_bf16(
              a[m][kc], b[n][kc], acc[m][n], 0, 0, 0);
    __builtin_amdgcn_s_setprio(0);
    __builtin_amdgcn_sched_barrier(0);
    // --- G3: m01 x n23 ---
    __builtin_amdgcn_s_setprio(1);
    #pragma unroll
    for (int kc = 0; kc < 2; ++kc)
      #pragma unroll
      for (int m = 0; m < 2; ++m)
        #pragma unroll
        for (int n = 2; n < 4; ++n)
          acc[m][n] = __builtin_amdgcn_mfma_f32_16x16x32_bf16(
              a[m][kc], b[n][kc], acc[m][n], 0, 0, 0);
    __builtin_amdgcn_s_setprio(0);
    __builtin_amdgcn_sched_barrier(0);
    // --- G4: m23 x n23 ---
    __builtin_amdgcn_s_setprio(1);
    #pragma unroll
    for (int kc = 0; kc < 2; ++kc)
      #pragma unroll
      for (int m = 2; m < 4; ++m)
        #pragma unroll
        for (int n = 2; n < 4; ++n)
          acc[m][n] = __builtin_amdgcn_mfma_f32_16x16x32_bf16(
              a[m][kc], b[n][kc], acc[m][n], 0, 0, 0);
    __builtin_amdgcn_s_setprio(0);
    __builtin_amdgcn_sched_barrier(0);
    // --- tile close: drain my reads (free by now), prove t+1 staged, bar ---
    asm volatile("s_waitcnt lgkmcnt(0)" ::: "memory");
    __builtin_amdgcn_sched_barrier(0);
    if (t + 2 < NTK)                   // newest 4 = SA(t+2); SB(t+1) retired
      asm volatile("s_waitcnt vmcnt(4)" ::: "memory");
    else if (t + 1 < NTK)              // tail: drain SB(t+1)
      asm volatile("s_waitcnt vmcnt(0)" ::: "memory");
    __builtin_amdgcn_sched_barrier(0);
    __builtin_amdgcn_s_barrier();
    cbA = (cbA + 1 >= 3) ? 0 : cbA + 1;
  }
#undef STAGE_A_
#undef STAGE_B_

  #pragma unroll
  for (int mi = 0; mi < 4; ++mi) {
    #pragma unroll
    for (int nj = 0; nj < 4; ++nj) {
      const int col = c0 + wc * 64 + nj * 16 + rl;
      #pragma unroll
      for (int r = 0; r < 4; ++r) {
        const int row = r0 + wr * 64 + mi * 16 + kq * 4 + r;
        const size_t idx = (size_t)row * Dc + col;
        float v = acc[mi][nj][r];
        if (mode == 0) {
          v = fmaxf(v, 0.f) * Y[idx];
          Gout[idx] = (__bf16)v;
        } else {
          Fout[idx] = v;
        }
      }
    }
  }
}

// ---------------------------------------------------------------------------
extern "C" void kernel_launch(void* const* d_in, const int* in_sizes, int n_in,
                              void* d_out, int out_size, void* d_ws, size_t ws_size,
                              hipStream_t stream) {
  const float* x  = (const float*)d_in[0];
  const float* k  = (const float*)d_in[1];
  const float* v  = (const float*)d_in[2];
  const float* Wh = (const float*)d_in[3];
  const float* wg = (const float*)d_in[4];
  const float* wo = (const float*)d_in[5];
  const float* gg = (const float*)d_in[6];
  const float* gb = (const float*)d_in[7];
  float* ws = (float*)d_ws;
  __bf16* Q   = (__bf16*)(ws + OFF_Q);
  __bf16* Kp  = (__bf16*)(ws + OFF_K);
  __bf16* VB  = (__bf16*)(ws + OFF_VB);
  __bf16* Vt  = (__bf16*)(ws + OFF_VT);
  __bf16* A   = (__bf16*)(ws + OFF_A);
  float*  O   = ws + OFF_O;
  float*  CT  = ws + OFF_CT;
  float*  PN  = ws + OFF_PN;
  __bf16* XB  = (__bf16*)(ws + OFF_XB);
  __bf16* WGT = (__bf16*)(ws + OFF_WGT);
  __bf16* WOT = (__bf16*)(ws + OFF_WOT);
  float*  SUF = ws + OFF_SUF;
  float*  TP  = ws + OFF_T;
  __bf16* WHT = (__bf16*)(ws + OFF_WHT);
  __bf16* KB2 = (__bf16*)(ws + OFF_KB2);  // aliases A (dead until k_ssm)
  __bf16* VB2 = (__bf16*)(ws + OFF_VB2);  // aliases A second half
  __bf16* G   = (__bf16*)(ws + OFF_Q);    // reuse Q region (dead after k_ssm)

  // one-time opt-in for 80 KiB dynamic LDS (host-side, graph-capture safe)
  static bool attr_done = false;
  if (!attr_done) {
    (void)hipFuncSetAttribute((const void*)k_mgemm,
                              hipFuncAttributeMaxDynamicSharedMemorySize,
                              MG_LDS);
    attr_done = true;
  }

  k_tables<<<Hc * Sc / 256, 256, 0, stream>>>(CT, PN);
  k_cast83<<<dim3((BSc * Dc) / (256 * 8), 3), 256, 0, stream>>>(
      x, k, v, XB, KB2, VB2);
  k_castT<<<dim3(Dc / 32, Dc / 32), 256, 0, stream>>>(wg, WGT);
  k_castT<<<dim3(Dc / 32, Dc / 32), 256, 0, stream>>>(wo, WOT);
  k_whT<<<dim3(4, 4, Hc), 256, 0, stream>>>(Wh, WHT);
  k_projm<<<dim3(BSc / 128, Hc, 3), 512, 0, stream>>>(XB, KB2, VB2, WHT,
                                                      Q, Kp, VB);
  k_vt<<<dim3(Sc / 32, HDc / 32, Bc * Hc), 256, 0, stream>>>(VB, Vt);
  k_vsum<<<dim3(8, Bc * Hc), 256, 0, stream>>>(VB, TP);
  k_vscan<<<Bc * Hc, 128, 0, stream>>>(TP, SUF);
  k_ssm<<<dim3(Sc / 128, Sc / 128, Hc), 512, 0, stream>>>(Q, Kp, CT, PN, A);
  k_avm<<<dim3(Sc / 128, 1, Bc * Hc), 512, 0, stream>>>(A, Vt, SUF, O);
  k_gnorm<<<BSc, 256, 0, stream>>>(O, gg, gb);
  k_mgemm<<<dim3(16, 32), 256, MG_LDS, stream>>>(XB, WGT, O, G, nullptr, 0);
  k_mgemm<<<dim3(16, 32), 256, MG_LDS, stream>>>(G, WOT, nullptr, nullptr,
                                                 (float*)d_out, 1);
}

// Round 5
// 376.092 us; speedup vs baseline: 1.0093x; 1.0093x over previous
//
#include <hip/hip_runtime.h>
#include <math.h>

// Problem constants
constexpr int Bc = 4, Sc = 1024, Dc = 2048, HDc = 128, Hc = 16;
constexpr int BSc = Bc * Sc;        // 4096 token rows
constexpr int KQKc = Bc * HDc;      // 512 = batch-concat K dim for SS GEMM
#define GN_EPS 1e-3f

typedef __bf16 bf16x8 __attribute__((ext_vector_type(8)));
typedef __bf16 bf16x4 __attribute__((ext_vector_type(4)));
typedef float f32x4 __attribute__((ext_vector_type(4)));

// Workspace layout (float units)
constexpr size_t OFF_Q   = 0;                                  // bf16 [H][S][512]
constexpr size_t OFF_K   = OFF_Q + (size_t)Hc * Sc * KQKc / 2; // bf16 same
constexpr size_t OFF_VB  = OFF_K + (size_t)Hc * Sc * KQKc / 2; // bf16 [BS][D]
constexpr size_t OFF_VT  = OFF_VB + (size_t)BSc * Dc / 2;      // bf16 [BH][128][1024]
constexpr size_t OFF_A   = OFF_VT + (size_t)BSc * Dc / 2;      // bf16 [H][S][S]
constexpr size_t OFF_O   = OFF_A + (size_t)Hc * Sc * Sc / 2;   // fp32 [BS][D]
constexpr size_t OFF_CT  = OFF_O + (size_t)BSc * Dc;           // [H][S]
constexpr size_t OFF_PN  = OFF_CT + (size_t)Hc * Sc;           // [H][S]
constexpr size_t OFF_XB  = OFF_PN + (size_t)Hc * Sc;           // bf16 [BS][D]
constexpr size_t OFF_WGT = OFF_XB + (size_t)BSc * Dc / 2;      // bf16 [D][D] T
constexpr size_t OFF_WOT = OFF_WGT + (size_t)Dc * Dc / 2;      // bf16 [D][D] T
constexpr size_t OFF_SUF = OFF_WOT + (size_t)Dc * Dc / 2;      // fp32 [64][9][128]
constexpr size_t OFF_T   = OFF_SUF + (size_t)64 * 9 * HDc;     // fp32 [64][8][128]
constexpr size_t OFF_WHT = OFF_T + (size_t)64 * 8 * HDc;       // bf16 [H][128][128]
// KB2 / VB2 (bf16 casts of raw k, v) alias the A region (dead until k_ssm).
// G (bf16 [BS][D]) reuses the Q buffer (dead after k_ssm).
constexpr size_t OFF_KB2 = OFF_A;
constexpr size_t OFF_VB2 = OFF_A + (size_t)BSc * Dc / 2;

#define GLOAD_LDS16(gp, lp)                                               \
  __builtin_amdgcn_global_load_lds(                                       \
      (const __attribute__((address_space(1))) void*)(gp),                \
      (__attribute__((address_space(3))) void*)(lp), 16, 0, 0)

// Swizzled staging: lane l stages row l>>2 (4 lanes/row -> one 64B segment,
// coalesced) at k-chunk c = (l&3) ^ key(row), key(r) = (r>>1)&3. LDS layout:
// (r,c) at chunkbase + r*32 + (c^key(r))*8 elems. Fragment read (rl,kq) ->
// 16B unit rl*4 + (kq^key(rl)): all 64 distinct, 8-lane groups hit 8 distinct
// bank quads -> conflict-free ds_read_b128 AND coalesced global fetch.

// ---------------------------------------------------------------------------
// Shared relaxed-sync 128x128 MFMA K-loop (session-verified in R3/R4).
// 256 threads, 4 waves (2M x 2N), per-wave 64x64, BK=64.
// LDS: A triple-buffered (3 x 16KB, staged 2 tiles ahead) + B double-buffered
// (2 x 16KB, staged 1 ahead) = 80 KiB -> 2 WGs/CU.
// Per K-tile: all 16 ds_reads up-front (a01,b01,a23,b23), stage B(t+1) +
// A(t+2), 4 MFMA groups gated by compiler counted lgkmcnt; close with
// lgkmcnt(0) + counted vmcnt(4) + ONE s_barrier. Requires ntk >= 2.
constexpr int ABUFE = 128 * 64;       // elems per A buffer (16 KB)
constexpr int BBUFE = 128 * 64;       // elems per B buffer (16 KB)
constexpr int MG_LDS = (3 * ABUFE + 2 * BBUFE) * 2;  // 81920 B

template <int ASTR, int BSTR>
__device__ __forceinline__ void mfma_loop128(const __bf16* __restrict__ Abase,
                                             const __bf16* __restrict__ Bbase,
                                             const int ntk,
                                             __bf16* As, __bf16* Bs,
                                             const int wave, const int lane,
                                             f32x4 acc[4][4]) {
  const int wr = wave >> 1, wc = wave & 1;          // 2(M) x 2(N) waves
  const int lr = lane >> 2;                         // staging row in chunk
  const int lkx = ((lane & 3) ^ ((lane >> 3) & 3)) * 8;  // staging k offset
  const int rl = lane & 15, kq = lane >> 4;         // frag row / k-quarter
  const int swo = rl * 32 + ((kq ^ ((rl >> 1) & 3)) * 8);

  // stage: one 16-row x 32-k chunk per wave per call; ci = i*4 + wave.
#define SA_(i, kt, bsel) do {                                               \
    const int ci_ = (i) * 4 + wave;                                         \
    GLOAD_LDS16(Abase + (size_t)((ci_ >> 1) * 16 + lr) * ASTR               \
                    + (kt) * 64 + (ci_ & 1) * 32 + lkx,                     \
                As + (bsel) * ABUFE + ci_ * 512);                           \
  } while (0)
#define SB_(j, kt, bsel) do {                                               \
    const int ci_ = (j) * 4 + wave;                                         \
    GLOAD_LDS16(Bbase + (size_t)((ci_ >> 1) * 16 + lr) * BSTR               \
                    + (kt) * 64 + (ci_ & 1) * 32 + lkx,                     \
                Bs + (bsel) * BBUFE + ci_ * 512);                           \
  } while (0)

  // Prologue: A(0), B(0), A(1) = 12 loads (B(1) staged inside tile 0).
  SA_(0, 0, 0); SA_(1, 0, 0); SA_(2, 0, 0); SA_(3, 0, 0);
  SB_(0, 0, 0); SB_(1, 0, 0); SB_(2, 0, 0); SB_(3, 0, 0);
  SA_(0, 1, 1); SA_(1, 1, 1); SA_(2, 1, 1); SA_(3, 1, 1);
  __builtin_amdgcn_sched_barrier(0);
  asm volatile("s_waitcnt vmcnt(4)" ::: "memory");  // A(0)+B(0) landed
  __builtin_amdgcn_sched_barrier(0);
  __builtin_amdgcn_s_barrier();

  int cbA = 0;                         // A buffer holding tile t
  for (int t = 0; t < ntk; ++t) {
    const int sbA = (cbA + 2 >= 3) ? cbA - 1 : cbA + 2;  // (cbA+2)%3
    const __bf16* Ac = As + cbA * ABUFE;
    const __bf16* Bc = Bs + (t & 1) * BBUFE;
    bf16x8 a[4][2], b[4][2];
    // --- issue all 16 ds_reads, order a01, b01, a23, b23 ---
    #pragma unroll
    for (int m = 0; m < 2; ++m)
      #pragma unroll
      for (int kc = 0; kc < 2; ++kc)
        a[m][kc] = *(const bf16x8*)&Ac[((wr * 4 + m) * 2 + kc) * 512 + swo];
    #pragma unroll
    for (int n = 0; n < 2; ++n)
      #pragma unroll
      for (int kc = 0; kc < 2; ++kc)
        b[n][kc] = *(const bf16x8*)&Bc[((wc * 4 + n) * 2 + kc) * 512 + swo];
    #pragma unroll
    for (int m = 2; m < 4; ++m)
      #pragma unroll
      for (int kc = 0; kc < 2; ++kc)
        a[m][kc] = *(const bf16x8*)&Ac[((wr * 4 + m) * 2 + kc) * 512 + swo];
    #pragma unroll
    for (int n = 2; n < 4; ++n)
      #pragma unroll
      for (int kc = 0; kc < 2; ++kc)
        b[n][kc] = *(const bf16x8*)&Bc[((wc * 4 + n) * 2 + kc) * 512 + swo];
    // --- issue staging: B for t+1, A for t+2 (order matters for vmcnt) ---
    if (t + 1 < ntk) {
      SB_(0, t + 1, (t + 1) & 1); SB_(1, t + 1, (t + 1) & 1);
      SB_(2, t + 1, (t + 1) & 1); SB_(3, t + 1, (t + 1) & 1);
    }
    if (t + 2 < ntk) {
      SA_(0, t + 2, sbA); SA_(1, t + 2, sbA);
      SA_(2, t + 2, sbA); SA_(3, t + 2, sbA);
    }
    __builtin_amdgcn_sched_barrier(0);
    // --- G1: m01 x n01 (compiler counted lgkmcnt gates on a01,b01) ---
    __builtin_amdgcn_s_setprio(1);
    #pragma unroll
    for (int kc = 0; kc < 2; ++kc)
      #pragma unroll
      for (int m = 0; m < 2; ++m)
        #pragma unroll
        for (int n = 0; n < 2; ++n)
          acc[m][n] = __builtin_amdgcn_mfma_f32_16x16x32_bf16(
              a[m][kc], b[n][kc], acc[m][n], 0, 0, 0);
    __builtin_amdgcn_s_setprio(0);
    __builtin_amdgcn_sched_barrier(0);
    // --- G2: m23 x n01 ---
    __builtin_amdgcn_s_setprio(1);
    #pragma unroll
    for (int kc = 0; kc < 2; ++kc)
      #pragma unroll
      for (int m = 2; m < 4; ++m)
        #pragma unroll
        for (int n = 0; n < 2; ++n)
          acc[m][n] = __builtin_amdgcn_mfma_f32_16x16x32_bf16(
              a[m][kc], b[n][kc], acc[m][n], 0, 0, 0);
    __builtin_amdgcn_s_setprio(0);
    __builtin_amdgcn_sched_barrier(0);
    // --- G3: m01 x n23 ---
    __builtin_amdgcn_s_setprio(1);
    #pragma unroll
    for (int kc = 0; kc < 2; ++kc)
      #pragma unroll
      for (int m = 0; m < 2; ++m)
        #pragma unroll
        for (int n = 2; n < 4; ++n)
          acc[m][n] = __builtin_amdgcn_mfma_f32_16x16x32_bf16(
              a[m][kc], b[n][kc], acc[m][n], 0, 0, 0);
    __builtin_amdgcn_s_setprio(0);
    __builtin_amdgcn_sched_barrier(0);
    // --- G4: m23 x n23 ---
    __builtin_amdgcn_s_setprio(1);
    #pragma unroll
    for (int kc = 0; kc < 2; ++kc)
      #pragma unroll
      for (int m = 2; m < 4; ++m)
        #pragma unroll
        for (int n = 2; n < 4; ++n)
          acc[m][n] = __builtin_amdgcn_mfma_f32_16x16x32_bf16(
              a[m][kc], b[n][kc], acc[m][n], 0, 0, 0);
    __builtin_amdgcn_s_setprio(0);
    __builtin_amdgcn_sched_barrier(0);
    // --- tile close: drain my reads (free by now), prove t+1 staged, bar ---
    asm volatile("s_waitcnt lgkmcnt(0)" ::: "memory");
    __builtin_amdgcn_sched_barrier(0);
    if (t + 2 < ntk)                   // newest 4 = SA(t+2); SB(t+1) retired
      asm volatile("s_waitcnt vmcnt(4)" ::: "memory");
    else if (t + 1 < ntk)              // tail: drain SB(t+1)
      asm volatile("s_waitcnt vmcnt(0)" ::: "memory");
    __builtin_amdgcn_sched_barrier(0);
    __builtin_amdgcn_s_barrier();
    cbA = (cbA + 1 >= 3) ? 0 : cbA + 1;
  }
#undef SA_
#undef SB_
}

// ---------------------------------------------------------------------------
// Decay tables: Dn[h,s,t] = ct[h,t] * pn[h,s]  (t<=s), computed in double.
__global__ __launch_bounds__(256) void k_tables(float* __restrict__ ct,
                                                float* __restrict__ pn) {
  int idx = blockIdx.x * 256 + threadIdx.x;   // 0 .. H*S-1
  int h = idx >> 10, t = idx & 1023;
  double gamma = 1.0 - exp2(-(double)(5 + h));
  double l2g = log2(gamma);
  double r = 1.0 / gamma;
  double rowsum = (exp2(-(double)(t + 1) * l2g) - 1.0) / (r - 1.0);
  ct[idx] = (float)(exp2((double)t * l2g) / sqrt(rowsum));
  pn[idx] = (float)exp2(-(double)t * l2g);
}

// ---------------------------------------------------------------------------
// fp32 -> bf16 cast, 8 elems/thread; grid.y selects which tensor (fused 3x).
__global__ __launch_bounds__(256) void k_cast83(const float* __restrict__ s0,
                                                const float* __restrict__ s1,
                                                const float* __restrict__ s2,
                                                __bf16* __restrict__ d0,
                                                __bf16* __restrict__ d1,
                                                __bf16* __restrict__ d2) {
  const int y = blockIdx.y;
  const float* src = (y == 0) ? s0 : (y == 1) ? s1 : s2;
  __bf16* dst = (y == 0) ? d0 : (y == 1) ? d1 : d2;
  size_t i = ((size_t)blockIdx.x * 256 + threadIdx.x) * 8;
  float4 a = *(const float4*)(src + i);
  float4 b = *(const float4*)(src + i + 4);
  bf16x8 o;
  o[0] = (__bf16)a.x; o[1] = (__bf16)a.y; o[2] = (__bf16)a.z; o[3] = (__bf16)a.w;
  o[4] = (__bf16)b.x; o[5] = (__bf16)b.y; o[6] = (__bf16)b.z; o[7] = (__bf16)b.w;
  *(bf16x8*)(dst + i) = o;
}

// ---------------------------------------------------------------------------
// Transpose-cast: dst[n][k] = (bf16) src[k][n], 2048x2048. 32x32 LDS tile.
__global__ __launch_bounds__(256) void k_castT(const float* __restrict__ src,
                                               __bf16* __restrict__ dst) {
  __shared__ float t[32][33];
  const int bx = blockIdx.x, by = blockIdx.y;
  const int tid = threadIdx.x;
  const int lx = tid & 31, ly = tid >> 5;   // 32 x 8
  #pragma unroll
  for (int r = 0; r < 32; r += 8)
    t[ly + r][lx] = src[(size_t)(by * 32 + ly + r) * Dc + bx * 32 + lx];
  __syncthreads();
  #pragma unroll
  for (int r = 0; r < 32; r += 8)
    dst[(size_t)(bx * 32 + ly + r) * Dc + by * 32 + lx] = (__bf16)t[lx][ly + r];
}

// ---------------------------------------------------------------------------
// Per-head transpose-cast of Wh: WhT[h][e][d] = (bf16) Wh[h][d][e].
__global__ __launch_bounds__(256) void k_whT(const float* __restrict__ Wh,
                                             __bf16* __restrict__ WhT) {
  __shared__ float t[32][33];
  const int h = blockIdx.z;
  const int d0 = blockIdx.x * 32, e0 = blockIdx.y * 32;
  const int tid = threadIdx.x;
  const int lx = tid & 31, ly = tid >> 5;
  #pragma unroll
  for (int r = 0; r < 32; r += 8)
    t[ly + r][lx] = Wh[(size_t)h * HDc * HDc + (d0 + ly + r) * HDc + e0 + lx];
  __syncthreads();
  #pragma unroll
  for (int r = 0; r < 32; r += 8)
    WhT[(size_t)h * HDc * HDc + (e0 + ly + r) * HDc + d0 + lx] =
        (__bf16)t[lx][ly + r];
}

// ---------------------------------------------------------------------------
// MFMA projections via shared loop: per head, C = Xin[:, h] @ WhT[h]^T, K=128.
// z=0: Xb -> Q layout [h][s][b*HD]; z=1: Kb2 -> K layout; z=2: Vb2 -> Vp.
__global__ __launch_bounds__(256, 2) void k_projm(const __bf16* __restrict__ Xb,
                                                  const __bf16* __restrict__ Kb2,
                                                  const __bf16* __restrict__ Vb2,
                                                  const __bf16* __restrict__ WhT,
                                                  __bf16* __restrict__ Qo,
                                                  __bf16* __restrict__ Ko,
                                                  __bf16* __restrict__ Vo) {
  extern __shared__ __bf16 lds[];
  __bf16* As = lds;
  __bf16* Bs = lds + 3 * ABUFE;
  const int r0 = blockIdx.x * 128;
  const int h = blockIdx.y;
  const int z = blockIdx.z;
  const __bf16* src = (z == 0) ? Xb : (z == 1) ? Kb2 : Vb2;
  const int tid = threadIdx.x;
  const int wave = tid >> 6, lane = tid & 63;
  f32x4 acc[4][4] = {{}};
  mfma_loop128<Dc, HDc>(src + (size_t)r0 * Dc + h * HDc,
                        WhT + (size_t)h * HDc * HDc, 2, As, Bs, wave, lane,
                        acc);
  const int wr = wave >> 1, wc = wave & 1;
  const int rl = lane & 15, kq = lane >> 4;
  #pragma unroll
  for (int mi = 0; mi < 4; ++mi) {
    #pragma unroll
    for (int nj = 0; nj < 4; ++nj) {
      const int col = wc * 64 + nj * 16 + rl;
      #pragma unroll
      for (int r = 0; r < 4; ++r) {
        const int row = r0 + wr * 64 + mi * 16 + kq * 4 + r;
        const __bf16 v = (__bf16)acc[mi][nj][r];
        if (z == 2) {
          Vo[(size_t)row * Dc + h * HDc + col] = v;
        } else {
          const int s = row & 1023, bb = row >> 10;
          __bf16* dst = (z == 0) ? Qo : Ko;
          dst[((size_t)(h * Sc + s) * Bc + bb) * HDc + col] = v;
        }
      }
    }
  }
}

// ---------------------------------------------------------------------------
// Transpose-cast V: VB[b][t][h*128+e] -> Vt[(b*16+h)][e][t]  (bf16 -> bf16)
__global__ __launch_bounds__(256) void k_vt(const __bf16* __restrict__ VB,
                                            __bf16* __restrict__ Vt) {
  __shared__ float tl[32][33];
  const int bh = blockIdx.z, bb = bh >> 4, h = bh & 15;
  const int t0 = blockIdx.x * 32, e0 = blockIdx.y * 32;
  const int tid = threadIdx.x;
  const int lx = tid & 31, ly = tid >> 5;
  #pragma unroll
  for (int r = 0; r < 32; r += 8)
    tl[ly + r][lx] =
        (float)VB[(size_t)(bb * Sc + t0 + ly + r) * Dc + h * HDc + e0 + lx];
  __syncthreads();
  #pragma unroll
  for (int r = 0; r < 32; r += 8)
    Vt[((size_t)bh * HDc + e0 + ly + r) * Sc + t0 + lx] = (__bf16)tl[lx][ly + r];
}

// ---------------------------------------------------------------------------
// Stage 1: per-(bh, 128-tile) partial sums of V along t.
__global__ __launch_bounds__(256) void k_vsum(const __bf16* __restrict__ VB,
                                              float* __restrict__ T) {
  const int jj = blockIdx.x, bh = blockIdx.y;
  const int bb = bh >> 4, h = bh & 15;
  const int tid = threadIdx.x;
  const int tp = tid >> 7, e = tid & 127;
  const __bf16* base =
      VB + (size_t)(bb * Sc + jj * 128 + tp * 64) * Dc + h * HDc + e;
  float a0 = 0.f, a1 = 0.f, a2 = 0.f, a3 = 0.f;
  float a4 = 0.f, a5 = 0.f, a6 = 0.f, a7 = 0.f;
  for (int t = 0; t < 64; t += 8) {
    a0 += (float)base[(size_t)(t + 0) * Dc];
    a1 += (float)base[(size_t)(t + 1) * Dc];
    a2 += (float)base[(size_t)(t + 2) * Dc];
    a3 += (float)base[(size_t)(t + 3) * Dc];
    a4 += (float)base[(size_t)(t + 4) * Dc];
    a5 += (float)base[(size_t)(t + 5) * Dc];
    a6 += (float)base[(size_t)(t + 6) * Dc];
    a7 += (float)base[(size_t)(t + 7) * Dc];
  }
  const float s = ((a0 + a1) + (a2 + a3)) + ((a4 + a5) + (a6 + a7));
  __shared__ float red[2][128];
  red[tp][e] = s;
  __syncthreads();
  if (tp == 0)
    T[((size_t)bh * 8 + jj) * HDc + e] = red[0][e] + red[1][e];
}

// ---------------------------------------------------------------------------
// Stage 2: suffix-scan tiles -> SufV[bh][j][e] = sum_{t >= 128*j} V[b,t,h,e].
__global__ __launch_bounds__(128) void k_vscan(const float* __restrict__ T,
                                               float* __restrict__ SufV) {
  const int bh = blockIdx.x;
  const int e = threadIdx.x;
  float acc = 0.f;
  SufV[((size_t)bh * 9 + 8) * HDc + e] = 0.f;
  for (int jj = 7; jj >= 1; --jj) {
    acc += T[((size_t)bh * 8 + jj) * HDc + e];
    SufV[((size_t)bh * 9 + jj) * HDc + e] = acc;
  }
}

// ---------------------------------------------------------------------------
// SS via shared loop: A[h][s][t] = clamp(|ct[t]*pn[s]*(Q·K^T)/sqrt(128)|,1)
// for t<=s (upper tiles skipped). 128x128 tiles, K=512 (NTK=8).
__global__ __launch_bounds__(256, 2) void k_ssm(const __bf16* __restrict__ Q,
                                                const __bf16* __restrict__ Kb,
                                                const float* __restrict__ ct,
                                                const float* __restrict__ pn,
                                                __bf16* __restrict__ A) {
  const int bx = blockIdx.x, by = blockIdx.y;
  if (bx > by) return;               // strictly-upper tile: skip entirely
  extern __shared__ __bf16 lds[];
  __bf16* As = lds;
  __bf16* Bs = lds + 3 * ABUFE;
  const int h = blockIdx.z;
  const int t0 = bx * 128, s0 = by * 128;
  const int tid = threadIdx.x;
  __bf16* Ah = A + (size_t)h * Sc * Sc;
  const int wave = tid >> 6, lane = tid & 63;
  f32x4 acc[4][4] = {{}};
  mfma_loop128<KQKc, KQKc>(Q + (size_t)(h * Sc + s0) * KQKc,
                           Kb + (size_t)(h * Sc + t0) * KQKc, KQKc / 64, As,
                           Bs, wave, lane, acc);
  const int wr = wave >> 1, wc = wave & 1;
  const int rl = lane & 15, kq = lane >> 4;
  const float rs = 0.088388347648318447f;  // 1/sqrt(128)
  #pragma unroll
  for (int mi = 0; mi < 4; ++mi) {
    #pragma unroll
    for (int nj = 0; nj < 4; ++nj) {
      const int t = t0 + wc * 64 + nj * 16 + rl;
      const float ctv = ct[h * Sc + t] * rs;
      #pragma unroll
      for (int r = 0; r < 4; ++r) {
        const int s = s0 + wr * 64 + mi * 16 + kq * 4 + r;
        float v = 1.0f;
        if (t <= s) v = fmaxf(fabsf(ctv * pn[h * Sc + s] * acc[mi][nj][r]), 1.0f);
        Ah[(size_t)s * Sc + t] = (__bf16)v;
      }
    }
  }
}

// ---------------------------------------------------------------------------
// O = A @ V via shared loop, triangular; all-ones region added as fp32 SufV.
// Tile 128(s) x 128(e), K = (itile+1)*128 (NTK = 2..16).
__global__ __launch_bounds__(256, 2) void k_avm(const __bf16* __restrict__ A,
                                                const __bf16* __restrict__ Vt,
                                                const float* __restrict__ SufV,
                                                float* __restrict__ O) {
  extern __shared__ __bf16 lds[];
  __bf16* As = lds;
  __bf16* Bs = lds + 3 * ABUFE;
  const int bh = blockIdx.z, bb = bh >> 4, h = bh & 15;
  const int itile = blockIdx.x;
  const int s0 = itile * 128;
  const int tid = threadIdx.x;
  const int wave = tid >> 6, lane = tid & 63;
  f32x4 acc[4][4] = {{}};
  mfma_loop128<Sc, Sc>(A + (size_t)(h * Sc + s0) * Sc,
                       Vt + (size_t)bh * HDc * Sc, (itile + 1) * 2, As, Bs,
                       wave, lane, acc);
  const int wr = wave >> 1, wc = wave & 1;
  const int rl = lane & 15, kq = lane >> 4;
  const float* sufr = SufV + ((size_t)bh * 9 + (itile + 1)) * HDc;
  #pragma unroll
  for (int mi = 0; mi < 4; ++mi) {
    #pragma unroll
    for (int nj = 0; nj < 4; ++nj) {
      const int e = wc * 64 + nj * 16 + rl;
      const float sv = sufr[e];
      #pragma unroll
      for (int r = 0; r < 4; ++r) {
        const int s = s0 + wr * 64 + mi * 16 + kq * 4 + r;
        O[(size_t)(bb * Sc + s) * Dc + h * HDc + e] = acc[mi][nj][r] + sv;
      }
    }
  }
}

// ---------------------------------------------------------------------------
// Per-token GroupNorm(groups=1) over 2048 channels, in place.
__global__ __launch_bounds__(256) void k_gnorm(float* __restrict__ O,
                                               const float* __restrict__ gw,
                                               const float* __restrict__ bw) {
  const int r = blockIdx.x;
  const int tid = threadIdx.x;
  float* row = O + (size_t)r * Dc;
  const int c = tid * 4;
  float4 v0 = *(const float4*)(row + c);
  float4 v1 = *(const float4*)(row + c + 1024);
  __shared__ float red[256];
  __shared__ float sh_mu, sh_inv;
  red[tid] = v0.x + v0.y + v0.z + v0.w + v1.x + v1.y + v1.z + v1.w;
  __syncthreads();
  for (int st = 128; st > 0; st >>= 1) {
    if (tid < st) red[tid] += red[tid + st];
    __syncthreads();
  }
  if (tid == 0) sh_mu = red[0] * (1.0f / Dc);
  __syncthreads();
  const float mu = sh_mu;
  float d[8] = {v0.x - mu, v0.y - mu, v0.z - mu, v0.w - mu,
                v1.x - mu, v1.y - mu, v1.z - mu, v1.w - mu};
  float ssq = 0.f;
  #pragma unroll
  for (int i = 0; i < 8; ++i) ssq += d[i] * d[i];
  red[tid] = ssq;
  __syncthreads();
  for (int st = 128; st > 0; st >>= 1) {
    if (tid < st) red[tid] += red[tid + st];
    __syncthreads();
  }
  if (tid == 0) sh_inv = rsqrtf(red[0] * (1.0f / Dc) + GN_EPS);
  __syncthreads();
  const float inv = sh_inv;
  float4 g0 = *(const float4*)(gw + c), g1 = *(const float4*)(gw + c + 1024);
  float4 b0 = *(const float4*)(bw + c), b1 = *(const float4*)(bw + c + 1024);
  float4 o0, o1;
  o0.x = d[0] * inv * g0.x + b0.x; o0.y = d[1] * inv * g0.y + b0.y;
  o0.z = d[2] * inv * g0.z + b0.z; o0.w = d[3] * inv * g0.w + b0.w;
  o1.x = d[4] * inv * g1.x + b1.x; o1.y = d[5] * inv * g1.y + b1.y;
  o1.z = d[6] * inv * g1.z + b1.z; o1.w = d[7] * inv * g1.w + b1.w;
  *(float4*)(row + c) = o0;
  *(float4*)(row + c + 1024) = o1;
}

// ---------------------------------------------------------------------------
// bf16 MFMA GEMM via shared loop: C = A @ Bt^T. M=4096, N=2048, K=2048
// (NTK=32). Grid 16(N) x 32(M) = 512 WGs = 2/CU. XCD-chunked swizzle.
// mode 0: Gout = bf16(relu(acc) * Y);  mode 1: Fout = acc (fp32).
__global__ __launch_bounds__(256, 2) void k_mgemm(const __bf16* __restrict__ Ab,
                                                  const __bf16* __restrict__ Bt,
                                                  const float* __restrict__ Y,
                                                  __bf16* __restrict__ Gout,
                                                  float* __restrict__ Fout,
                                                  int mode) {
  extern __shared__ __bf16 lds[];
  __bf16* As = lds;
  __bf16* Bs = lds + 3 * ABUFE;
  // XCD-chunked swizzle: 512 WGs, 64 consecutive work-ids per XCD ->
  // each XCD owns 4 adjacent A-panels (4 x 0.5MB) x full B sweep.
  int wid = blockIdx.y * gridDim.x + blockIdx.x;
  wid = (wid & 7) * 64 + (wid >> 3);
  const int r0 = (wid >> 4) * 128;    // M block (32)
  const int c0 = (wid & 15) * 128;    // N block (16)
  const int tid = threadIdx.x;
  const int wave = tid >> 6, lane = tid & 63;
  f32x4 acc[4][4] = {{}};
  mfma_loop128<Dc, Dc>(Ab + (size_t)r0 * Dc, Bt + (size_t)c0 * Dc, Dc / 64,
                       As, Bs, wave, lane, acc);
  const int wr = wave >> 1, wc = wave & 1;
  const int rl = lane & 15, kq = lane >> 4;
  #pragma unroll
  for (int mi = 0; mi < 4; ++mi) {
    #pragma unroll
    for (int nj = 0; nj < 4; ++nj) {
      const int col = c0 + wc * 64 + nj * 16 + rl;
      #pragma unroll
      for (int r = 0; r < 4; ++r) {
        const int row = r0 + wr * 64 + mi * 16 + kq * 4 + r;
        const size_t idx = (size_t)row * Dc + col;
        float v = acc[mi][nj][r];
        if (mode == 0) {
          v = fmaxf(v, 0.f) * Y[idx];
          Gout[idx] = (__bf16)v;
        } else {
          Fout[idx] = v;
        }
      }
    }
  }
}

// ---------------------------------------------------------------------------
extern "C" void kernel_launch(void* const* d_in, const int* in_sizes, int n_in,
                              void* d_out, int out_size, void* d_ws, size_t ws_size,
                              hipStream_t stream) {
  const float* x  = (const float*)d_in[0];
  const float* k  = (const float*)d_in[1];
  const float* v  = (const float*)d_in[2];
  const float* Wh = (const float*)d_in[3];
  const float* wg = (const float*)d_in[4];
  const float* wo = (const float*)d_in[5];
  const float* gg = (const float*)d_in[6];
  const float* gb = (const float*)d_in[7];
  float* ws = (float*)d_ws;
  __bf16* Q   = (__bf16*)(ws + OFF_Q);
  __bf16* Kp  = (__bf16*)(ws + OFF_K);
  __bf16* VB  = (__bf16*)(ws + OFF_VB);
  __bf16* Vt  = (__bf16*)(ws + OFF_VT);
  __bf16* A   = (__bf16*)(ws + OFF_A);
  float*  O   = ws + OFF_O;
  float*  CT  = ws + OFF_CT;
  float*  PN  = ws + OFF_PN;
  __bf16* XB  = (__bf16*)(ws + OFF_XB);
  __bf16* WGT = (__bf16*)(ws + OFF_WGT);
  __bf16* WOT = (__bf16*)(ws + OFF_WOT);
  float*  SUF = ws + OFF_SUF;
  float*  TP  = ws + OFF_T;
  __bf16* WHT = (__bf16*)(ws + OFF_WHT);
  __bf16* KB2 = (__bf16*)(ws + OFF_KB2);  // aliases A (dead until k_ssm)
  __bf16* VB2 = (__bf16*)(ws + OFF_VB2);  // aliases A second half
  __bf16* G   = (__bf16*)(ws + OFF_Q);    // reuse Q region (dead after k_ssm)

  // one-time opt-in for 80 KiB dynamic LDS (host-side, graph-capture safe)
  static bool attr_done = false;
  if (!attr_done) {
    (void)hipFuncSetAttribute((const void*)k_mgemm,
                              hipFuncAttributeMaxDynamicSharedMemorySize,
                              MG_LDS);
    (void)hipFuncSetAttribute((const void*)k_projm,
                              hipFuncAttributeMaxDynamicSharedMemorySize,
                              MG_LDS);
    (void)hipFuncSetAttribute((const void*)k_ssm,
                              hipFuncAttributeMaxDynamicSharedMemorySize,
                              MG_LDS);
    (void)hipFuncSetAttribute((const void*)k_avm,
                              hipFuncAttributeMaxDynamicSharedMemorySize,
                              MG_LDS);
    attr_done = true;
  }

  k_tables<<<Hc * Sc / 256, 256, 0, stream>>>(CT, PN);
  k_cast83<<<dim3((BSc * Dc) / (256 * 8), 3), 256, 0, stream>>>(
      x, k, v, XB, KB2, VB2);
  k_castT<<<dim3(Dc / 32, Dc / 32), 256, 0, stream>>>(wg, WGT);
  k_castT<<<dim3(Dc / 32, Dc / 32), 256, 0, stream>>>(wo, WOT);
  k_whT<<<dim3(4, 4, Hc), 256, 0, stream>>>(Wh, WHT);
  k_projm<<<dim3(BSc / 128, Hc, 3), 256, MG_LDS, stream>>>(XB, KB2, VB2, WHT,
                                                           Q, Kp, VB);
  k_vt<<<dim3(Sc / 32, HDc / 32, Bc * Hc), 256, 0, stream>>>(VB, Vt);
  k_vsum<<<dim3(8, Bc * Hc), 256, 0, stream>>>(VB, TP);
  k_vscan<<<Bc * Hc, 128, 0, stream>>>(TP, SUF);
  k_ssm<<<dim3(Sc / 128, Sc / 128, Hc), 256, MG_LDS, stream>>>(Q, Kp, CT, PN,
                                                               A);
  k_avm<<<dim3(Sc / 128, 1, Bc * Hc), 256, MG_LDS, stream>>>(A, Vt, SUF, O);
  k_gnorm<<<BSc, 256, 0, stream>>>(O, gg, gb);
  k_mgemm<<<dim3(16, 32), 256, MG_LDS, stream>>>(XB, WGT, O, G, nullptr, 0);
  k_mgemm<<<dim3(16, 32), 256, MG_LDS, stream>>>(G, WOT, nullptr, nullptr,
                                                 (float*)d_out, 1);
}

// Round 6
// 364.864 us; speedup vs baseline: 1.0404x; 1.0308x over previous
//
#include <hip/hip_runtime.h>
#include <math.h>

// Problem constants
constexpr int Bc = 4, Sc = 1024, Dc = 2048, HDc = 128, Hc = 16;
constexpr int BSc = Bc * Sc;        // 4096 token rows
constexpr int KQKc = Bc * HDc;      // 512 = batch-concat K dim for SS GEMM
#define GN_EPS 1e-3f

typedef __bf16 bf16x8 __attribute__((ext_vector_type(8)));
typedef __bf16 bf16x4 __attribute__((ext_vector_type(4)));
typedef float f32x4 __attribute__((ext_vector_type(4)));

// Workspace layout (float units)
constexpr size_t OFF_Q   = 0;                                  // bf16 [H][S][512]
constexpr size_t OFF_K   = OFF_Q + (size_t)Hc * Sc * KQKc / 2; // bf16 same
constexpr size_t OFF_VB  = OFF_K + (size_t)Hc * Sc * KQKc / 2; // bf16 [BS][D]
constexpr size_t OFF_VT  = OFF_VB + (size_t)BSc * Dc / 2;      // bf16 [BH][128][1024]
constexpr size_t OFF_A   = OFF_VT + (size_t)BSc * Dc / 2;      // bf16 [H][S][S]
constexpr size_t OFF_O   = OFF_A + (size_t)Hc * Sc * Sc / 2;   // fp32 [BS][D]
constexpr size_t OFF_CT  = OFF_O + (size_t)BSc * Dc;           // [H][S]
constexpr size_t OFF_PN  = OFF_CT + (size_t)Hc * Sc;           // [H][S]
constexpr size_t OFF_XB  = OFF_PN + (size_t)Hc * Sc;           // bf16 [BS][D]
constexpr size_t OFF_WGT = OFF_XB + (size_t)BSc * Dc / 2;      // bf16 [D][D] T
constexpr size_t OFF_WOT = OFF_WGT + (size_t)Dc * Dc / 2;      // bf16 [D][D] T
constexpr size_t OFF_SUF = OFF_WOT + (size_t)Dc * Dc / 2;      // fp32 [64][9][128]
constexpr size_t OFF_T   = OFF_SUF + (size_t)64 * 9 * HDc;     // fp32 [64][8][128]
constexpr size_t OFF_WHT = OFF_T + (size_t)64 * 8 * HDc;       // bf16 [H][128][128]
constexpr size_t OFF_STAT= OFF_WHT + (size_t)Hc * HDc * HDc / 2; // fp32 [BS][2]
// KB2 / VB2 (bf16 casts of raw k, v) alias the A region (dead until k_ssm).
// G (bf16 [BS][D]) reuses the Q buffer (dead after k_ssm).
constexpr size_t OFF_KB2 = OFF_A;
constexpr size_t OFF_VB2 = OFF_A + (size_t)BSc * Dc / 2;

#define GLOAD_LDS16(gp, lp)                                               \
  __builtin_amdgcn_global_load_lds(                                       \
      (const __attribute__((address_space(1))) void*)(gp),                \
      (__attribute__((address_space(3))) void*)(lp), 16, 0, 0)

// Swizzled staging: lane l stages row l>>2 (4 lanes/row -> one 64B segment,
// coalesced) at k-chunk c = (l&3) ^ key(row), key(r) = (r>>1)&3. LDS layout:
// (r,c) at chunkbase + r*32 + (c^key(r))*8 elems. Fragment read (rl,kq) ->
// 16B unit rl*4 + (kq^key(rl)): all 64 distinct, 8-lane groups hit 8 distinct
// bank quads -> conflict-free ds_read_b128 AND coalesced global fetch.

// ---------------------------------------------------------------------------
// Shared relaxed-sync 128x128 MFMA K-loop (session-verified in R3/R4).
// 256 threads, 4 waves (2M x 2N), per-wave 64x64, BK=64.
// LDS: A triple-buffered (3 x 16KB, staged 2 tiles ahead) + B double-buffered
// (2 x 16KB, staged 1 ahead) = 80 KiB -> 2 WGs/CU.
// Per K-tile: all 16 ds_reads up-front (a01,b01,a23,b23), stage B(t+1) +
// A(t+2), 4 MFMA groups gated by compiler counted lgkmcnt; close with
// lgkmcnt(0) + counted vmcnt(4) + ONE s_barrier. Requires ntk >= 2.
constexpr int ABUFE = 128 * 64;       // elems per A buffer (16 KB)
constexpr int BBUFE = 128 * 64;       // elems per B buffer (16 KB)
constexpr int MG_LDS = (3 * ABUFE + 2 * BBUFE) * 2;  // 81920 B

template <int ASTR, int BSTR>
__device__ __forceinline__ void mfma_loop128(const __bf16* __restrict__ Abase,
                                             const __bf16* __restrict__ Bbase,
                                             const int ntk,
                                             __bf16* As, __bf16* Bs,
                                             const int wave, const int lane,
                                             f32x4 acc[4][4]) {
  const int wr = wave >> 1, wc = wave & 1;          // 2(M) x 2(N) waves
  const int lr = lane >> 2;                         // staging row in chunk
  const int lkx = ((lane & 3) ^ ((lane >> 3) & 3)) * 8;  // staging k offset
  const int rl = lane & 15, kq = lane >> 4;         // frag row / k-quarter
  const int swo = rl * 32 + ((kq ^ ((rl >> 1) & 3)) * 8);

  // stage: one 16-row x 32-k chunk per wave per call; ci = i*4 + wave.
#define SA_(i, kt, bsel) do {                                               \
    const int ci_ = (i) * 4 + wave;                                         \
    GLOAD_LDS16(Abase + (size_t)((ci_ >> 1) * 16 + lr) * ASTR               \
                    + (kt) * 64 + (ci_ & 1) * 32 + lkx,                     \
                As + (bsel) * ABUFE + ci_ * 512);                           \
  } while (0)
#define SB_(j, kt, bsel) do {                                               \
    const int ci_ = (j) * 4 + wave;                                         \
    GLOAD_LDS16(Bbase + (size_t)((ci_ >> 1) * 16 + lr) * BSTR               \
                    + (kt) * 64 + (ci_ & 1) * 32 + lkx,                     \
                Bs + (bsel) * BBUFE + ci_ * 512);                           \
  } while (0)

  // Prologue: A(0), B(0), A(1) = 12 loads (B(1) staged inside tile 0).
  SA_(0, 0, 0); SA_(1, 0, 0); SA_(2, 0, 0); SA_(3, 0, 0);
  SB_(0, 0, 0); SB_(1, 0, 0); SB_(2, 0, 0); SB_(3, 0, 0);
  SA_(0, 1, 1); SA_(1, 1, 1); SA_(2, 1, 1); SA_(3, 1, 1);
  __builtin_amdgcn_sched_barrier(0);
  asm volatile("s_waitcnt vmcnt(4)" ::: "memory");  // A(0)+B(0) landed
  __builtin_amdgcn_sched_barrier(0);
  __builtin_amdgcn_s_barrier();

  int cbA = 0;                         // A buffer holding tile t
  for (int t = 0; t < ntk; ++t) {
    const int sbA = (cbA + 2 >= 3) ? cbA - 1 : cbA + 2;  // (cbA+2)%3
    const __bf16* Ac = As + cbA * ABUFE;
    const __bf16* Bc = Bs + (t & 1) * BBUFE;
    bf16x8 a[4][2], b[4][2];
    // --- issue all 16 ds_reads, order a01, b01, a23, b23 ---
    #pragma unroll
    for (int m = 0; m < 2; ++m)
      #pragma unroll
      for (int kc = 0; kc < 2; ++kc)
        a[m][kc] = *(const bf16x8*)&Ac[((wr * 4 + m) * 2 + kc) * 512 + swo];
    #pragma unroll
    for (int n = 0; n < 2; ++n)
      #pragma unroll
      for (int kc = 0; kc < 2; ++kc)
        b[n][kc] = *(const bf16x8*)&Bc[((wc * 4 + n) * 2 + kc) * 512 + swo];
    #pragma unroll
    for (int m = 2; m < 4; ++m)
      #pragma unroll
      for (int kc = 0; kc < 2; ++kc)
        a[m][kc] = *(const bf16x8*)&Ac[((wr * 4 + m) * 2 + kc) * 512 + swo];
    #pragma unroll
    for (int n = 2; n < 4; ++n)
      #pragma unroll
      for (int kc = 0; kc < 2; ++kc)
        b[n][kc] = *(const bf16x8*)&Bc[((wc * 4 + n) * 2 + kc) * 512 + swo];
    // --- issue staging: B for t+1, A for t+2 (order matters for vmcnt) ---
    if (t + 1 < ntk) {
      SB_(0, t + 1, (t + 1) & 1); SB_(1, t + 1, (t + 1) & 1);
      SB_(2, t + 1, (t + 1) & 1); SB_(3, t + 1, (t + 1) & 1);
    }
    if (t + 2 < ntk) {
      SA_(0, t + 2, sbA); SA_(1, t + 2, sbA);
      SA_(2, t + 2, sbA); SA_(3, t + 2, sbA);
    }
    __builtin_amdgcn_sched_barrier(0);
    // --- G1: m01 x n01 (compiler counted lgkmcnt gates on a01,b01) ---
    __builtin_amdgcn_s_setprio(1);
    #pragma unroll
    for (int kc = 0; kc < 2; ++kc)
      #pragma unroll
      for (int m = 0; m < 2; ++m)
        #pragma unroll
        for (int n = 0; n < 2; ++n)
          acc[m][n] = __builtin_amdgcn_mfma_f32_16x16x32_bf16(
              a[m][kc], b[n][kc], acc[m][n], 0, 0, 0);
    __builtin_amdgcn_s_setprio(0);
    __builtin_amdgcn_sched_barrier(0);
    // --- G2: m23 x n01 ---
    __builtin_amdgcn_s_setprio(1);
    #pragma unroll
    for (int kc = 0; kc < 2; ++kc)
      #pragma unroll
      for (int m = 2; m < 4; ++m)
        #pragma unroll
        for (int n = 0; n < 2; ++n)
          acc[m][n] = __builtin_amdgcn_mfma_f32_16x16x32_bf16(
              a[m][kc], b[n][kc], acc[m][n], 0, 0, 0);
    __builtin_amdgcn_s_setprio(0);
    __builtin_amdgcn_sched_barrier(0);
    // --- G3: m01 x n23 ---
    __builtin_amdgcn_s_setprio(1);
    #pragma unroll
    for (int kc = 0; kc < 2; ++kc)
      #pragma unroll
      for (int m = 0; m < 2; ++m)
        #pragma unroll
        for (int n = 2; n < 4; ++n)
          acc[m][n] = __builtin_amdgcn_mfma_f32_16x16x32_bf16(
              a[m][kc], b[n][kc], acc[m][n], 0, 0, 0);
    __builtin_amdgcn_s_setprio(0);
    __builtin_amdgcn_sched_barrier(0);
    // --- G4: m23 x n23 ---
    __builtin_amdgcn_s_setprio(1);
    #pragma unroll
    for (int kc = 0; kc < 2; ++kc)
      #pragma unroll
      for (int m = 2; m < 4; ++m)
        #pragma unroll
        for (int n = 2; n < 4; ++n)
          acc[m][n] = __builtin_amdgcn_mfma_f32_16x16x32_bf16(
              a[m][kc], b[n][kc], acc[m][n], 0, 0, 0);
    __builtin_amdgcn_s_setprio(0);
    __builtin_amdgcn_sched_barrier(0);
    // --- tile close: drain my reads (free by now), prove t+1 staged, bar ---
    asm volatile("s_waitcnt lgkmcnt(0)" ::: "memory");
    __builtin_amdgcn_sched_barrier(0);
    if (t + 2 < ntk)                   // newest 4 = SA(t+2); SB(t+1) retired
      asm volatile("s_waitcnt vmcnt(4)" ::: "memory");
    else if (t + 1 < ntk)              // tail: drain SB(t+1)
      asm volatile("s_waitcnt vmcnt(0)" ::: "memory");
    __builtin_amdgcn_sched_barrier(0);
    __builtin_amdgcn_s_barrier();
    cbA = (cbA + 1 >= 3) ? 0 : cbA + 1;
  }
#undef SA_
#undef SB_
}

// ---------------------------------------------------------------------------
// Decay tables + zero the TP / STAT accumulators (inside the graph, so each
// replay re-zeroes before k_vt / k_avm atomics).
__global__ __launch_bounds__(256) void k_tables(float* __restrict__ ct,
                                                float* __restrict__ pn,
                                                float* __restrict__ TP,
                                                float* __restrict__ STAT) {
  int idx = blockIdx.x * 256 + threadIdx.x;   // 0 .. H*S-1 (16384)
  int h = idx >> 10, t = idx & 1023;
  double gamma = 1.0 - exp2(-(double)(5 + h));
  double l2g = log2(gamma);
  double r = 1.0 / gamma;
  double rowsum = (exp2(-(double)(t + 1) * l2g) - 1.0) / (r - 1.0);
  ct[idx] = (float)(exp2((double)t * l2g) / sqrt(rowsum));
  pn[idx] = (float)exp2(-(double)t * l2g);
  float4 z4 = {0.f, 0.f, 0.f, 0.f};
  *(float4*)(TP + (size_t)idx * 4) = z4;      // 16384*4 = 65536 floats
  if (idx < BSc * 2) STAT[idx] = 0.f;         // 8192 floats
}

// ---------------------------------------------------------------------------
// fp32 -> bf16 cast, 8 elems/thread; grid.y selects which tensor (fused 3x).
__global__ __launch_bounds__(256) void k_cast83(const float* __restrict__ s0,
                                                const float* __restrict__ s1,
                                                const float* __restrict__ s2,
                                                __bf16* __restrict__ d0,
                                                __bf16* __restrict__ d1,
                                                __bf16* __restrict__ d2) {
  const int y = blockIdx.y;
  const float* src = (y == 0) ? s0 : (y == 1) ? s1 : s2;
  __bf16* dst = (y == 0) ? d0 : (y == 1) ? d1 : d2;
  size_t i = ((size_t)blockIdx.x * 256 + threadIdx.x) * 8;
  float4 a = *(const float4*)(src + i);
  float4 b = *(const float4*)(src + i + 4);
  bf16x8 o;
  o[0] = (__bf16)a.x; o[1] = (__bf16)a.y; o[2] = (__bf16)a.z; o[3] = (__bf16)a.w;
  o[4] = (__bf16)b.x; o[5] = (__bf16)b.y; o[6] = (__bf16)b.z; o[7] = (__bf16)b.w;
  *(bf16x8*)(dst + i) = o;
}

// ---------------------------------------------------------------------------
// Transpose-cast x2: dst[n][k] = (bf16) src[k][n], 2048x2048; z selects wg/wo.
__global__ __launch_bounds__(256) void k_castT2(const float* __restrict__ s0,
                                                const float* __restrict__ s1,
                                                __bf16* __restrict__ d0,
                                                __bf16* __restrict__ d1) {
  __shared__ float t[32][33];
  const int bx = blockIdx.x, by = blockIdx.y;
  const float* src = blockIdx.z ? s1 : s0;
  __bf16* dst = blockIdx.z ? d1 : d0;
  const int tid = threadIdx.x;
  const int lx = tid & 31, ly = tid >> 5;   // 32 x 8
  #pragma unroll
  for (int r = 0; r < 32; r += 8)
    t[ly + r][lx] = src[(size_t)(by * 32 + ly + r) * Dc + bx * 32 + lx];
  __syncthreads();
  #pragma unroll
  for (int r = 0; r < 32; r += 8)
    dst[(size_t)(bx * 32 + ly + r) * Dc + by * 32 + lx] = (__bf16)t[lx][ly + r];
}

// ---------------------------------------------------------------------------
// Per-head transpose-cast of Wh: WhT[h][e][d] = (bf16) Wh[h][d][e].
__global__ __launch_bounds__(256) void k_whT(const float* __restrict__ Wh,
                                             __bf16* __restrict__ WhT) {
  __shared__ float t[32][33];
  const int h = blockIdx.z;
  const int d0 = blockIdx.x * 32, e0 = blockIdx.y * 32;
  const int tid = threadIdx.x;
  const int lx = tid & 31, ly = tid >> 5;
  #pragma unroll
  for (int r = 0; r < 32; r += 8)
    t[ly + r][lx] = Wh[(size_t)h * HDc * HDc + (d0 + ly + r) * HDc + e0 + lx];
  __syncthreads();
  #pragma unroll
  for (int r = 0; r < 32; r += 8)
    WhT[(size_t)h * HDc * HDc + (e0 + ly + r) * HDc + d0 + lx] =
        (__bf16)t[lx][ly + r];
}

// ---------------------------------------------------------------------------
// MFMA projections via shared loop: per head, C = Xin[:, h] @ WhT[h]^T, K=128.
// z=0: Xb -> Q layout [h][s][b*HD]; z=1: Kb2 -> K layout; z=2: Vb2 -> Vp.
__global__ __launch_bounds__(256, 2) void k_projm(const __bf16* __restrict__ Xb,
                                                  const __bf16* __restrict__ Kb2,
                                                  const __bf16* __restrict__ Vb2,
                                                  const __bf16* __restrict__ WhT,
                                                  __bf16* __restrict__ Qo,
                                                  __bf16* __restrict__ Ko,
                                                  __bf16* __restrict__ Vo) {
  extern __shared__ __bf16 lds[];
  __bf16* As = lds;
  __bf16* Bs = lds + 3 * ABUFE;
  const int r0 = blockIdx.x * 128;
  const int h = blockIdx.y;
  const int z = blockIdx.z;
  const __bf16* src = (z == 0) ? Xb : (z == 1) ? Kb2 : Vb2;
  const int tid = threadIdx.x;
  const int wave = tid >> 6, lane = tid & 63;
  f32x4 acc[4][4] = {{}};
  mfma_loop128<Dc, HDc>(src + (size_t)r0 * Dc + h * HDc,
                        WhT + (size_t)h * HDc * HDc, 2, As, Bs, wave, lane,
                        acc);
  const int wr = wave >> 1, wc = wave & 1;
  const int rl = lane & 15, kq = lane >> 4;
  #pragma unroll
  for (int mi = 0; mi < 4; ++mi) {
    #pragma unroll
    for (int nj = 0; nj < 4; ++nj) {
      const int col = wc * 64 + nj * 16 + rl;
      #pragma unroll
      for (int r = 0; r < 4; ++r) {
        const int row = r0 + wr * 64 + mi * 16 + kq * 4 + r;
        const __bf16 v = (__bf16)acc[mi][nj][r];
        if (z == 2) {
          Vo[(size_t)row * Dc + h * HDc + col] = v;
        } else {
          const int s = row & 1023, bb = row >> 10;
          __bf16* dst = (z == 0) ? Qo : Ko;
          dst[((size_t)(h * Sc + s) * Bc + bb) * HDc + col] = v;
        }
      }
    }
  }
}

// ---------------------------------------------------------------------------
// Transpose-cast V + fused per-128-t-tile column sums (replaces k_vsum):
// Vt[(b*16+h)][e][t] = VB[b][t][h*128+e]; TP[bh][t0/128][e] += sum_t V.
__global__ __launch_bounds__(256) void k_vt(const __bf16* __restrict__ VB,
                                            __bf16* __restrict__ Vt,
                                            float* __restrict__ TP) {
  __shared__ float tl[32][33];
  __shared__ float rs[8][32];
  const int bh = blockIdx.z, bb = bh >> 4, h = bh & 15;
  const int t0 = blockIdx.x * 32, e0 = blockIdx.y * 32;
  const int tid = threadIdx.x;
  const int lx = tid & 31, ly = tid >> 5;
  float ps = 0.f;
  #pragma unroll
  for (int r = 0; r < 32; r += 8) {
    const float v =
        (float)VB[(size_t)(bb * Sc + t0 + ly + r) * Dc + h * HDc + e0 + lx];
    tl[ly + r][lx] = v;
    ps += v;
  }
  rs[ly][lx] = ps;
  __syncthreads();
  #pragma unroll
  for (int r = 0; r < 32; r += 8)
    Vt[((size_t)bh * HDc + e0 + ly + r) * Sc + t0 + lx] = (__bf16)tl[lx][ly + r];
  if (ly == 0) {
    float s = ((rs[0][lx] + rs[1][lx]) + (rs[2][lx] + rs[3][lx])) +
              ((rs[4][lx] + rs[5][lx]) + (rs[6][lx] + rs[7][lx]));
    atomicAdd(&TP[((size_t)bh * 8 + (t0 >> 7)) * HDc + e0 + lx], s);
  }
}

// ---------------------------------------------------------------------------
// Stage 2: suffix-scan tiles -> SufV[bh][j][e] = sum_{t >= 128*j} V[b,t,h,e].
__global__ __launch_bounds__(128) void k_vscan(const float* __restrict__ T,
                                               float* __restrict__ SufV) {
  const int bh = blockIdx.x;
  const int e = threadIdx.x;
  float acc = 0.f;
  SufV[((size_t)bh * 9 + 8) * HDc + e] = 0.f;
  for (int jj = 7; jj >= 1; --jj) {
    acc += T[((size_t)bh * 8 + jj) * HDc + e];
    SufV[((size_t)bh * 9 + jj) * HDc + e] = acc;
  }
}

// ---------------------------------------------------------------------------
// SS via shared loop: A[h][s][t] = clamp(|ct[t]*pn[s]*(Q·K^T)/sqrt(128)|,1)
// for t<=s. Triangle-compact grid (36, 16): no dead blocks.
__global__ __launch_bounds__(256, 2) void k_ssm(const __bf16* __restrict__ Q,
                                                const __bf16* __restrict__ Kb,
                                                const float* __restrict__ ct,
                                                const float* __restrict__ pn,
                                                __bf16* __restrict__ A) {
  const int q = blockIdx.x;            // 0..35 -> (row, col) with col <= row
  int trow = (int)((sqrtf(8.f * q + 1.f) - 1.f) * 0.5f);
  if (((trow + 1) * (trow + 2)) >> 1 <= q) ++trow;
  const int tcol = q - ((trow * (trow + 1)) >> 1);
  extern __shared__ __bf16 lds[];
  __bf16* As = lds;
  __bf16* Bs = lds + 3 * ABUFE;
  const int h = blockIdx.y;
  const int t0 = tcol * 128, s0 = trow * 128;
  const int tid = threadIdx.x;
  __bf16* Ah = A + (size_t)h * Sc * Sc;
  const int wave = tid >> 6, lane = tid & 63;
  f32x4 acc[4][4] = {{}};
  mfma_loop128<KQKc, KQKc>(Q + (size_t)(h * Sc + s0) * KQKc,
                           Kb + (size_t)(h * Sc + t0) * KQKc, KQKc / 64, As,
                           Bs, wave, lane, acc);
  const int wr = wave >> 1, wc = wave & 1;
  const int rl = lane & 15, kq = lane >> 4;
  const float rs = 0.088388347648318447f;  // 1/sqrt(128)
  #pragma unroll
  for (int mi = 0; mi < 4; ++mi) {
    #pragma unroll
    for (int nj = 0; nj < 4; ++nj) {
      const int t = t0 + wc * 64 + nj * 16 + rl;
      const float ctv = ct[h * Sc + t] * rs;
      #pragma unroll
      for (int r = 0; r < 4; ++r) {
        const int s = s0 + wr * 64 + mi * 16 + kq * 4 + r;
        float v = 1.0f;
        if (t <= s) v = fmaxf(fabsf(ctv * pn[h * Sc + s] * acc[mi][nj][r]), 1.0f);
        Ah[(size_t)s * Sc + t] = (__bf16)v;
      }
    }
  }
}

// ---------------------------------------------------------------------------
// O = A @ V via shared loop, triangular; all-ones region added as fp32 SufV.
// Grid (4, 1, 64): each block processes the COMPLEMENTARY itile pair
// {bx, 7-bx} -> exactly 18 K-tiles per block (deterministic load balance;
// old (8,·) grid had 8x spread and same-itile CU pairing under round-robin).
// Epilogue also accumulates GroupNorm stats (sum, sumsq per token row) into
// STAT via 16-lane shfl reduce + 2 atomics per row per wave.
__global__ __launch_bounds__(256, 2) void k_avm(const __bf16* __restrict__ A,
                                                const __bf16* __restrict__ Vt,
                                                const float* __restrict__ SufV,
                                                float* __restrict__ O,
                                                float* __restrict__ STAT) {
  extern __shared__ __bf16 lds[];
  __bf16* As = lds;
  __bf16* Bs = lds + 3 * ABUFE;
  const int bh = blockIdx.z, bb = bh >> 4, h = bh & 15;
  const int tid = threadIdx.x;
  const int wave = tid >> 6, lane = tid & 63;
  const int wr = wave >> 1, wc = wave & 1;
  const int rl = lane & 15, kq = lane >> 4;
  for (int half = 0; half < 2; ++half) {
    const int itile = half ? 7 - (int)blockIdx.x : (int)blockIdx.x;
    const int s0 = itile * 128;
    f32x4 acc[4][4] = {{}};
    mfma_loop128<Sc, Sc>(A + (size_t)(h * Sc + s0) * Sc,
                         Vt + (size_t)bh * HDc * Sc, (itile + 1) * 2, As, Bs,
                         wave, lane, acc);
    const float* sufr = SufV + ((size_t)bh * 9 + (itile + 1)) * HDc;
    #pragma unroll
    for (int mi = 0; mi < 4; ++mi) {
      #pragma unroll
      for (int r = 0; r < 4; ++r) {
        const int s = s0 + wr * 64 + mi * 16 + kq * 4 + r;
        const size_t orow = (size_t)(bb * Sc + s);
        float vs = 0.f, vq = 0.f;
        #pragma unroll
        for (int nj = 0; nj < 4; ++nj) {
          const int e = wc * 64 + nj * 16 + rl;
          const float v = acc[mi][nj][r] + sufr[e];
          O[orow * Dc + h * HDc + e] = v;
          vs += v;
          vq += v * v;
        }
        #pragma unroll
        for (int m = 1; m < 16; m <<= 1) {
          vs += __shfl_xor(vs, m);
          vq += __shfl_xor(vq, m);
        }
        if (rl == 0) {
          atomicAdd(&STAT[orow * 2], vs);
          atomicAdd(&STAT[orow * 2 + 1], vq);
        }
      }
    }
  }
}

// ---------------------------------------------------------------------------
// bf16 MFMA GEMM via shared loop: C = A @ Bt^T. M=4096, N=2048, K=2048
// (NTK=32). Grid 16(N) x 32(M) = 512 WGs = 2/CU. XCD-chunked swizzle.
// mode 0: Gout = bf16(relu(acc) * groupnorm(Y; STAT, gw, bw))  (gnorm fused:
//         mu/var from STAT one-pass; O is near zero-mean per row so
//         E[x^2]-mu^2 cancellation is negligible).
// mode 1: Fout = acc (fp32).
__global__ __launch_bounds__(256, 2) void k_mgemm(const __bf16* __restrict__ Ab,
                                                  const __bf16* __restrict__ Bt,
                                                  const float* __restrict__ Y,
                                                  const float* __restrict__ gw,
                                                  const float* __restrict__ bw,
                                                  const float* __restrict__ STAT,
                                                  __bf16* __restrict__ Gout,
                                                  float* __restrict__ Fout,
                                                  int mode) {
  extern __shared__ __bf16 lds[];
  __bf16* As = lds;
  __bf16* Bs = lds + 3 * ABUFE;
  // XCD-chunked swizzle: 512 WGs, 64 consecutive work-ids per XCD ->
  // each XCD owns 4 adjacent A-panels (4 x 0.5MB) x full B sweep.
  int wid = blockIdx.y * gridDim.x + blockIdx.x;
  wid = (wid & 7) * 64 + (wid >> 3);
  const int r0 = (wid >> 4) * 128;    // M block (32)
  const int c0 = (wid & 15) * 128;    // N block (16)
  const int tid = threadIdx.x;
  const int wave = tid >> 6, lane = tid & 63;
  f32x4 acc[4][4] = {{}};
  mfma_loop128<Dc, Dc>(Ab + (size_t)r0 * Dc, Bt + (size_t)c0 * Dc, Dc / 64,
                       As, Bs, wave, lane, acc);
  const int wr = wave >> 1, wc = wave & 1;
  const int rl = lane & 15, kq = lane >> 4;
  if (mode == 0) {
    #pragma unroll
    for (int mi = 0; mi < 4; ++mi) {
      #pragma unroll
      for (int r = 0; r < 4; ++r) {
        const int row = r0 + wr * 64 + mi * 16 + kq * 4 + r;
        const float mu = STAT[(size_t)row * 2] * (1.0f / Dc);
        const float va = STAT[(size_t)row * 2 + 1] * (1.0f / Dc) - mu * mu;
        const float inv = rsqrtf(va + GN_EPS);
        #pragma unroll
        for (int nj = 0; nj < 4; ++nj) {
          const int col = c0 + wc * 64 + nj * 16 + rl;
          const size_t idx = (size_t)row * Dc + col;
          const float yv = (Y[idx] - mu) * inv * gw[col] + bw[col];
          Gout[idx] = (__bf16)(fmaxf(acc[mi][nj][r], 0.f) * yv);
        }
      }
    }
  } else {
    #pragma unroll
    for (int mi = 0; mi < 4; ++mi) {
      #pragma unroll
      for (int nj = 0; nj < 4; ++nj) {
        const int col = c0 + wc * 64 + nj * 16 + rl;
        #pragma unroll
        for (int r = 0; r < 4; ++r) {
          const int row = r0 + wr * 64 + mi * 16 + kq * 4 + r;
          Fout[(size_t)row * Dc + col] = acc[mi][nj][r];
        }
      }
    }
  }
}

// ---------------------------------------------------------------------------
extern "C" void kernel_launch(void* const* d_in, const int* in_sizes, int n_in,
                              void* d_out, int out_size, void* d_ws, size_t ws_size,
                              hipStream_t stream) {
  const float* x  = (const float*)d_in[0];
  const float* k  = (const float*)d_in[1];
  const float* v  = (const float*)d_in[2];
  const float* Wh = (const float*)d_in[3];
  const float* wg = (const float*)d_in[4];
  const float* wo = (const float*)d_in[5];
  const float* gg = (const float*)d_in[6];
  const float* gb = (const float*)d_in[7];
  float* ws = (float*)d_ws;
  __bf16* Q   = (__bf16*)(ws + OFF_Q);
  __bf16* Kp  = (__bf16*)(ws + OFF_K);
  __bf16* VB  = (__bf16*)(ws + OFF_VB);
  __bf16* Vt  = (__bf16*)(ws + OFF_VT);
  __bf16* A   = (__bf16*)(ws + OFF_A);
  float*  O   = ws + OFF_O;
  float*  CT  = ws + OFF_CT;
  float*  PN  = ws + OFF_PN;
  __bf16* XB  = (__bf16*)(ws + OFF_XB);
  __bf16* WGT = (__bf16*)(ws + OFF_WGT);
  __bf16* WOT = (__bf16*)(ws + OFF_WOT);
  float*  SUF = ws + OFF_SUF;
  float*  TP  = ws + OFF_T;
  __bf16* WHT = (__bf16*)(ws + OFF_WHT);
  float*  STAT= ws + OFF_STAT;
  __bf16* KB2 = (__bf16*)(ws + OFF_KB2);  // aliases A (dead until k_ssm)
  __bf16* VB2 = (__bf16*)(ws + OFF_VB2);  // aliases A second half
  __bf16* G   = (__bf16*)(ws + OFF_Q);    // reuse Q region (dead after k_ssm)

  // one-time opt-in for 80 KiB dynamic LDS (host-side, graph-capture safe)
  static bool attr_done = false;
  if (!attr_done) {
    (void)hipFuncSetAttribute((const void*)k_mgemm,
                              hipFuncAttributeMaxDynamicSharedMemorySize,
                              MG_LDS);
    (void)hipFuncSetAttribute((const void*)k_projm,
                              hipFuncAttributeMaxDynamicSharedMemorySize,
                              MG_LDS);
    (void)hipFuncSetAttribute((const void*)k_ssm,
                              hipFuncAttributeMaxDynamicSharedMemorySize,
                              MG_LDS);
    (void)hipFuncSetAttribute((const void*)k_avm,
                              hipFuncAttributeMaxDynamicSharedMemorySize,
                              MG_LDS);
    attr_done = true;
  }

  k_tables<<<Hc * Sc / 256, 256, 0, stream>>>(CT, PN, TP, STAT);
  k_cast83<<<dim3((BSc * Dc) / (256 * 8), 3), 256, 0, stream>>>(
      x, k, v, XB, KB2, VB2);
  k_castT2<<<dim3(Dc / 32, Dc / 32, 2), 256, 0, stream>>>(wg, wo, WGT, WOT);
  k_whT<<<dim3(4, 4, Hc), 256, 0, stream>>>(Wh, WHT);
  k_projm<<<dim3(BSc / 128, Hc, 3), 256, MG_LDS, stream>>>(XB, KB2, VB2, WHT,
                                                           Q, Kp, VB);
  k_vt<<<dim3(Sc / 32, HDc / 32, Bc * Hc), 256, 0, stream>>>(VB, Vt, TP);
  k_vscan<<<Bc * Hc, 128, 0, stream>>>(TP, SUF);
  k_ssm<<<dim3(36, Hc), 256, MG_LDS, stream>>>(Q, Kp, CT, PN, A);
  k_avm<<<dim3(4, 1, Bc * Hc), 256, MG_LDS, stream>>>(A, Vt, SUF, O, STAT);
  k_mgemm<<<dim3(16, 32), 256, MG_LDS, stream>>>(XB, WGT, O, gg, gb, STAT, G,
                                                 nullptr, 0);
  k_mgemm<<<dim3(16, 32), 256, MG_LDS, stream>>>(G, WOT, nullptr, nullptr,
                                                 nullptr, nullptr, nullptr,
                                                 (float*)d_out, 1);
}

// Round 7
// 360.263 us; speedup vs baseline: 1.0537x; 1.0128x over previous
//
#include <hip/hip_runtime.h>
#include <math.h>

// Problem constants
constexpr int Bc = 4, Sc = 1024, Dc = 2048, HDc = 128, Hc = 16;
constexpr int BSc = Bc * Sc;        // 4096 token rows
constexpr int KQKc = Bc * HDc;      // 512 = batch-concat K dim for SS GEMM
#define GN_EPS 1e-3f

typedef __bf16 bf16x8 __attribute__((ext_vector_type(8)));
typedef __bf16 bf16x4 __attribute__((ext_vector_type(4)));
typedef float f32x4 __attribute__((ext_vector_type(4)));

// Workspace layout (float units)
constexpr size_t OFF_Q   = 0;                                  // bf16 [H][S][512]
constexpr size_t OFF_K   = OFF_Q + (size_t)Hc * Sc * KQKc / 2; // bf16 same
constexpr size_t OFF_VB  = OFF_K + (size_t)Hc * Sc * KQKc / 2; // bf16 [BS][D]
constexpr size_t OFF_VT  = OFF_VB + (size_t)BSc * Dc / 2;      // bf16 [BH][128][1024]
constexpr size_t OFF_A   = OFF_VT + (size_t)BSc * Dc / 2;      // bf16 [H][S][S]
constexpr size_t OFF_O   = OFF_A + (size_t)Hc * Sc * Sc / 2;   // fp32 [BS][D]
constexpr size_t OFF_CT  = OFF_O + (size_t)BSc * Dc;           // [H][S]
constexpr size_t OFF_PN  = OFF_CT + (size_t)Hc * Sc;           // [H][S]
constexpr size_t OFF_XB  = OFF_PN + (size_t)Hc * Sc;           // bf16 [BS][D]
constexpr size_t OFF_WGT = OFF_XB + (size_t)BSc * Dc / 2;      // bf16 [D][D] T
constexpr size_t OFF_WOT = OFF_WGT + (size_t)Dc * Dc / 2;      // bf16 [D][D] T
constexpr size_t OFF_SUF = OFF_WOT + (size_t)Dc * Dc / 2;      // fp32 [64][9][128]
constexpr size_t OFF_T   = OFF_SUF + (size_t)64 * 9 * HDc;     // fp32 [64][8][128]
constexpr size_t OFF_WHT = OFF_T + (size_t)64 * 8 * HDc;       // bf16 [H][128][128]
constexpr size_t OFF_STAT= OFF_WHT + (size_t)Hc * HDc * HDc / 2; // fp32 [BS][2]
// KB2 / VB2 (bf16 casts of raw k, v) alias the A region (dead until k_ssm).
// G (bf16 [BS][D]) reuses the Q buffer (dead after k_ssm).
constexpr size_t OFF_KB2 = OFF_A;
constexpr size_t OFF_VB2 = OFF_A + (size_t)BSc * Dc / 2;

#define GLOAD_LDS16(gp, lp)                                               \
  __builtin_amdgcn_global_load_lds(                                       \
      (const __attribute__((address_space(1))) void*)(gp),                \
      (__attribute__((address_space(3))) void*)(lp), 16, 0, 0)

// Swizzled staging: lane l stages row l>>2 (4 lanes/row -> one 64B segment,
// coalesced) at k-chunk c = (l&3) ^ key(row), key(r) = (r>>1)&3. LDS layout:
// (r,c) at chunkbase + r*32 + (c^key(r))*8 elems. Fragment read (rl,kq) ->
// 16B unit rl*4 + (kq^key(rl)): all 64 distinct, 8-lane groups hit 8 distinct
// bank quads -> conflict-free ds_read_b128 AND coalesced global fetch.

// ---------------------------------------------------------------------------
// Shared relaxed-sync 128x128 MFMA K-loop (session-verified in R3/R4).
// 256 threads, 4 waves (2M x 2N), per-wave 64x64, BK=64.
// LDS: A triple-buffered (3 x 16KB, staged 2 tiles ahead) + B double-buffered
// (2 x 16KB, staged 1 ahead) = 80 KiB -> 2 WGs/CU.
// Per K-tile: all 16 ds_reads up-front (a01,b01,a23,b23), stage B(t+1) +
// A(t+2), 4 MFMA groups gated by compiler counted lgkmcnt; close with
// lgkmcnt(0) + counted vmcnt(4) + ONE s_barrier. Requires ntk >= 2.
constexpr int ABUFE = 128 * 64;       // elems per A buffer (16 KB)
constexpr int BBUFE = 128 * 64;       // elems per B buffer (16 KB)
constexpr int MG_LDS = (3 * ABUFE + 2 * BBUFE) * 2;  // 81920 B
constexpr int PJ_LDS = 4 * 8192 * 2;                 // 65536 B (k_projm)

template <int ASTR, int BSTR>
__device__ __forceinline__ void mfma_loop128(const __bf16* __restrict__ Abase,
                                             const __bf16* __restrict__ Bbase,
                                             const int ntk,
                                             __bf16* As, __bf16* Bs,
                                             const int wave, const int lane,
                                             f32x4 acc[4][4]) {
  const int wr = wave >> 1, wc = wave & 1;          // 2(M) x 2(N) waves
  const int lr = lane >> 2;                         // staging row in chunk
  const int lkx = ((lane & 3) ^ ((lane >> 3) & 3)) * 8;  // staging k offset
  const int rl = lane & 15, kq = lane >> 4;         // frag row / k-quarter
  const int swo = rl * 32 + ((kq ^ ((rl >> 1) & 3)) * 8);

  // stage: one 16-row x 32-k chunk per wave per call; ci = i*4 + wave.
#define SA_(i, kt, bsel) do {                                               \
    const int ci_ = (i) * 4 + wave;                                         \
    GLOAD_LDS16(Abase + (size_t)((ci_ >> 1) * 16 + lr) * ASTR               \
                    + (kt) * 64 + (ci_ & 1) * 32 + lkx,                     \
                As + (bsel) * ABUFE + ci_ * 512);                           \
  } while (0)
#define SB_(j, kt, bsel) do {                                               \
    const int ci_ = (j) * 4 + wave;                                         \
    GLOAD_LDS16(Bbase + (size_t)((ci_ >> 1) * 16 + lr) * BSTR               \
                    + (kt) * 64 + (ci_ & 1) * 32 + lkx,                     \
                Bs + (bsel) * BBUFE + ci_ * 512);                           \
  } while (0)

  // Prologue: A(0), B(0), A(1) = 12 loads (B(1) staged inside tile 0).
  SA_(0, 0, 0); SA_(1, 0, 0); SA_(2, 0, 0); SA_(3, 0, 0);
  SB_(0, 0, 0); SB_(1, 0, 0); SB_(2, 0, 0); SB_(3, 0, 0);
  SA_(0, 1, 1); SA_(1, 1, 1); SA_(2, 1, 1); SA_(3, 1, 1);
  __builtin_amdgcn_sched_barrier(0);
  asm volatile("s_waitcnt vmcnt(4)" ::: "memory");  // A(0)+B(0) landed
  __builtin_amdgcn_sched_barrier(0);
  __builtin_amdgcn_s_barrier();

  int cbA = 0;                         // A buffer holding tile t
  for (int t = 0; t < ntk; ++t) {
    const int sbA = (cbA + 2 >= 3) ? cbA - 1 : cbA + 2;  // (cbA+2)%3
    const __bf16* Ac = As + cbA * ABUFE;
    const __bf16* Bc = Bs + (t & 1) * BBUFE;
    bf16x8 a[4][2], b[4][2];
    // --- issue all 16 ds_reads, order a01, b01, a23, b23 ---
    #pragma unroll
    for (int m = 0; m < 2; ++m)
      #pragma unroll
      for (int kc = 0; kc < 2; ++kc)
        a[m][kc] = *(const bf16x8*)&Ac[((wr * 4 + m) * 2 + kc) * 512 + swo];
    #pragma unroll
    for (int n = 0; n < 2; ++n)
      #pragma unroll
      for (int kc = 0; kc < 2; ++kc)
        b[n][kc] = *(const bf16x8*)&Bc[((wc * 4 + n) * 2 + kc) * 512 + swo];
    #pragma unroll
    for (int m = 2; m < 4; ++m)
      #pragma unroll
      for (int kc = 0; kc < 2; ++kc)
        a[m][kc] = *(const bf16x8*)&Ac[((wr * 4 + m) * 2 + kc) * 512 + swo];
    #pragma unroll
    for (int n = 2; n < 4; ++n)
      #pragma unroll
      for (int kc = 0; kc < 2; ++kc)
        b[n][kc] = *(const bf16x8*)&Bc[((wc * 4 + n) * 2 + kc) * 512 + swo];
    // --- issue staging: B for t+1, A for t+2 (order matters for vmcnt) ---
    if (t + 1 < ntk) {
      SB_(0, t + 1, (t + 1) & 1); SB_(1, t + 1, (t + 1) & 1);
      SB_(2, t + 1, (t + 1) & 1); SB_(3, t + 1, (t + 1) & 1);
    }
    if (t + 2 < ntk) {
      SA_(0, t + 2, sbA); SA_(1, t + 2, sbA);
      SA_(2, t + 2, sbA); SA_(3, t + 2, sbA);
    }
    __builtin_amdgcn_sched_barrier(0);
    // --- G1: m01 x n01 (compiler counted lgkmcnt gates on a01,b01) ---
    __builtin_amdgcn_s_setprio(1);
    #pragma unroll
    for (int kc = 0; kc < 2; ++kc)
      #pragma unroll
      for (int m = 0; m < 2; ++m)
        #pragma unroll
        for (int n = 0; n < 2; ++n)
          acc[m][n] = __builtin_amdgcn_mfma_f32_16x16x32_bf16(
              a[m][kc], b[n][kc], acc[m][n], 0, 0, 0);
    __builtin_amdgcn_s_setprio(0);
    __builtin_amdgcn_sched_barrier(0);
    // --- G2: m23 x n01 ---
    __builtin_amdgcn_s_setprio(1);
    #pragma unroll
    for (int kc = 0; kc < 2; ++kc)
      #pragma unroll
      for (int m = 2; m < 4; ++m)
        #pragma unroll
        for (int n = 0; n < 2; ++n)
          acc[m][n] = __builtin_amdgcn_mfma_f32_16x16x32_bf16(
              a[m][kc], b[n][kc], acc[m][n], 0, 0, 0);
    __builtin_amdgcn_s_setprio(0);
    __builtin_amdgcn_sched_barrier(0);
    // --- G3: m01 x n23 ---
    __builtin_amdgcn_s_setprio(1);
    #pragma unroll
    for (int kc = 0; kc < 2; ++kc)
      #pragma unroll
      for (int m = 0; m < 2; ++m)
        #pragma unroll
        for (int n = 2; n < 4; ++n)
          acc[m][n] = __builtin_amdgcn_mfma_f32_16x16x32_bf16(
              a[m][kc], b[n][kc], acc[m][n], 0, 0, 0);
    __builtin_amdgcn_s_setprio(0);
    __builtin_amdgcn_sched_barrier(0);
    // --- G4: m23 x n23 ---
    __builtin_amdgcn_s_setprio(1);
    #pragma unroll
    for (int kc = 0; kc < 2; ++kc)
      #pragma unroll
      for (int m = 2; m < 4; ++m)
        #pragma unroll
        for (int n = 2; n < 4; ++n)
          acc[m][n] = __builtin_amdgcn_mfma_f32_16x16x32_bf16(
              a[m][kc], b[n][kc], acc[m][n], 0, 0, 0);
    __builtin_amdgcn_s_setprio(0);
    __builtin_amdgcn_sched_barrier(0);
    // --- tile close: drain my reads (free by now), prove t+1 staged, bar ---
    asm volatile("s_waitcnt lgkmcnt(0)" ::: "memory");
    __builtin_amdgcn_sched_barrier(0);
    if (t + 2 < ntk)                   // newest 4 = SA(t+2); SB(t+1) retired
      asm volatile("s_waitcnt vmcnt(4)" ::: "memory");
    else if (t + 1 < ntk)              // tail: drain SB(t+1)
      asm volatile("s_waitcnt vmcnt(0)" ::: "memory");
    __builtin_amdgcn_sched_barrier(0);
    __builtin_amdgcn_s_barrier();
    cbA = (cbA + 1 >= 3) ? 0 : cbA + 1;
  }
#undef SA_
#undef SB_
}

// ---------------------------------------------------------------------------
// Decay tables + zero the TP / STAT accumulators (inside the graph, so each
// replay re-zeroes before k_vt / k_avm atomics).
__global__ __launch_bounds__(256) void k_tables(float* __restrict__ ct,
                                                float* __restrict__ pn,
                                                float* __restrict__ TP,
                                                float* __restrict__ STAT) {
  int idx = blockIdx.x * 256 + threadIdx.x;   // 0 .. H*S-1 (16384)
  int h = idx >> 10, t = idx & 1023;
  double gamma = 1.0 - exp2(-(double)(5 + h));
  double l2g = log2(gamma);
  double r = 1.0 / gamma;
  double rowsum = (exp2(-(double)(t + 1) * l2g) - 1.0) / (r - 1.0);
  ct[idx] = (float)(exp2((double)t * l2g) / sqrt(rowsum));
  pn[idx] = (float)exp2(-(double)t * l2g);
  float4 z4 = {0.f, 0.f, 0.f, 0.f};
  *(float4*)(TP + (size_t)idx * 4) = z4;      // 16384*4 = 65536 floats
  if (idx < BSc * 2) STAT[idx] = 0.f;         // 8192 floats
}

// ---------------------------------------------------------------------------
// fp32 -> bf16 cast, 8 elems/thread; grid.y selects which tensor (fused 3x).
__global__ __launch_bounds__(256) void k_cast83(const float* __restrict__ s0,
                                                const float* __restrict__ s1,
                                                const float* __restrict__ s2,
                                                __bf16* __restrict__ d0,
                                                __bf16* __restrict__ d1,
                                                __bf16* __restrict__ d2) {
  const int y = blockIdx.y;
  const float* src = (y == 0) ? s0 : (y == 1) ? s1 : s2;
  __bf16* dst = (y == 0) ? d0 : (y == 1) ? d1 : d2;
  size_t i = ((size_t)blockIdx.x * 256 + threadIdx.x) * 8;
  float4 a = *(const float4*)(src + i);
  float4 b = *(const float4*)(src + i + 4);
  bf16x8 o;
  o[0] = (__bf16)a.x; o[1] = (__bf16)a.y; o[2] = (__bf16)a.z; o[3] = (__bf16)a.w;
  o[4] = (__bf16)b.x; o[5] = (__bf16)b.y; o[6] = (__bf16)b.z; o[7] = (__bf16)b.w;
  *(bf16x8*)(dst + i) = o;
}

// ---------------------------------------------------------------------------
// Transpose-cast x2: dst[n][k] = (bf16) src[k][n], 2048x2048; z selects wg/wo.
__global__ __launch_bounds__(256) void k_castT2(const float* __restrict__ s0,
                                                const float* __restrict__ s1,
                                                __bf16* __restrict__ d0,
                                                __bf16* __restrict__ d1) {
  __shared__ float t[32][33];
  const int bx = blockIdx.x, by = blockIdx.y;
  const float* src = blockIdx.z ? s1 : s0;
  __bf16* dst = blockIdx.z ? d1 : d0;
  const int tid = threadIdx.x;
  const int lx = tid & 31, ly = tid >> 5;   // 32 x 8
  #pragma unroll
  for (int r = 0; r < 32; r += 8)
    t[ly + r][lx] = src[(size_t)(by * 32 + ly + r) * Dc + bx * 32 + lx];
  __syncthreads();
  #pragma unroll
  for (int r = 0; r < 32; r += 8)
    dst[(size_t)(bx * 32 + ly + r) * Dc + by * 32 + lx] = (__bf16)t[lx][ly + r];
}

// ---------------------------------------------------------------------------
// Per-head transpose-cast of Wh: WhT[h][e][d] = (bf16) Wh[h][d][e].
__global__ __launch_bounds__(256) void k_whT(const float* __restrict__ Wh,
                                             __bf16* __restrict__ WhT) {
  __shared__ float t[32][33];
  const int h = blockIdx.z;
  const int d0 = blockIdx.x * 32, e0 = blockIdx.y * 32;
  const int tid = threadIdx.x;
  const int lx = tid & 31, ly = tid >> 5;
  #pragma unroll
  for (int r = 0; r < 32; r += 8)
    t[ly + r][lx] = Wh[(size_t)h * HDc * HDc + (d0 + ly + r) * HDc + e0 + lx];
  __syncthreads();
  #pragma unroll
  for (int r = 0; r < 32; r += 8)
    WhT[(size_t)h * HDc * HDc + (e0 + ly + r) * HDc + d0 + lx] =
        (__bf16)t[lx][ly + r];
}

// ---------------------------------------------------------------------------
// MFMA projections, SINGLE-STAGE (K=128 fits in LDS; the pipelined loop at
// NTK=2 was pure prologue overhead). Stage X-panel (32 KB) + W-panel (32 KB)
// once (16 gloads/wave), one vmcnt(0) + one barrier, 128 MFMA/wave straight
// through with compiler counted lgkmcnt. 64 KiB LDS -> 2 WGs/CU; 1536 blocks
// stream 6 rounds/CU, co-resident WG hides the load latency.
// z=0: Xb -> Q layout [h][s][b*HD]; z=1: Kb2 -> K layout; z=2: Vb2 -> Vp.
__global__ __launch_bounds__(256, 2) void k_projm(const __bf16* __restrict__ Xb,
                                                  const __bf16* __restrict__ Kb2,
                                                  const __bf16* __restrict__ Vb2,
                                                  const __bf16* __restrict__ WhT,
                                                  __bf16* __restrict__ Qo,
                                                  __bf16* __restrict__ Ko,
                                                  __bf16* __restrict__ Vo) {
  extern __shared__ __bf16 lds[];
  __bf16* Xs = lds;                    // 2 x 8192 (kt-major)
  __bf16* Ws = lds + 2 * 8192;         // 2 x 8192
  const int r0 = blockIdx.x * 128;
  const int h = blockIdx.y;
  const int z = blockIdx.z;
  const __bf16* src = (z == 0) ? Xb : (z == 1) ? Kb2 : Vb2;
  const __bf16* wsrc = WhT + (size_t)h * HDc * HDc;
  const int tid = threadIdx.x;
  const int wave = tid >> 6, lane = tid & 63;
  const int wr = wave >> 1, wc = wave & 1;
  const int lr = lane >> 2;
  const int lkx = ((lane & 3) ^ ((lane >> 3) & 3)) * 8;
  const int rl = lane & 15, kq = lane >> 4;
  const int swo = rl * 32 + ((kq ^ ((rl >> 1) & 3)) * 8);
  // stage both K-halves of both operands (same chunk swizzle as the loop)
  #pragma unroll
  for (int kt = 0; kt < 2; ++kt) {
    #pragma unroll
    for (int i = 0; i < 4; ++i) {
      const int ci = i * 4 + wave;
      const int row = (ci >> 1) * 16 + lr;
      const int ko = kt * 64 + (ci & 1) * 32 + lkx;
      GLOAD_LDS16(src + (size_t)(r0 + row) * Dc + h * HDc + ko,
                  Xs + kt * 8192 + ci * 512);
      GLOAD_LDS16(wsrc + (size_t)row * HDc + ko, Ws + kt * 8192 + ci * 512);
    }
  }
  __builtin_amdgcn_sched_barrier(0);
  asm volatile("s_waitcnt vmcnt(0)" ::: "memory");
  __builtin_amdgcn_sched_barrier(0);
  __builtin_amdgcn_s_barrier();
  f32x4 acc[4][4] = {{}};
  #pragma unroll
  for (int kt = 0; kt < 2; ++kt) {
    bf16x8 a[4][2], b[4][2];
    #pragma unroll
    for (int m = 0; m < 4; ++m)
      #pragma unroll
      for (int kc = 0; kc < 2; ++kc)
        a[m][kc] =
            *(const bf16x8*)&Xs[kt * 8192 + ((wr * 4 + m) * 2 + kc) * 512 + swo];
    #pragma unroll
    for (int n = 0; n < 4; ++n)
      #pragma unroll
      for (int kc = 0; kc < 2; ++kc)
        b[n][kc] =
            *(const bf16x8*)&Ws[kt * 8192 + ((wc * 4 + n) * 2 + kc) * 512 + swo];
    #pragma unroll
    for (int kc = 0; kc < 2; ++kc)
      #pragma unroll
      for (int m = 0; m < 4; ++m)
        #pragma unroll
        for (int n = 0; n < 4; ++n)
          acc[m][n] = __builtin_amdgcn_mfma_f32_16x16x32_bf16(
              a[m][kc], b[n][kc], acc[m][n], 0, 0, 0);
  }
  #pragma unroll
  for (int mi = 0; mi < 4; ++mi) {
    #pragma unroll
    for (int nj = 0; nj < 4; ++nj) {
      const int col = wc * 64 + nj * 16 + rl;
      #pragma unroll
      for (int r = 0; r < 4; ++r) {
        const int row = r0 + wr * 64 + mi * 16 + kq * 4 + r;
        const __bf16 v = (__bf16)acc[mi][nj][r];
        if (z == 2) {
          Vo[(size_t)row * Dc + h * HDc + col] = v;
        } else {
          const int s = row & 1023, bb = row >> 10;
          __bf16* dst = (z == 0) ? Qo : Ko;
          dst[((size_t)(h * Sc + s) * Bc + bb) * HDc + col] = v;
        }
      }
    }
  }
}

// ---------------------------------------------------------------------------
// Transpose-cast V + fused per-128-t-tile column sums (replaces k_vsum):
// Vt[(b*16+h)][e][t] = VB[b][t][h*128+e]; TP[bh][t0/128][e] += sum_t V.
__global__ __launch_bounds__(256) void k_vt(const __bf16* __restrict__ VB,
                                            __bf16* __restrict__ Vt,
                                            float* __restrict__ TP) {
  __shared__ float tl[32][33];
  __shared__ float rs[8][32];
  const int bh = blockIdx.z, bb = bh >> 4, h = bh & 15;
  const int t0 = blockIdx.x * 32, e0 = blockIdx.y * 32;
  const int tid = threadIdx.x;
  const int lx = tid & 31, ly = tid >> 5;
  float ps = 0.f;
  #pragma unroll
  for (int r = 0; r < 32; r += 8) {
    const float v =
        (float)VB[(size_t)(bb * Sc + t0 + ly + r) * Dc + h * HDc + e0 + lx];
    tl[ly + r][lx] = v;
    ps += v;
  }
  rs[ly][lx] = ps;
  __syncthreads();
  #pragma unroll
  for (int r = 0; r < 32; r += 8)
    Vt[((size_t)bh * HDc + e0 + ly + r) * Sc + t0 + lx] = (__bf16)tl[lx][ly + r];
  if (ly == 0) {
    float s = ((rs[0][lx] + rs[1][lx]) + (rs[2][lx] + rs[3][lx])) +
              ((rs[4][lx] + rs[5][lx]) + (rs[6][lx] + rs[7][lx]));
    atomicAdd(&TP[((size_t)bh * 8 + (t0 >> 7)) * HDc + e0 + lx], s);
  }
}

// ---------------------------------------------------------------------------
// Stage 2: suffix-scan tiles -> SufV[bh][j][e] = sum_{t >= 128*j} V[b,t,h,e].
__global__ __launch_bounds__(128) void k_vscan(const float* __restrict__ T,
                                               float* __restrict__ SufV) {
  const int bh = blockIdx.x;
  const int e = threadIdx.x;
  float acc = 0.f;
  SufV[((size_t)bh * 9 + 8) * HDc + e] = 0.f;
  for (int jj = 7; jj >= 1; --jj) {
    acc += T[((size_t)bh * 8 + jj) * HDc + e];
    SufV[((size_t)bh * 9 + jj) * HDc + e] = acc;
  }
}

// ---------------------------------------------------------------------------
// SS via shared loop: A[h][s][t] = clamp(|ct[t]*pn[s]*(Q·K^T)/sqrt(128)|,1)
// for t<=s. Grid (8,8,16) with bx>by early-exit — R6's triangle-compact grid
// measurably regressed (+6 µs); padded grid's dispatch pattern is faster.
__global__ __launch_bounds__(256, 2) void k_ssm(const __bf16* __restrict__ Q,
                                                const __bf16* __restrict__ Kb,
                                                const float* __restrict__ ct,
                                                const float* __restrict__ pn,
                                                __bf16* __restrict__ A) {
  const int bx = blockIdx.x, by = blockIdx.y;
  if (bx > by) return;               // strictly-upper tile: skip entirely
  extern __shared__ __bf16 lds[];
  __bf16* As = lds;
  __bf16* Bs = lds + 3 * ABUFE;
  const int h = blockIdx.z;
  const int t0 = bx * 128, s0 = by * 128;
  const int tid = threadIdx.x;
  __bf16* Ah = A + (size_t)h * Sc * Sc;
  const int wave = tid >> 6, lane = tid & 63;
  f32x4 acc[4][4] = {{}};
  mfma_loop128<KQKc, KQKc>(Q + (size_t)(h * Sc + s0) * KQKc,
                           Kb + (size_t)(h * Sc + t0) * KQKc, KQKc / 64, As,
                           Bs, wave, lane, acc);
  const int wr = wave >> 1, wc = wave & 1;
  const int rl = lane & 15, kq = lane >> 4;
  const float rs = 0.088388347648318447f;  // 1/sqrt(128)
  #pragma unroll
  for (int mi = 0; mi < 4; ++mi) {
    #pragma unroll
    for (int nj = 0; nj < 4; ++nj) {
      const int t = t0 + wc * 64 + nj * 16 + rl;
      const float ctv = ct[h * Sc + t] * rs;
      #pragma unroll
      for (int r = 0; r < 4; ++r) {
        const int s = s0 + wr * 64 + mi * 16 + kq * 4 + r;
        float v = 1.0f;
        if (t <= s) v = fmaxf(fabsf(ctv * pn[h * Sc + s] * acc[mi][nj][r]), 1.0f);
        Ah[(size_t)s * Sc + t] = (__bf16)v;
      }
    }
  }
}

// ---------------------------------------------------------------------------
// O = A @ V via shared loop, triangular; all-ones region added as fp32 SufV.
// Grid (4, 1, 64): each block processes the COMPLEMENTARY itile pair
// {bx, 7-bx} -> exactly 18 K-tiles per block (deterministic load balance).
// Epilogue also accumulates GroupNorm stats (sum, sumsq per token row) into
// STAT via 16-lane shfl reduce + 2 atomics per row per wave.
__global__ __launch_bounds__(256, 2) void k_avm(const __bf16* __restrict__ A,
                                                const __bf16* __restrict__ Vt,
                                                const float* __restrict__ SufV,
                                                float* __restrict__ O,
                                                float* __restrict__ STAT) {
  extern __shared__ __bf16 lds[];
  __bf16* As = lds;
  __bf16* Bs = lds + 3 * ABUFE;
  const int bh = blockIdx.z, bb = bh >> 4, h = bh & 15;
  const int tid = threadIdx.x;
  const int wave = tid >> 6, lane = tid & 63;
  const int wr = wave >> 1, wc = wave & 1;
  const int rl = lane & 15, kq = lane >> 4;
  for (int half = 0; half < 2; ++half) {
    const int itile = half ? 7 - (int)blockIdx.x : (int)blockIdx.x;
    const int s0 = itile * 128;
    f32x4 acc[4][4] = {{}};
    mfma_loop128<Sc, Sc>(A + (size_t)(h * Sc + s0) * Sc,
                         Vt + (size_t)bh * HDc * Sc, (itile + 1) * 2, As, Bs,
                         wave, lane, acc);
    const float* sufr = SufV + ((size_t)bh * 9 + (itile + 1)) * HDc;
    #pragma unroll
    for (int mi = 0; mi < 4; ++mi) {
      #pragma unroll
      for (int r = 0; r < 4; ++r) {
        const int s = s0 + wr * 64 + mi * 16 + kq * 4 + r;
        const size_t orow = (size_t)(bb * Sc + s);
        float vs = 0.f, vq = 0.f;
        #pragma unroll
        for (int nj = 0; nj < 4; ++nj) {
          const int e = wc * 64 + nj * 16 + rl;
          const float v = acc[mi][nj][r] + sufr[e];
          O[orow * Dc + h * HDc + e] = v;
          vs += v;
          vq += v * v;
        }
        #pragma unroll
        for (int m = 1; m < 16; m <<= 1) {
          vs += __shfl_xor(vs, m);
          vq += __shfl_xor(vq, m);
        }
        if (rl == 0) {
          atomicAdd(&STAT[orow * 2], vs);
          atomicAdd(&STAT[orow * 2 + 1], vq);
        }
      }
    }
  }
}

// ---------------------------------------------------------------------------
// bf16 MFMA GEMM via shared loop: C = A @ Bt^T. M=4096, N=2048, K=2048
// (NTK=32). Grid 16(N) x 32(M) = 512 WGs = 2/CU. XCD-chunked swizzle.
// mode 0: Gout = bf16(relu(acc) * groupnorm(Y; STAT, gw, bw))  (gnorm fused:
//         mu/var from STAT one-pass; O is near zero-mean per row so
//         E[x^2]-mu^2 cancellation is negligible).
// mode 1: Fout = acc (fp32).
__global__ __launch_bounds__(256, 2) void k_mgemm(const __bf16* __restrict__ Ab,
                                                  const __bf16* __restrict__ Bt,
                                                  const float* __restrict__ Y,
                                                  const float* __restrict__ gw,
                                                  const float* __restrict__ bw,
                                                  const float* __restrict__ STAT,
                                                  __bf16* __restrict__ Gout,
                                                  float* __restrict__ Fout,
                                                  int mode) {
  extern __shared__ __bf16 lds[];
  __bf16* As = lds;
  __bf16* Bs = lds + 3 * ABUFE;
  // XCD-chunked swizzle: 512 WGs, 64 consecutive work-ids per XCD ->
  // each XCD owns 4 adjacent A-panels (4 x 0.5MB) x full B sweep.
  int wid = blockIdx.y * gridDim.x + blockIdx.x;
  wid = (wid & 7) * 64 + (wid >> 3);
  const int r0 = (wid >> 4) * 128;    // M block (32)
  const int c0 = (wid & 15) * 128;    // N block (16)
  const int tid = threadIdx.x;
  const int wave = tid >> 6, lane = tid & 63;
  f32x4 acc[4][4] = {{}};
  mfma_loop128<Dc, Dc>(Ab + (size_t)r0 * Dc, Bt + (size_t)c0 * Dc, Dc / 64,
                       As, Bs, wave, lane, acc);
  const int wr = wave >> 1, wc = wave & 1;
  const int rl = lane & 15, kq = lane >> 4;
  if (mode == 0) {
    #pragma unroll
    for (int mi = 0; mi < 4; ++mi) {
      #pragma unroll
      for (int r = 0; r < 4; ++r) {
        const int row = r0 + wr * 64 + mi * 16 + kq * 4 + r;
        const float mu = STAT[(size_t)row * 2] * (1.0f / Dc);
        const float va = STAT[(size_t)row * 2 + 1] * (1.0f / Dc) - mu * mu;
        const float inv = rsqrtf(va + GN_EPS);
        #pragma unroll
        for (int nj = 0; nj < 4; ++nj) {
          const int col = c0 + wc * 64 + nj * 16 + rl;
          const size_t idx = (size_t)row * Dc + col;
          const float yv = (Y[idx] - mu) * inv * gw[col] + bw[col];
          Gout[idx] = (__bf16)(fmaxf(acc[mi][nj][r], 0.f) * yv);
        }
      }
    }
  } else {
    #pragma unroll
    for (int mi = 0; mi < 4; ++mi) {
      #pragma unroll
      for (int nj = 0; nj < 4; ++nj) {
        const int col = c0 + wc * 64 + nj * 16 + rl;
        #pragma unroll
        for (int r = 0; r < 4; ++r) {
          const int row = r0 + wr * 64 + mi * 16 + kq * 4 + r;
          Fout[(size_t)row * Dc + col] = acc[mi][nj][r];
        }
      }
    }
  }
}

// ---------------------------------------------------------------------------
extern "C" void kernel_launch(void* const* d_in, const int* in_sizes, int n_in,
                              void* d_out, int out_size, void* d_ws, size_t ws_size,
                              hipStream_t stream) {
  const float* x  = (const float*)d_in[0];
  const float* k  = (const float*)d_in[1];
  const float* v  = (const float*)d_in[2];
  const float* Wh = (const float*)d_in[3];
  const float* wg = (const float*)d_in[4];
  const float* wo = (const float*)d_in[5];
  const float* gg = (const float*)d_in[6];
  const float* gb = (const float*)d_in[7];
  float* ws = (float*)d_ws;
  __bf16* Q   = (__bf16*)(ws + OFF_Q);
  __bf16* Kp  = (__bf16*)(ws + OFF_K);
  __bf16* VB  = (__bf16*)(ws + OFF_VB);
  __bf16* Vt  = (__bf16*)(ws + OFF_VT);
  __bf16* A   = (__bf16*)(ws + OFF_A);
  float*  O   = ws + OFF_O;
  float*  CT  = ws + OFF_CT;
  float*  PN  = ws + OFF_PN;
  __bf16* XB  = (__bf16*)(ws + OFF_XB);
  __bf16* WGT = (__bf16*)(ws + OFF_WGT);
  __bf16* WOT = (__bf16*)(ws + OFF_WOT);
  float*  SUF = ws + OFF_SUF;
  float*  TP  = ws + OFF_T;
  __bf16* WHT = (__bf16*)(ws + OFF_WHT);
  float*  STAT= ws + OFF_STAT;
  __bf16* KB2 = (__bf16*)(ws + OFF_KB2);  // aliases A (dead until k_ssm)
  __bf16* VB2 = (__bf16*)(ws + OFF_VB2);  // aliases A second half
  __bf16* G   = (__bf16*)(ws + OFF_Q);    // reuse Q region (dead after k_ssm)

  // one-time opt-in for dynamic LDS (host-side, graph-capture safe)
  static bool attr_done = false;
  if (!attr_done) {
    (void)hipFuncSetAttribute((const void*)k_mgemm,
                              hipFuncAttributeMaxDynamicSharedMemorySize,
                              MG_LDS);
    (void)hipFuncSetAttribute((const void*)k_projm,
                              hipFuncAttributeMaxDynamicSharedMemorySize,
                              PJ_LDS);
    (void)hipFuncSetAttribute((const void*)k_ssm,
                              hipFuncAttributeMaxDynamicSharedMemorySize,
                              MG_LDS);
    (void)hipFuncSetAttribute((const void*)k_avm,
                              hipFuncAttributeMaxDynamicSharedMemorySize,
                              MG_LDS);
    attr_done = true;
  }

  k_tables<<<Hc * Sc / 256, 256, 0, stream>>>(CT, PN, TP, STAT);
  k_cast83<<<dim3((BSc * Dc) / (256 * 8), 3), 256, 0, stream>>>(
      x, k, v, XB, KB2, VB2);
  k_castT2<<<dim3(Dc / 32, Dc / 32, 2), 256, 0, stream>>>(wg, wo, WGT, WOT);
  k_whT<<<dim3(4, 4, Hc), 256, 0, stream>>>(Wh, WHT);
  k_projm<<<dim3(BSc / 128, Hc, 3), 256, PJ_LDS, stream>>>(XB, KB2, VB2, WHT,
                                                           Q, Kp, VB);
  k_vt<<<dim3(Sc / 32, HDc / 32, Bc * Hc), 256, 0, stream>>>(VB, Vt, TP);
  k_vscan<<<Bc * Hc, 128, 0, stream>>>(TP, SUF);
  k_ssm<<<dim3(Sc / 128, Sc / 128, Hc), 256, MG_LDS, stream>>>(Q, Kp, CT, PN,
                                                               A);
  k_avm<<<dim3(4, 1, Bc * Hc), 256, MG_LDS, stream>>>(A, Vt, SUF, O, STAT);
  k_mgemm<<<dim3(16, 32), 256, MG_LDS, stream>>>(XB, WGT, O, gg, gb, STAT, G,
                                                 nullptr, 0);
  k_mgemm<<<dim3(16, 32), 256, MG_LDS, stream>>>(G, WOT, nullptr, nullptr,
                                                 nullptr, nullptr, nullptr,
                                                 (float*)d_out, 1);
}

// Round 9
// 356.404 us; speedup vs baseline: 1.0651x; 1.0108x over previous
//
#include <hip/hip_runtime.h>
#include <math.h>

// Problem constants
constexpr int Bc = 4, Sc = 1024, Dc = 2048, HDc = 128, Hc = 16;
constexpr int BSc = Bc * Sc;        // 4096 token rows
constexpr int KQKc = Bc * HDc;      // 512 = batch-concat K dim for SS GEMM
#define GN_EPS 1e-3f

typedef __bf16 bf16x8 __attribute__((ext_vector_type(8)));
typedef __bf16 bf16x4 __attribute__((ext_vector_type(4)));
typedef float f32x4 __attribute__((ext_vector_type(4)));

// Workspace layout (float units)
constexpr size_t OFF_Q   = 0;                                  // bf16 [H][S][512]
constexpr size_t OFF_K   = OFF_Q + (size_t)Hc * Sc * KQKc / 2; // bf16 same
constexpr size_t OFF_VB  = OFF_K + (size_t)Hc * Sc * KQKc / 2; // bf16 [BS][D]
constexpr size_t OFF_VT  = OFF_VB + (size_t)BSc * Dc / 2;      // bf16 [BH][128][1024]
constexpr size_t OFF_A   = OFF_VT + (size_t)BSc * Dc / 2;      // bf16 [H][S][S]
constexpr size_t OFF_O   = OFF_A + (size_t)Hc * Sc * Sc / 2;   // fp32 [BS][D]
constexpr size_t OFF_CT  = OFF_O + (size_t)BSc * Dc;           // [H][S]
constexpr size_t OFF_PN  = OFF_CT + (size_t)Hc * Sc;           // [H][S]
constexpr size_t OFF_XB  = OFF_PN + (size_t)Hc * Sc;           // bf16 [BS][D]
constexpr size_t OFF_WGT = OFF_XB + (size_t)BSc * Dc / 2;      // bf16 [D][D] T
constexpr size_t OFF_WOT = OFF_WGT + (size_t)Dc * Dc / 2;      // bf16 [D][D] T
constexpr size_t OFF_SUF = OFF_WOT + (size_t)Dc * Dc / 2;      // fp32 [64][9][128]
constexpr size_t OFF_T   = OFF_SUF + (size_t)64 * 9 * HDc;     // fp32 [64][8][128]
constexpr size_t OFF_WHT = OFF_T + (size_t)64 * 8 * HDc;       // bf16 [H][128][128]
constexpr size_t OFF_STAT= OFF_WHT + (size_t)Hc * HDc * HDc / 2; // fp32 [BS][2]
// KB2 / VB2 (bf16 casts of raw k, v) alias the A region (dead until k_ssm).
// G (bf16 [BS][D]) reuses the Q buffer (dead after k_ssm).
constexpr size_t OFF_KB2 = OFF_A;
constexpr size_t OFF_VB2 = OFF_A + (size_t)BSc * Dc / 2;

#define GLOAD_LDS16(gp, lp)                                               \
  __builtin_amdgcn_global_load_lds(                                       \
      (const __attribute__((address_space(1))) void*)(gp),                \
      (__attribute__((address_space(3))) void*)(lp), 16, 0, 0)

// Swizzled staging: lane l stages row l>>2 (4 lanes/row -> one 64B segment,
// coalesced) at k-chunk c = (l&3) ^ key(row), key(r) = (r>>1)&3. LDS layout:
// (r,c) at chunkbase + r*32 + (c^key(r))*8 elems. Fragment read (rl,kq) ->
// 16B unit rl*4 + (kq^key(rl)): all 64 distinct, 8-lane groups hit 8 distinct
// bank quads -> conflict-free ds_read_b128 AND coalesced global fetch.

// ---------------------------------------------------------------------------
// Shared relaxed-sync 128x128 MFMA K-loop (session-verified in R3/R4).
// 256 threads, 4 waves (2M x 2N), per-wave 64x64, BK=64.
// LDS: A triple-buffered (3 x 16KB, staged 2 tiles ahead) + B double-buffered
// (2 x 16KB, staged 1 ahead) = 80 KiB -> 2 WGs/CU.
// Per K-tile: all 16 ds_reads up-front (a01,b01,a23,b23), stage B(t+1) +
// A(t+2), 4 MFMA groups gated by compiler counted lgkmcnt; close with
// lgkmcnt(0) + counted vmcnt(4) + ONE s_barrier. Requires ntk >= 2.
constexpr int ABUFE = 128 * 64;       // elems per A buffer (16 KB)
constexpr int BBUFE = 128 * 64;       // elems per B buffer (16 KB)
constexpr int MG_LDS = (3 * ABUFE + 2 * BBUFE) * 2;  // 81920 B
constexpr int PJ_LDS = 4 * 8192 * 2;                 // 65536 B (k_projm)

template <int ASTR, int BSTR>
__device__ __forceinline__ void mfma_loop128(const __bf16* __restrict__ Abase,
                                             const __bf16* __restrict__ Bbase,
                                             const int ntk,
                                             __bf16* As, __bf16* Bs,
                                             const int wave, const int lane,
                                             f32x4 acc[4][4]) {
  const int wr = wave >> 1, wc = wave & 1;          // 2(M) x 2(N) waves
  const int lr = lane >> 2;                         // staging row in chunk
  const int lkx = ((lane & 3) ^ ((lane >> 3) & 3)) * 8;  // staging k offset
  const int rl = lane & 15, kq = lane >> 4;         // frag row / k-quarter
  const int swo = rl * 32 + ((kq ^ ((rl >> 1) & 3)) * 8);

  // stage: one 16-row x 32-k chunk per wave per call; ci = i*4 + wave.
#define SA_(i, kt, bsel) do {                                               \
    const int ci_ = (i) * 4 + wave;                                         \
    GLOAD_LDS16(Abase + (size_t)((ci_ >> 1) * 16 + lr) * ASTR               \
                    + (kt) * 64 + (ci_ & 1) * 32 + lkx,                     \
                As + (bsel) * ABUFE + ci_ * 512);                           \
  } while (0)
#define SB_(j, kt, bsel) do {                                               \
    const int ci_ = (j) * 4 + wave;                                         \
    GLOAD_LDS16(Bbase + (size_t)((ci_ >> 1) * 16 + lr) * BSTR               \
                    + (kt) * 64 + (ci_ & 1) * 32 + lkx,                     \
                Bs + (bsel) * BBUFE + ci_ * 512);                           \
  } while (0)

  // Prologue: A(0), B(0), A(1) = 12 loads (B(1) staged inside tile 0).
  SA_(0, 0, 0); SA_(1, 0, 0); SA_(2, 0, 0); SA_(3, 0, 0);
  SB_(0, 0, 0); SB_(1, 0, 0); SB_(2, 0, 0); SB_(3, 0, 0);
  SA_(0, 1, 1); SA_(1, 1, 1); SA_(2, 1, 1); SA_(3, 1, 1);
  __builtin_amdgcn_sched_barrier(0);
  asm volatile("s_waitcnt vmcnt(4)" ::: "memory");  // A(0)+B(0) landed
  __builtin_amdgcn_sched_barrier(0);
  __builtin_amdgcn_s_barrier();

  int cbA = 0;                         // A buffer holding tile t
  for (int t = 0; t < ntk; ++t) {
    const int sbA = (cbA + 2 >= 3) ? cbA - 1 : cbA + 2;  // (cbA+2)%3
    const __bf16* Ac = As + cbA * ABUFE;
    const __bf16* Bc = Bs + (t & 1) * BBUFE;
    bf16x8 a[4][2], b[4][2];
    // --- issue all 16 ds_reads, order a01, b01, a23, b23 ---
    #pragma unroll
    for (int m = 0; m < 2; ++m)
      #pragma unroll
      for (int kc = 0; kc < 2; ++kc)
        a[m][kc] = *(const bf16x8*)&Ac[((wr * 4 + m) * 2 + kc) * 512 + swo];
    #pragma unroll
    for (int n = 0; n < 2; ++n)
      #pragma unroll
      for (int kc = 0; kc < 2; ++kc)
        b[n][kc] = *(const bf16x8*)&Bc[((wc * 4 + n) * 2 + kc) * 512 + swo];
    #pragma unroll
    for (int m = 2; m < 4; ++m)
      #pragma unroll
      for (int kc = 0; kc < 2; ++kc)
        a[m][kc] = *(const bf16x8*)&Ac[((wr * 4 + m) * 2 + kc) * 512 + swo];
    #pragma unroll
    for (int n = 2; n < 4; ++n)
      #pragma unroll
      for (int kc = 0; kc < 2; ++kc)
        b[n][kc] = *(const bf16x8*)&Bc[((wc * 4 + n) * 2 + kc) * 512 + swo];
    // --- issue staging: B for t+1, A for t+2 (order matters for vmcnt) ---
    if (t + 1 < ntk) {
      SB_(0, t + 1, (t + 1) & 1); SB_(1, t + 1, (t + 1) & 1);
      SB_(2, t + 1, (t + 1) & 1); SB_(3, t + 1, (t + 1) & 1);
    }
    if (t + 2 < ntk) {
      SA_(0, t + 2, sbA); SA_(1, t + 2, sbA);
      SA_(2, t + 2, sbA); SA_(3, t + 2, sbA);
    }
    __builtin_amdgcn_sched_barrier(0);
    // --- G1: m01 x n01 (compiler counted lgkmcnt gates on a01,b01) ---
    __builtin_amdgcn_s_setprio(1);
    #pragma unroll
    for (int kc = 0; kc < 2; ++kc)
      #pragma unroll
      for (int m = 0; m < 2; ++m)
        #pragma unroll
        for (int n = 0; n < 2; ++n)
          acc[m][n] = __builtin_amdgcn_mfma_f32_16x16x32_bf16(
              a[m][kc], b[n][kc], acc[m][n], 0, 0, 0);
    __builtin_amdgcn_s_setprio(0);
    __builtin_amdgcn_sched_barrier(0);
    // --- G2: m23 x n01 ---
    __builtin_amdgcn_s_setprio(1);
    #pragma unroll
    for (int kc = 0; kc < 2; ++kc)
      #pragma unroll
      for (int m = 2; m < 4; ++m)
        #pragma unroll
        for (int n = 0; n < 2; ++n)
          acc[m][n] = __builtin_amdgcn_mfma_f32_16x16x32_bf16(
              a[m][kc], b[n][kc], acc[m][n], 0, 0, 0);
    __builtin_amdgcn_s_setprio(0);
    __builtin_amdgcn_sched_barrier(0);
    // --- G3: m01 x n23 ---
    __builtin_amdgcn_s_setprio(1);
    #pragma unroll
    for (int kc = 0; kc < 2; ++kc)
      #pragma unroll
      for (int m = 0; m < 2; ++m)
        #pragma unroll
        for (int n = 2; n < 4; ++n)
          acc[m][n] = __builtin_amdgcn_mfma_f32_16x16x32_bf16(
              a[m][kc], b[n][kc], acc[m][n], 0, 0, 0);
    __builtin_amdgcn_s_setprio(0);
    __builtin_amdgcn_sched_barrier(0);
    // --- G4: m23 x n23 ---
    __builtin_amdgcn_s_setprio(1);
    #pragma unroll
    for (int kc = 0; kc < 2; ++kc)
      #pragma unroll
      for (int m = 2; m < 4; ++m)
        #pragma unroll
        for (int n = 2; n < 4; ++n)
          acc[m][n] = __builtin_amdgcn_mfma_f32_16x16x32_bf16(
              a[m][kc], b[n][kc], acc[m][n], 0, 0, 0);
    __builtin_amdgcn_s_setprio(0);
    __builtin_amdgcn_sched_barrier(0);
    // --- tile close: drain my reads (free by now), prove t+1 staged, bar ---
    asm volatile("s_waitcnt lgkmcnt(0)" ::: "memory");
    __builtin_amdgcn_sched_barrier(0);
    if (t + 2 < ntk)                   // newest 4 = SA(t+2); SB(t+1) retired
      asm volatile("s_waitcnt vmcnt(4)" ::: "memory");
    else if (t + 1 < ntk)              // tail: drain SB(t+1)
      asm volatile("s_waitcnt vmcnt(0)" ::: "memory");
    __builtin_amdgcn_sched_barrier(0);
    __builtin_amdgcn_s_barrier();
    cbA = (cbA + 1 >= 3) ? 0 : cbA + 1;
  }
#undef SA_
#undef SB_
}

// ---------------------------------------------------------------------------
// Decay tables + zero the TP / STAT accumulators (inside the graph, so each
// replay re-zeroes before k_vt / k_avm atomics).
__global__ __launch_bounds__(256) void k_tables(float* __restrict__ ct,
                                                float* __restrict__ pn,
                                                float* __restrict__ TP,
                                                float* __restrict__ STAT) {
  int idx = blockIdx.x * 256 + threadIdx.x;   // 0 .. H*S-1 (16384)
  int h = idx >> 10, t = idx & 1023;
  double gamma = 1.0 - exp2(-(double)(5 + h));
  double l2g = log2(gamma);
  double r = 1.0 / gamma;
  double rowsum = (exp2(-(double)(t + 1) * l2g) - 1.0) / (r - 1.0);
  ct[idx] = (float)(exp2((double)t * l2g) / sqrt(rowsum));
  pn[idx] = (float)exp2(-(double)t * l2g);
  float4 z4 = {0.f, 0.f, 0.f, 0.f};
  *(float4*)(TP + (size_t)idx * 4) = z4;      // 16384*4 = 65536 floats
  if (idx < BSc * 2) STAT[idx] = 0.f;         // 8192 floats
}

// ---------------------------------------------------------------------------
// fp32 -> bf16 cast, 8 elems/thread; grid.y selects which tensor (fused 3x).
__global__ __launch_bounds__(256) void k_cast83(const float* __restrict__ s0,
                                                const float* __restrict__ s1,
                                                const float* __restrict__ s2,
                                                __bf16* __restrict__ d0,
                                                __bf16* __restrict__ d1,
                                                __bf16* __restrict__ d2) {
  const int y = blockIdx.y;
  const float* src = (y == 0) ? s0 : (y == 1) ? s1 : s2;
  __bf16* dst = (y == 0) ? d0 : (y == 1) ? d1 : d2;
  size_t i = ((size_t)blockIdx.x * 256 + threadIdx.x) * 8;
  float4 a = *(const float4*)(src + i);
  float4 b = *(const float4*)(src + i + 4);
  bf16x8 o;
  o[0] = (__bf16)a.x; o[1] = (__bf16)a.y; o[2] = (__bf16)a.z; o[3] = (__bf16)a.w;
  o[4] = (__bf16)b.x; o[5] = (__bf16)b.y; o[6] = (__bf16)b.z; o[7] = (__bf16)b.w;
  *(bf16x8*)(dst + i) = o;
}

// ---------------------------------------------------------------------------
// Transpose-cast x2: dst[n][k] = (bf16) src[k][n], 2048x2048; z selects wg/wo.
__global__ __launch_bounds__(256) void k_castT2(const float* __restrict__ s0,
                                                const float* __restrict__ s1,
                                                __bf16* __restrict__ d0,
                                                __bf16* __restrict__ d1) {
  __shared__ float t[32][33];
  const int bx = blockIdx.x, by = blockIdx.y;
  const float* src = blockIdx.z ? s1 : s0;
  __bf16* dst = blockIdx.z ? d1 : d0;
  const int tid = threadIdx.x;
  const int lx = tid & 31, ly = tid >> 5;   // 32 x 8
  #pragma unroll
  for (int r = 0; r < 32; r += 8)
    t[ly + r][lx] = src[(size_t)(by * 32 + ly + r) * Dc + bx * 32 + lx];
  __syncthreads();
  #pragma unroll
  for (int r = 0; r < 32; r += 8)
    dst[(size_t)(bx * 32 + ly + r) * Dc + by * 32 + lx] = (__bf16)t[lx][ly + r];
}

// ---------------------------------------------------------------------------
// Per-head transpose-cast of Wh: WhT[h][e][d] = (bf16) Wh[h][d][e].
__global__ __launch_bounds__(256) void k_whT(const float* __restrict__ Wh,
                                             __bf16* __restrict__ WhT) {
  __shared__ float t[32][33];
  const int h = blockIdx.z;
  const int d0 = blockIdx.x * 32, e0 = blockIdx.y * 32;
  const int tid = threadIdx.x;
  const int lx = tid & 31, ly = tid >> 5;
  #pragma unroll
  for (int r = 0; r < 32; r += 8)
    t[ly + r][lx] = Wh[(size_t)h * HDc * HDc + (d0 + ly + r) * HDc + e0 + lx];
  __syncthreads();
  #pragma unroll
  for (int r = 0; r < 32; r += 8)
    WhT[(size_t)h * HDc * HDc + (e0 + ly + r) * HDc + d0 + lx] =
        (__bf16)t[lx][ly + r];
}

// ---------------------------------------------------------------------------
// MFMA projections, SINGLE-STAGE (K=128 fits in LDS; the pipelined loop at
// NTK=2 was pure prologue overhead). Stage X-panel (32 KB) + W-panel (32 KB)
// once (16 gloads/wave), one vmcnt(0) + one barrier, 128 MFMA/wave straight
// through with compiler counted lgkmcnt. 64 KiB LDS -> 2 WGs/CU; 1536 blocks
// stream 6 rounds/CU, co-resident WG hides the load latency.
// z=0: Xb -> Q layout [h][s][b*HD]; z=1: Kb2 -> K layout; z=2: Vb2 -> Vp.
__global__ __launch_bounds__(256, 2) void k_projm(const __bf16* __restrict__ Xb,
                                                  const __bf16* __restrict__ Kb2,
                                                  const __bf16* __restrict__ Vb2,
                                                  const __bf16* __restrict__ WhT,
                                                  __bf16* __restrict__ Qo,
                                                  __bf16* __restrict__ Ko,
                                                  __bf16* __restrict__ Vo) {
  extern __shared__ __bf16 lds[];
  __bf16* Xs = lds;                    // 2 x 8192 (kt-major)
  __bf16* Ws = lds + 2 * 8192;         // 2 x 8192
  const int r0 = blockIdx.x * 128;
  const int h = blockIdx.y;
  const int z = blockIdx.z;
  const __bf16* src = (z == 0) ? Xb : (z == 1) ? Kb2 : Vb2;
  const __bf16* wsrc = WhT + (size_t)h * HDc * HDc;
  const int tid = threadIdx.x;
  const int wave = tid >> 6, lane = tid & 63;
  const int wr = wave >> 1, wc = wave & 1;
  const int lr = lane >> 2;
  const int lkx = ((lane & 3) ^ ((lane >> 3) & 3)) * 8;
  const int rl = lane & 15, kq = lane >> 4;
  const int swo = rl * 32 + ((kq ^ ((rl >> 1) & 3)) * 8);
  // stage both K-halves of both operands (same chunk swizzle as the loop)
  #pragma unroll
  for (int kt = 0; kt < 2; ++kt) {
    #pragma unroll
    for (int i = 0; i < 4; ++i) {
      const int ci = i * 4 + wave;
      const int row = (ci >> 1) * 16 + lr;
      const int ko = kt * 64 + (ci & 1) * 32 + lkx;
      GLOAD_LDS16(src + (size_t)(r0 + row) * Dc + h * HDc + ko,
                  Xs + kt * 8192 + ci * 512);
      GLOAD_LDS16(wsrc + (size_t)row * HDc + ko, Ws + kt * 8192 + ci * 512);
    }
  }
  __builtin_amdgcn_sched_barrier(0);
  asm volatile("s_waitcnt vmcnt(0)" ::: "memory");
  __builtin_amdgcn_sched_barrier(0);
  __builtin_amdgcn_s_barrier();
  f32x4 acc[4][4] = {{}};
  #pragma unroll
  for (int kt = 0; kt < 2; ++kt) {
    bf16x8 a[4][2], b[4][2];
    #pragma unroll
    for (int m = 0; m < 4; ++m)
      #pragma unroll
      for (int kc = 0; kc < 2; ++kc)
        a[m][kc] =
            *(const bf16x8*)&Xs[kt * 8192 + ((wr * 4 + m) * 2 + kc) * 512 + swo];
    #pragma unroll
    for (int n = 0; n < 4; ++n)
      #pragma unroll
      for (int kc = 0; kc < 2; ++kc)
        b[n][kc] =
            *(const bf16x8*)&Ws[kt * 8192 + ((wc * 4 + n) * 2 + kc) * 512 + swo];
    #pragma unroll
    for (int kc = 0; kc < 2; ++kc)
      #pragma unroll
      for (int m = 0; m < 4; ++m)
        #pragma unroll
        for (int n = 0; n < 4; ++n)
          acc[m][n] = __builtin_amdgcn_mfma_f32_16x16x32_bf16(
              a[m][kc], b[n][kc], acc[m][n], 0, 0, 0);
  }
  #pragma unroll
  for (int mi = 0; mi < 4; ++mi) {
    #pragma unroll
    for (int nj = 0; nj < 4; ++nj) {
      const int col = wc * 64 + nj * 16 + rl;
      #pragma unroll
      for (int r = 0; r < 4; ++r) {
        const int row = r0 + wr * 64 + mi * 16 + kq * 4 + r;
        const __bf16 v = (__bf16)acc[mi][nj][r];
        if (z == 2) {
          Vo[(size_t)row * Dc + h * HDc + col] = v;
        } else {
          const int s = row & 1023, bb = row >> 10;
          __bf16* dst = (z == 0) ? Qo : Ko;
          dst[((size_t)(h * Sc + s) * Bc + bb) * HDc + col] = v;
        }
      }
    }
  }
}

// ---------------------------------------------------------------------------
// Transpose-cast V + fused per-128-t-tile column sums (replaces k_vsum):
// Vt[(b*16+h)][e][t] = VB[b][t][h*128+e]; TP[bh][t0/128][e] += sum_t V.
__global__ __launch_bounds__(256) void k_vt(const __bf16* __restrict__ VB,
                                            __bf16* __restrict__ Vt,
                                            float* __restrict__ TP) {
  __shared__ float tl[32][33];
  __shared__ float rs[8][32];
  const int bh = blockIdx.z, bb = bh >> 4, h = bh & 15;
  const int t0 = blockIdx.x * 32, e0 = blockIdx.y * 32;
  const int tid = threadIdx.x;
  const int lx = tid & 31, ly = tid >> 5;
  float ps = 0.f;
  #pragma unroll
  for (int r = 0; r < 32; r += 8) {
    const float v =
        (float)VB[(size_t)(bb * Sc + t0 + ly + r) * Dc + h * HDc + e0 + lx];
    tl[ly + r][lx] = v;
    ps += v;
  }
  rs[ly][lx] = ps;
  __syncthreads();
  #pragma unroll
  for (int r = 0; r < 32; r += 8)
    Vt[((size_t)bh * HDc + e0 + ly + r) * Sc + t0 + lx] = (__bf16)tl[lx][ly + r];
  if (ly == 0) {
    float s = ((rs[0][lx] + rs[1][lx]) + (rs[2][lx] + rs[3][lx])) +
              ((rs[4][lx] + rs[5][lx]) + (rs[6][lx] + rs[7][lx]));
    atomicAdd(&TP[((size_t)bh * 8 + (t0 >> 7)) * HDc + e0 + lx], s);
  }
}

// ---------------------------------------------------------------------------
// Stage 2: suffix-scan tiles -> SufV[bh][j][e] = sum_{t >= 128*j} V[b,t,h,e].
__global__ __launch_bounds__(128) void k_vscan(const float* __restrict__ T,
                                               float* __restrict__ SufV) {
  const int bh = blockIdx.x;
  const int e = threadIdx.x;
  float acc = 0.f;
  SufV[((size_t)bh * 9 + 8) * HDc + e] = 0.f;
  for (int jj = 7; jj >= 1; --jj) {
    acc += T[((size_t)bh * 8 + jj) * HDc + e];
    SufV[((size_t)bh * 9 + jj) * HDc + e] = acc;
  }
}

// ---------------------------------------------------------------------------
// SS via shared loop: A[h][s][t] = clamp(|ct[t]*pn[s]*(Q·K^T)/sqrt(128)|,1)
// for t<=s. Grid (8,8,16) with bx>by early-exit — R6's triangle-compact grid
// measurably regressed (+6 µs); padded grid's dispatch pattern is faster.
__global__ __launch_bounds__(256, 2) void k_ssm(const __bf16* __restrict__ Q,
                                                const __bf16* __restrict__ Kb,
                                                const float* __restrict__ ct,
                                                const float* __restrict__ pn,
                                                __bf16* __restrict__ A) {
  const int bx = blockIdx.x, by = blockIdx.y;
  if (bx > by) return;               // strictly-upper tile: skip entirely
  extern __shared__ __bf16 lds[];
  __bf16* As = lds;
  __bf16* Bs = lds + 3 * ABUFE;
  const int h = blockIdx.z;
  const int t0 = bx * 128, s0 = by * 128;
  const int tid = threadIdx.x;
  __bf16* Ah = A + (size_t)h * Sc * Sc;
  const int wave = tid >> 6, lane = tid & 63;
  f32x4 acc[4][4] = {{}};
  mfma_loop128<KQKc, KQKc>(Q + (size_t)(h * Sc + s0) * KQKc,
                           Kb + (size_t)(h * Sc + t0) * KQKc, KQKc / 64, As,
                           Bs, wave, lane, acc);
  const int wr = wave >> 1, wc = wave & 1;
  const int rl = lane & 15, kq = lane >> 4;
  const float rs = 0.088388347648318447f;  // 1/sqrt(128)
  #pragma unroll
  for (int mi = 0; mi < 4; ++mi) {
    #pragma unroll
    for (int nj = 0; nj < 4; ++nj) {
      const int t = t0 + wc * 64 + nj * 16 + rl;
      const float ctv = ct[h * Sc + t] * rs;
      #pragma unroll
      for (int r = 0; r < 4; ++r) {
        const int s = s0 + wr * 64 + mi * 16 + kq * 4 + r;
        float v = 1.0f;
        if (t <= s) v = fmaxf(fabsf(ctv * pn[h * Sc + s] * acc[mi][nj][r]), 1.0f);
        Ah[(size_t)s * Sc + t] = (__bf16)v;
      }
    }
  }
}

// ---------------------------------------------------------------------------
// O = A @ V via shared loop, triangular; all-ones region added as fp32 SufV.
// Grid (8,1,64) = 512 blocks = 2 WGs/CU (R5's 256-block pairing collapsed
// occupancy to 1 WG/CU -> every vmcnt/barrier drain exposed, 8.3% occ, 6.9%
// MfmaUtil measured R7). lid-remap keeps deterministic balance: lids 0..255
// take itile = slot&3 (1..4 K-tiles), lids 256..511 take 7-(slot&3) (5..8);
// under round-robin fill CU c holds lids c and c+256 -> 9 K-tiles/CU AND
// both WGs co-resident (each fills the other's drains).
// Epilogue also accumulates GroupNorm stats (sum, sumsq per token row) into
// STAT via 16-lane shfl reduce + 2 atomics per row per wave.
__global__ __launch_bounds__(256, 2) void k_avm(const __bf16* __restrict__ A,
                                                const __bf16* __restrict__ Vt,
                                                const float* __restrict__ SufV,
                                                float* __restrict__ O,
                                                float* __restrict__ STAT) {
  extern __shared__ __bf16 lds[];
  __bf16* As = lds;
  __bf16* Bs = lds + 3 * ABUFE;
  const int lid = (int)blockIdx.z * 8 + (int)blockIdx.x;  // 0..511, x fastest
  const int slot = lid & 255;
  const int bh = slot >> 2;                                // 0..63
  const int itile = (lid < 256) ? (slot & 3) : 7 - (slot & 3);
  const int bb = bh >> 4, h = bh & 15;
  const int s0 = itile * 128;
  const int tid = threadIdx.x;
  const int wave = tid >> 6, lane = tid & 63;
  const int wr = wave >> 1, wc = wave & 1;
  const int rl = lane & 15, kq = lane >> 4;
  f32x4 acc[4][4] = {{}};
  mfma_loop128<Sc, Sc>(A + (size_t)(h * Sc + s0) * Sc,
                       Vt + (size_t)bh * HDc * Sc, (itile + 1) * 2, As, Bs,
                       wave, lane, acc);
  const float* sufr = SufV + ((size_t)bh * 9 + (itile + 1)) * HDc;
  #pragma unroll
  for (int mi = 0; mi < 4; ++mi) {
    #pragma unroll
    for (int r = 0; r < 4; ++r) {
      const int s = s0 + wr * 64 + mi * 16 + kq * 4 + r;
      const size_t orow = (size_t)(bb * Sc + s);
      float vs = 0.f, vq = 0.f;
      #pragma unroll
      for (int nj = 0; nj < 4; ++nj) {
        const int e = wc * 64 + nj * 16 + rl;
        const float v = acc[mi][nj][r] + sufr[e];
        O[orow * Dc + h * HDc + e] = v;
        vs += v;
        vq += v * v;
      }
      #pragma unroll
      for (int m = 1; m < 16; m <<= 1) {
        vs += __shfl_xor(vs, m);
        vq += __shfl_xor(vq, m);
      }
      if (rl == 0) {
        atomicAdd(&STAT[orow * 2], vs);
        atomicAdd(&STAT[orow * 2 + 1], vq);
      }
    }
  }
}

// ---------------------------------------------------------------------------
// bf16 MFMA GEMM via shared loop: C = A @ Bt^T. M=4096, N=2048, K=2048
// (NTK=32). Grid 16(N) x 32(M) = 512 WGs = 2/CU. XCD-chunked swizzle.
// mode 0: Gout = bf16(relu(acc) * groupnorm(Y; STAT, gw, bw))  (gnorm fused:
//         mu/var from STAT one-pass; O is near zero-mean per row so
//         E[x^2]-mu^2 cancellation is negligible).
// mode 1: Fout = acc (fp32).
__global__ __launch_bounds__(256, 2) void k_mgemm(const __bf16* __restrict__ Ab,
                                                  const __bf16* __restrict__ Bt,
                                                  const float* __restrict__ Y,
                                                  const float* __restrict__ gw,
                                                  const float* __restrict__ bw,
                                                  const float* __restrict__ STAT,
                                                  __bf16* __restrict__ Gout,
                                                  float* __restrict__ Fout,
                                                  int mode) {
  extern __shared__ __bf16 lds[];
  __bf16* As = lds;
  __bf16* Bs = lds + 3 * ABUFE;
  // XCD-chunked swizzle: 512 WGs, 64 consecutive work-ids per XCD ->
  // each XCD owns 4 adjacent A-panels (4 x 0.5MB) x full B sweep.
  int wid = blockIdx.y * gridDim.x + blockIdx.x;
  wid = (wid & 7) * 64 + (wid >> 3);
  const int r0 = (wid >> 4) * 128;    // M block (32)
  const int c0 = (wid & 15) * 128;    // N block (16)
  const int tid = threadIdx.x;
  const int wave = tid >> 6, lane = tid & 63;
  f32x4 acc[4][4] = {{}};
  mfma_loop128<Dc, Dc>(Ab + (size_t)r0 * Dc, Bt + (size_t)c0 * Dc, Dc / 64,
                       As, Bs, wave, lane, acc);
  const int wr = wave >> 1, wc = wave & 1;
  const int rl = lane & 15, kq = lane >> 4;
  if (mode == 0) {
    #pragma unroll
    for (int mi = 0; mi < 4; ++mi) {
      #pragma unroll
      for (int r = 0; r < 4; ++r) {
        const int row = r0 + wr * 64 + mi * 16 + kq * 4 + r;
        const float mu = STAT[(size_t)row * 2] * (1.0f / Dc);
        const float va = STAT[(size_t)row * 2 + 1] * (1.0f / Dc) - mu * mu;
        const float inv = rsqrtf(va + GN_EPS);
        #pragma unroll
        for (int nj = 0; nj < 4; ++nj) {
          const int col = c0 + wc * 64 + nj * 16 + rl;
          const size_t idx = (size_t)row * Dc + col;
          const float yv = (Y[idx] - mu) * inv * gw[col] + bw[col];
          Gout[idx] = (__bf16)(fmaxf(acc[mi][nj][r], 0.f) * yv);
        }
      }
    }
  } else {
    #pragma unroll
    for (int mi = 0; mi < 4; ++mi) {
      #pragma unroll
      for (int nj = 0; nj < 4; ++nj) {
        const int col = c0 + wc * 64 + nj * 16 + rl;
        #pragma unroll
        for (int r = 0; r < 4; ++r) {
          const int row = r0 + wr * 64 + mi * 16 + kq * 4 + r;
          Fout[(size_t)row * Dc + col] = acc[mi][nj][r];
        }
      }
    }
  }
}

// ---------------------------------------------------------------------------
extern "C" void kernel_launch(void* const* d_in, const int* in_sizes, int n_in,
                              void* d_out, int out_size, void* d_ws, size_t ws_size,
                              hipStream_t stream) {
  const float* x  = (const float*)d_in[0];
  const float* k  = (const float*)d_in[1];
  const float* v  = (const float*)d_in[2];
  const float* Wh = (const float*)d_in[3];
  const float* wg = (const float*)d_in[4];
  const float* wo = (const float*)d_in[5];
  const float* gg = (const float*)d_in[6];
  const float* gb = (const float*)d_in[7];
  float* ws = (float*)d_ws;
  __bf16* Q   = (__bf16*)(ws + OFF_Q);
  __bf16* Kp  = (__bf16*)(ws + OFF_K);
  __bf16* VB  = (__bf16*)(ws + OFF_VB);
  __bf16* Vt  = (__bf16*)(ws + OFF_VT);
  __bf16* A   = (__bf16*)(ws + OFF_A);
  float*  O   = ws + OFF_O;
  float*  CT  = ws + OFF_CT;
  float*  PN  = ws + OFF_PN;
  __bf16* XB  = (__bf16*)(ws + OFF_XB);
  __bf16* WGT = (__bf16*)(ws + OFF_WGT);
  __bf16* WOT = (__bf16*)(ws + OFF_WOT);
  float*  SUF = ws + OFF_SUF;
  float*  TP  = ws + OFF_T;
  __bf16* WHT = (__bf16*)(ws + OFF_WHT);
  float*  STAT= ws + OFF_STAT;
  __bf16* KB2 = (__bf16*)(ws + OFF_KB2);  // aliases A (dead until k_ssm)
  __bf16* VB2 = (__bf16*)(ws + OFF_VB2);  // aliases A second half
  __bf16* G   = (__bf16*)(ws + OFF_Q);    // reuse Q region (dead after k_ssm)

  // one-time opt-in for dynamic LDS (host-side, graph-capture safe)
  static bool attr_done = false;
  if (!attr_done) {
    (void)hipFuncSetAttribute((const void*)k_mgemm,
                              hipFuncAttributeMaxDynamicSharedMemorySize,
                              MG_LDS);
    (void)hipFuncSetAttribute((const void*)k_projm,
                              hipFuncAttributeMaxDynamicSharedMemorySize,
                              PJ_LDS);
    (void)hipFuncSetAttribute((const void*)k_ssm,
                              hipFuncAttributeMaxDynamicSharedMemorySize,
                              MG_LDS);
    (void)hipFuncSetAttribute((const void*)k_avm,
                              hipFuncAttributeMaxDynamicSharedMemorySize,
                              MG_LDS);
    attr_done = true;
  }

  k_tables<<<Hc * Sc / 256, 256, 0, stream>>>(CT, PN, TP, STAT);
  k_cast83<<<dim3((BSc * Dc) / (256 * 8), 3), 256, 0, stream>>>(
      x, k, v, XB, KB2, VB2);
  k_castT2<<<dim3(Dc / 32, Dc / 32, 2), 256, 0, stream>>>(wg, wo, WGT, WOT);
  k_whT<<<dim3(4, 4, Hc), 256, 0, stream>>>(Wh, WHT);
  k_projm<<<dim3(BSc / 128, Hc, 3), 256, PJ_LDS, stream>>>(XB, KB2, VB2, WHT,
                                                           Q, Kp, VB);
  k_vt<<<dim3(Sc / 32, HDc / 32, Bc * Hc), 256, 0, stream>>>(VB, Vt, TP);
  k_vscan<<<Bc * Hc, 128, 0, stream>>>(TP, SUF);
  k_ssm<<<dim3(Sc / 128, Sc / 128, Hc), 256, MG_LDS, stream>>>(Q, Kp, CT, PN,
                                                               A);
  k_avm<<<dim3(8, 1, Bc * Hc), 256, MG_LDS, stream>>>(A, Vt, SUF, O, STAT);
  k_mgemm<<<dim3(16, 32), 256, MG_LDS, stream>>>(XB, WGT, O, gg, gb, STAT, G,
                                                 nullptr, 0);
  k_mgemm<<<dim3(16, 32), 256, MG_LDS, stream>>>(G, WOT, nullptr, nullptr,
                                                 nullptr, nullptr, nullptr,
                                                 (float*)d_out, 1);
}

// Round 10
// 348.504 us; speedup vs baseline: 1.0892x; 1.0227x over previous
//
#include <hip/hip_runtime.h>
#include <math.h>

// Problem constants
constexpr int Bc = 4, Sc = 1024, Dc = 2048, HDc = 128, Hc = 16;
constexpr int BSc = Bc * Sc;        // 4096 token rows
constexpr int KQKc = Bc * HDc;      // 512 = batch-concat K dim for SS GEMM
#define GN_EPS 1e-3f

typedef __bf16 bf16x8 __attribute__((ext_vector_type(8)));
typedef __bf16 bf16x4 __attribute__((ext_vector_type(4)));
typedef float f32x4 __attribute__((ext_vector_type(4)));

// Workspace layout (float units)
constexpr size_t OFF_Q   = 0;                                  // bf16 [H][S][512]
constexpr size_t OFF_K   = OFF_Q + (size_t)Hc * Sc * KQKc / 2; // bf16 same
constexpr size_t OFF_VB  = OFF_K + (size_t)Hc * Sc * KQKc / 2; // bf16 [BS][D]
constexpr size_t OFF_VT  = OFF_VB + (size_t)BSc * Dc / 2;      // bf16 [BH][128][1024]
constexpr size_t OFF_A   = OFF_VT + (size_t)BSc * Dc / 2;      // bf16 [H][S][S]
constexpr size_t OFF_O   = OFF_A + (size_t)Hc * Sc * Sc / 2;   // fp32 [BS][D]
constexpr size_t OFF_CT  = OFF_O + (size_t)BSc * Dc;           // [H][S]
constexpr size_t OFF_PN  = OFF_CT + (size_t)Hc * Sc;           // [H][S]
constexpr size_t OFF_XB  = OFF_PN + (size_t)Hc * Sc;           // bf16 [BS][D]
constexpr size_t OFF_WGT = OFF_XB + (size_t)BSc * Dc / 2;      // bf16 [D][D] T
constexpr size_t OFF_WOT = OFF_WGT + (size_t)Dc * Dc / 2;      // bf16 [D][D] T
constexpr size_t OFF_SUF = OFF_WOT + (size_t)Dc * Dc / 2;      // fp32 [64][9][128]
constexpr size_t OFF_T   = OFF_SUF + (size_t)64 * 9 * HDc;     // fp32 [64][8][128]
constexpr size_t OFF_WHT = OFF_T + (size_t)64 * 8 * HDc;       // bf16 [H][128][128]
constexpr size_t OFF_STAT= OFF_WHT + (size_t)Hc * HDc * HDc / 2; // fp32 [BS][2]
// KB2 / VB2 (bf16 casts of raw k, v) alias the A region (dead until k_ssm).
// G (bf16 [BS][D]) reuses the Q buffer (dead after k_ssm).
constexpr size_t OFF_KB2 = OFF_A;
constexpr size_t OFF_VB2 = OFF_A + (size_t)BSc * Dc / 2;

#define GLOAD_LDS16(gp, lp)                                               \
  __builtin_amdgcn_global_load_lds(                                       \
      (const __attribute__((address_space(1))) void*)(gp),                \
      (__attribute__((address_space(3))) void*)(lp), 16, 0, 0)

// Swizzled staging: lane l stages row l>>2 (4 lanes/row -> one 64B segment,
// coalesced) at k-chunk c = (l&3) ^ key(row), key(r) = (r>>1)&3. LDS layout:
// (r,c) at chunkbase + r*32 + (c^key(r))*8 elems. Fragment read (rl,kq) ->
// 16B unit rl*4 + (kq^key(rl)): all 64 distinct, 8-lane groups hit 8 distinct
// bank quads -> conflict-free ds_read_b128 AND coalesced global fetch.

// ---------------------------------------------------------------------------
// Shared relaxed-sync 128xN MFMA K-loop (session-verified R3/R4; NF templates
// the B-fragment count: NF=4 -> N=128 tile, NF=2 -> N=64 half-tile for ssm
// load balancing). 256 threads, 4 waves (2M x 2N), per-wave 64 x 16*NF, BK=64.
// LDS: A triple-buffered (staged 2 tiles ahead) + B double-buffered (1 ahead)
// = 80 KiB -> 2 WGs/CU.
// Per K-tile: all ds_reads up-front, stage B(t+1) (NF loads) + A(t+2) (4),
// 4 MFMA groups gated by compiler counted lgkmcnt; close with lgkmcnt(0) +
// counted vmcnt(4) (A's 4 loads are always the newest; B's NF retire) +
// ONE s_barrier. Requires ntk >= 2.
constexpr int ABUFE = 128 * 64;       // elems per A buffer (16 KB)
constexpr int BBUFE = 128 * 64;       // elems per B buffer (16 KB; NF=2 uses half)
constexpr int MG_LDS = (3 * ABUFE + 2 * BBUFE) * 2;  // 81920 B
constexpr int PJ_LDS = 4 * 8192 * 2;                 // 65536 B (k_projm)

template <int ASTR, int BSTR, int NF = 4>
__device__ __forceinline__ void mfma_loop128(const __bf16* __restrict__ Abase,
                                             const __bf16* __restrict__ Bbase,
                                             const int ntk,
                                             __bf16* As, __bf16* Bs,
                                             const int wave, const int lane,
                                             f32x4 acc[4][4]) {
  constexpr int NH = NF / 2;                        // n per group
  const int wr = wave >> 1, wc = wave & 1;          // 2(M) x 2(N) waves
  const int lr = lane >> 2;                         // staging row in chunk
  const int lkx = ((lane & 3) ^ ((lane >> 3) & 3)) * 8;  // staging k offset
  const int rl = lane & 15, kq = lane >> 4;         // frag row / k-quarter
  const int swo = rl * 32 + ((kq ^ ((rl >> 1) & 3)) * 8);

  // stage: one 16-row x 32-k chunk per wave per call; ci = i*4 + wave.
#define SA_(i, kt, bsel) do {                                               \
    const int ci_ = (i) * 4 + wave;                                         \
    GLOAD_LDS16(Abase + (size_t)((ci_ >> 1) * 16 + lr) * ASTR               \
                    + (kt) * 64 + (ci_ & 1) * 32 + lkx,                     \
                As + (bsel) * ABUFE + ci_ * 512);                           \
  } while (0)
#define SB_(j, kt, bsel) do {                                               \
    const int ci_ = (j) * 4 + wave;                                         \
    GLOAD_LDS16(Bbase + (size_t)((ci_ >> 1) * 16 + lr) * BSTR               \
                    + (kt) * 64 + (ci_ & 1) * 32 + lkx,                     \
                Bs + (bsel) * BBUFE + ci_ * 512);                           \
  } while (0)

  // Prologue: A(0), B(0), A(1)  (B(1) staged inside tile 0).
  SA_(0, 0, 0); SA_(1, 0, 0); SA_(2, 0, 0); SA_(3, 0, 0);
  #pragma unroll
  for (int j = 0; j < NF; ++j) SB_(j, 0, 0);
  SA_(0, 1, 1); SA_(1, 1, 1); SA_(2, 1, 1); SA_(3, 1, 1);
  __builtin_amdgcn_sched_barrier(0);
  asm volatile("s_waitcnt vmcnt(4)" ::: "memory");  // A(0)+B(0) landed
  __builtin_amdgcn_sched_barrier(0);
  __builtin_amdgcn_s_barrier();

  int cbA = 0;                         // A buffer holding tile t
  for (int t = 0; t < ntk; ++t) {
    const int sbA = (cbA + 2 >= 3) ? cbA - 1 : cbA + 2;  // (cbA+2)%3
    const __bf16* Ac = As + cbA * ABUFE;
    const __bf16* Bc = Bs + (t & 1) * BBUFE;
    bf16x8 a[4][2], b[NF][2];
    // --- issue all ds_reads, order a01, b-lo, a23, b-hi ---
    #pragma unroll
    for (int m = 0; m < 2; ++m)
      #pragma unroll
      for (int kc = 0; kc < 2; ++kc)
        a[m][kc] = *(const bf16x8*)&Ac[((wr * 4 + m) * 2 + kc) * 512 + swo];
    #pragma unroll
    for (int n = 0; n < NH; ++n)
      #pragma unroll
      for (int kc = 0; kc < 2; ++kc)
        b[n][kc] = *(const bf16x8*)&Bc[((wc * NF + n) * 2 + kc) * 512 + swo];
    #pragma unroll
    for (int m = 2; m < 4; ++m)
      #pragma unroll
      for (int kc = 0; kc < 2; ++kc)
        a[m][kc] = *(const bf16x8*)&Ac[((wr * 4 + m) * 2 + kc) * 512 + swo];
    #pragma unroll
    for (int n = NH; n < NF; ++n)
      #pragma unroll
      for (int kc = 0; kc < 2; ++kc)
        b[n][kc] = *(const bf16x8*)&Bc[((wc * NF + n) * 2 + kc) * 512 + swo];
    // --- issue staging: B for t+1, A for t+2 (order matters for vmcnt) ---
    if (t + 1 < ntk) {
      #pragma unroll
      for (int j = 0; j < NF; ++j) SB_(j, t + 1, (t + 1) & 1);
    }
    if (t + 2 < ntk) {
      SA_(0, t + 2, sbA); SA_(1, t + 2, sbA);
      SA_(2, t + 2, sbA); SA_(3, t + 2, sbA);
    }
    __builtin_amdgcn_sched_barrier(0);
    // --- G1: m01 x n-lo (compiler counted lgkmcnt gates) ---
    __builtin_amdgcn_s_setprio(1);
    #pragma unroll
    for (int kc = 0; kc < 2; ++kc)
      #pragma unroll
      for (int m = 0; m < 2; ++m)
        #pragma unroll
        for (int n = 0; n < NH; ++n)
          acc[m][n] = __builtin_amdgcn_mfma_f32_16x16x32_bf16(
              a[m][kc], b[n][kc], acc[m][n], 0, 0, 0);
    __builtin_amdgcn_s_setprio(0);
    __builtin_amdgcn_sched_barrier(0);
    // --- G2: m23 x n-lo ---
    __builtin_amdgcn_s_setprio(1);
    #pragma unroll
    for (int kc = 0; kc < 2; ++kc)
      #pragma unroll
      for (int m = 2; m < 4; ++m)
        #pragma unroll
        for (int n = 0; n < NH; ++n)
          acc[m][n] = __builtin_amdgcn_mfma_f32_16x16x32_bf16(
              a[m][kc], b[n][kc], acc[m][n], 0, 0, 0);
    __builtin_amdgcn_s_setprio(0);
    __builtin_amdgcn_sched_barrier(0);
    // --- G3: m01 x n-hi ---
    __builtin_amdgcn_s_setprio(1);
    #pragma unroll
    for (int kc = 0; kc < 2; ++kc)
      #pragma unroll
      for (int m = 0; m < 2; ++m)
        #pragma unroll
        for (int n = NH; n < NF; ++n)
          acc[m][n] = __builtin_amdgcn_mfma_f32_16x16x32_bf16(
              a[m][kc], b[n][kc], acc[m][n], 0, 0, 0);
    __builtin_amdgcn_s_setprio(0);
    __builtin_amdgcn_sched_barrier(0);
    // --- G4: m23 x n-hi ---
    __builtin_amdgcn_s_setprio(1);
    #pragma unroll
    for (int kc = 0; kc < 2; ++kc)
      #pragma unroll
      for (int m = 2; m < 4; ++m)
        #pragma unroll
        for (int n = NH; n < NF; ++n)
          acc[m][n] = __builtin_amdgcn_mfma_f32_16x16x32_bf16(
              a[m][kc], b[n][kc], acc[m][n], 0, 0, 0);
    __builtin_amdgcn_s_setprio(0);
    __builtin_amdgcn_sched_barrier(0);
    // --- tile close: drain my reads (free by now), prove t+1 staged, bar ---
    asm volatile("s_waitcnt lgkmcnt(0)" ::: "memory");
    __builtin_amdgcn_sched_barrier(0);
    if (t + 2 < ntk)                   // newest 4 = SA(t+2); SB(t+1) retired
      asm volatile("s_waitcnt vmcnt(4)" ::: "memory");
    else if (t + 1 < ntk)              // tail: drain SB(t+1)
      asm volatile("s_waitcnt vmcnt(0)" ::: "memory");
    __builtin_amdgcn_sched_barrier(0);
    __builtin_amdgcn_s_barrier();
    cbA = (cbA + 1 >= 3) ? 0 : cbA + 1;
  }
#undef SA_
#undef SB_
}

// ---------------------------------------------------------------------------
// Decay tables + zero the TP / STAT accumulators (inside the graph, so each
// replay re-zeroes before k_vt / k_avm atomics).
__global__ __launch_bounds__(256) void k_tables(float* __restrict__ ct,
                                                float* __restrict__ pn,
                                                float* __restrict__ TP,
                                                float* __restrict__ STAT) {
  int idx = blockIdx.x * 256 + threadIdx.x;   // 0 .. H*S-1 (16384)
  int h = idx >> 10, t = idx & 1023;
  double gamma = 1.0 - exp2(-(double)(5 + h));
  double l2g = log2(gamma);
  double r = 1.0 / gamma;
  double rowsum = (exp2(-(double)(t + 1) * l2g) - 1.0) / (r - 1.0);
  ct[idx] = (float)(exp2((double)t * l2g) / sqrt(rowsum));
  pn[idx] = (float)exp2(-(double)t * l2g);
  float4 z4 = {0.f, 0.f, 0.f, 0.f};
  *(float4*)(TP + (size_t)idx * 4) = z4;      // 16384*4 = 65536 floats
  if (idx < BSc * 2) STAT[idx] = 0.f;         // 8192 floats
}

// ---------------------------------------------------------------------------
// fp32 -> bf16 cast, 8 elems/thread; grid.y selects which tensor (fused 3x).
__global__ __launch_bounds__(256) void k_cast83(const float* __restrict__ s0,
                                                const float* __restrict__ s1,
                                                const float* __restrict__ s2,
                                                __bf16* __restrict__ d0,
                                                __bf16* __restrict__ d1,
                                                __bf16* __restrict__ d2) {
  const int y = blockIdx.y;
  const float* src = (y == 0) ? s0 : (y == 1) ? s1 : s2;
  __bf16* dst = (y == 0) ? d0 : (y == 1) ? d1 : d2;
  size_t i = ((size_t)blockIdx.x * 256 + threadIdx.x) * 8;
  float4 a = *(const float4*)(src + i);
  float4 b = *(const float4*)(src + i + 4);
  bf16x8 o;
  o[0] = (__bf16)a.x; o[1] = (__bf16)a.y; o[2] = (__bf16)a.z; o[3] = (__bf16)a.w;
  o[4] = (__bf16)b.x; o[5] = (__bf16)b.y; o[6] = (__bf16)b.z; o[7] = (__bf16)b.w;
  *(bf16x8*)(dst + i) = o;
}

// ---------------------------------------------------------------------------
// Transpose-cast x2: dst[n][k] = (bf16) src[k][n], 2048x2048; z selects wg/wo.
__global__ __launch_bounds__(256) void k_castT2(const float* __restrict__ s0,
                                                const float* __restrict__ s1,
                                                __bf16* __restrict__ d0,
                                                __bf16* __restrict__ d1) {
  __shared__ float t[32][33];
  const int bx = blockIdx.x, by = blockIdx.y;
  const float* src = blockIdx.z ? s1 : s0;
  __bf16* dst = blockIdx.z ? d1 : d0;
  const int tid = threadIdx.x;
  const int lx = tid & 31, ly = tid >> 5;   // 32 x 8
  #pragma unroll
  for (int r = 0; r < 32; r += 8)
    t[ly + r][lx] = src[(size_t)(by * 32 + ly + r) * Dc + bx * 32 + lx];
  __syncthreads();
  #pragma unroll
  for (int r = 0; r < 32; r += 8)
    dst[(size_t)(bx * 32 + ly + r) * Dc + by * 32 + lx] = (__bf16)t[lx][ly + r];
}

// ---------------------------------------------------------------------------
// Per-head transpose-cast of Wh: WhT[h][e][d] = (bf16) Wh[h][d][e].
__global__ __launch_bounds__(256) void k_whT(const float* __restrict__ Wh,
                                             __bf16* __restrict__ WhT) {
  __shared__ float t[32][33];
  const int h = blockIdx.z;
  const int d0 = blockIdx.x * 32, e0 = blockIdx.y * 32;
  const int tid = threadIdx.x;
  const int lx = tid & 31, ly = tid >> 5;
  #pragma unroll
  for (int r = 0; r < 32; r += 8)
    t[ly + r][lx] = Wh[(size_t)h * HDc * HDc + (d0 + ly + r) * HDc + e0 + lx];
  __syncthreads();
  #pragma unroll
  for (int r = 0; r < 32; r += 8)
    WhT[(size_t)h * HDc * HDc + (e0 + ly + r) * HDc + d0 + lx] =
        (__bf16)t[lx][ly + r];
}

// ---------------------------------------------------------------------------
// MFMA projections, SINGLE-STAGE (K=128 fits in LDS; the pipelined loop at
// NTK=2 was pure prologue overhead). Stage X-panel (32 KB) + W-panel (32 KB)
// once (16 gloads/wave), one vmcnt(0) + one barrier, 128 MFMA/wave straight
// through with compiler counted lgkmcnt. 64 KiB LDS -> 2 WGs/CU; 1536 blocks
// stream 6 rounds/CU, co-resident WG hides the load latency.
// z=0: Xb -> Q layout [h][s][b*HD]; z=1: Kb2 -> K layout; z=2: Vb2 -> Vp.
__global__ __launch_bounds__(256, 2) void k_projm(const __bf16* __restrict__ Xb,
                                                  const __bf16* __restrict__ Kb2,
                                                  const __bf16* __restrict__ Vb2,
                                                  const __bf16* __restrict__ WhT,
                                                  __bf16* __restrict__ Qo,
                                                  __bf16* __restrict__ Ko,
                                                  __bf16* __restrict__ Vo) {
  extern __shared__ __bf16 lds[];
  __bf16* Xs = lds;                    // 2 x 8192 (kt-major)
  __bf16* Ws = lds + 2 * 8192;         // 2 x 8192
  const int r0 = blockIdx.x * 128;
  const int h = blockIdx.y;
  const int z = blockIdx.z;
  const __bf16* src = (z == 0) ? Xb : (z == 1) ? Kb2 : Vb2;
  const __bf16* wsrc = WhT + (size_t)h * HDc * HDc;
  const int tid = threadIdx.x;
  const int wave = tid >> 6, lane = tid & 63;
  const int wr = wave >> 1, wc = wave & 1;
  const int lr = lane >> 2;
  const int lkx = ((lane & 3) ^ ((lane >> 3) & 3)) * 8;
  const int rl = lane & 15, kq = lane >> 4;
  const int swo = rl * 32 + ((kq ^ ((rl >> 1) & 3)) * 8);
  // stage both K-halves of both operands (same chunk swizzle as the loop)
  #pragma unroll
  for (int kt = 0; kt < 2; ++kt) {
    #pragma unroll
    for (int i = 0; i < 4; ++i) {
      const int ci = i * 4 + wave;
      const int row = (ci >> 1) * 16 + lr;
      const int ko = kt * 64 + (ci & 1) * 32 + lkx;
      GLOAD_LDS16(src + (size_t)(r0 + row) * Dc + h * HDc + ko,
                  Xs + kt * 8192 + ci * 512);
      GLOAD_LDS16(wsrc + (size_t)row * HDc + ko, Ws + kt * 8192 + ci * 512);
    }
  }
  __builtin_amdgcn_sched_barrier(0);
  asm volatile("s_waitcnt vmcnt(0)" ::: "memory");
  __builtin_amdgcn_sched_barrier(0);
  __builtin_amdgcn_s_barrier();
  f32x4 acc[4][4] = {{}};
  #pragma unroll
  for (int kt = 0; kt < 2; ++kt) {
    bf16x8 a[4][2], b[4][2];
    #pragma unroll
    for (int m = 0; m < 4; ++m)
      #pragma unroll
      for (int kc = 0; kc < 2; ++kc)
        a[m][kc] =
            *(const bf16x8*)&Xs[kt * 8192 + ((wr * 4 + m) * 2 + kc) * 512 + swo];
    #pragma unroll
    for (int n = 0; n < 4; ++n)
      #pragma unroll
      for (int kc = 0; kc < 2; ++kc)
        b[n][kc] =
            *(const bf16x8*)&Ws[kt * 8192 + ((wc * 4 + n) * 2 + kc) * 512 + swo];
    #pragma unroll
    for (int kc = 0; kc < 2; ++kc)
      #pragma unroll
      for (int m = 0; m < 4; ++m)
        #pragma unroll
        for (int n = 0; n < 4; ++n)
          acc[m][n] = __builtin_amdgcn_mfma_f32_16x16x32_bf16(
              a[m][kc], b[n][kc], acc[m][n], 0, 0, 0);
  }
  #pragma unroll
  for (int mi = 0; mi < 4; ++mi) {
    #pragma unroll
    for (int nj = 0; nj < 4; ++nj) {
      const int col = wc * 64 + nj * 16 + rl;
      #pragma unroll
      for (int r = 0; r < 4; ++r) {
        const int row = r0 + wr * 64 + mi * 16 + kq * 4 + r;
        const __bf16 v = (__bf16)acc[mi][nj][r];
        if (z == 2) {
          Vo[(size_t)row * Dc + h * HDc + col] = v;
        } else {
          const int s = row & 1023, bb = row >> 10;
          __bf16* dst = (z == 0) ? Qo : Ko;
          dst[((size_t)(h * Sc + s) * Bc + bb) * HDc + col] = v;
        }
      }
    }
  }
}

// ---------------------------------------------------------------------------
// Transpose-cast V + fused per-128-t-tile column sums (replaces k_vsum):
// Vt[(b*16+h)][e][t] = VB[b][t][h*128+e]; TP[bh][t0/128][e] += sum_t V.
__global__ __launch_bounds__(256) void k_vt(const __bf16* __restrict__ VB,
                                            __bf16* __restrict__ Vt,
                                            float* __restrict__ TP) {
  __shared__ float tl[32][33];
  __shared__ float rs[8][32];
  const int bh = blockIdx.z, bb = bh >> 4, h = bh & 15;
  const int t0 = blockIdx.x * 32, e0 = blockIdx.y * 32;
  const int tid = threadIdx.x;
  const int lx = tid & 31, ly = tid >> 5;
  float ps = 0.f;
  #pragma unroll
  for (int r = 0; r < 32; r += 8) {
    const float v =
        (float)VB[(size_t)(bb * Sc + t0 + ly + r) * Dc + h * HDc + e0 + lx];
    tl[ly + r][lx] = v;
    ps += v;
  }
  rs[ly][lx] = ps;
  __syncthreads();
  #pragma unroll
  for (int r = 0; r < 32; r += 8)
    Vt[((size_t)bh * HDc + e0 + ly + r) * Sc + t0 + lx] = (__bf16)tl[lx][ly + r];
  if (ly == 0) {
    float s = ((rs[0][lx] + rs[1][lx]) + (rs[2][lx] + rs[3][lx])) +
              ((rs[4][lx] + rs[5][lx]) + (rs[6][lx] + rs[7][lx]));
    atomicAdd(&TP[((size_t)bh * 8 + (t0 >> 7)) * HDc + e0 + lx], s);
  }
}

// ---------------------------------------------------------------------------
// Stage 2: suffix-scan tiles -> SufV[bh][j][e] = sum_{t >= 128*j} V[b,t,h,e].
__global__ __launch_bounds__(128) void k_vscan(const float* __restrict__ T,
                                               float* __restrict__ SufV) {
  const int bh = blockIdx.x;
  const int e = threadIdx.x;
  float acc = 0.f;
  SufV[((size_t)bh * 9 + 8) * HDc + e] = 0.f;
  for (int jj = 7; jj >= 1; --jj) {
    acc += T[((size_t)bh * 8 + jj) * HDc + e];
    SufV[((size_t)bh * 9 + jj) * HDc + e] = acc;
  }
}

// ---------------------------------------------------------------------------
// SS via shared loop (NF=2 half-tiles): A[h][s][t] =
// clamp(|ct[t]*pn[s]*(Q·K^T)/sqrt(128)|,1) for t<=s, 1.0 for t>s in-tile.
// Grid (8,9,16) = 1152 blocks, ONE 128(s)x64(t) half-tile each -> all 256 CUs
// active with 4-5 blocks (R7/R9 grid serialized 4 FULL tiles on 144 CUs and
// idled 112: blocks {c,c+256,..} shared (bx,by) so worker status was per-CU
// all-or-nothing; measured 9% occupancy, 7% MfmaUtil). Decode keeps
// id mod 8 == bx so each XCD still specializes in few K-panel columns.
//   by<8, bx<=by -> tile (r=by, c=bx) half 0
//   by<8, bx> by -> tile (r=bx, c=by) half 1   (mirror pairing)
//   by==8        -> diagonal tile (bx,bx) half 1
__global__ __launch_bounds__(256, 2) void k_ssm(const __bf16* __restrict__ Q,
                                                const __bf16* __restrict__ Kb,
                                                const float* __restrict__ ct,
                                                const float* __restrict__ pn,
                                                __bf16* __restrict__ A) {
  const int bx = blockIdx.x, by = blockIdx.y;
  int r, c, half;
  if (by == 8)       { r = bx; c = bx; half = 1; }
  else if (bx > by)  { r = bx; c = by; half = 1; }
  else               { r = by; c = bx; half = 0; }
  extern __shared__ __bf16 lds[];
  __bf16* As = lds;
  __bf16* Bs = lds + 3 * ABUFE;
  const int h = blockIdx.z;
  const int s0 = r * 128;
  const int t0 = c * 128 + half * 64;
  const int tid = threadIdx.x;
  __bf16* Ah = A + (size_t)h * Sc * Sc;
  const int wave = tid >> 6, lane = tid & 63;
  f32x4 acc[4][4] = {{}};
  mfma_loop128<KQKc, KQKc, 2>(Q + (size_t)(h * Sc + s0) * KQKc,
                              Kb + (size_t)(h * Sc + t0) * KQKc, KQKc / 64,
                              As, Bs, wave, lane, acc);
  const int wr = wave >> 1, wc = wave & 1;
  const int rl = lane & 15, kq = lane >> 4;
  const float rs = 0.088388347648318447f;  // 1/sqrt(128)
  #pragma unroll
  for (int mi = 0; mi < 4; ++mi) {
    #pragma unroll
    for (int nj = 0; nj < 2; ++nj) {
      const int t = t0 + wc * 32 + nj * 16 + rl;
      const float ctv = ct[h * Sc + t] * rs;
      #pragma unroll
      for (int rr = 0; rr < 4; ++rr) {
        const int s = s0 + wr * 64 + mi * 16 + kq * 4 + rr;
        float v = 1.0f;
        if (t <= s) v = fmaxf(fabsf(ctv * pn[h * Sc + s] * acc[mi][nj][rr]), 1.0f);
        Ah[(size_t)s * Sc + t] = (__bf16)v;
      }
    }
  }
}

// ---------------------------------------------------------------------------
// O = A @ V via shared loop, triangular; all-ones region added as fp32 SufV.
// Grid (8,1,64) = 512 blocks = 2 WGs/CU. lid-remap keeps deterministic
// balance: lids 0..255 take itile = slot&3 (1..4 K-tiles), lids 256..511 take
// 7-(slot&3) (5..8); under round-robin fill CU c holds lids c and c+256 ->
// 9 K-tiles/CU AND both WGs co-resident (each fills the other's drains).
// Epilogue also accumulates GroupNorm stats (sum, sumsq per token row) into
// STAT via 16-lane shfl reduce + 2 atomics per row per wave.
__global__ __launch_bounds__(256, 2) void k_avm(const __bf16* __restrict__ A,
                                                const __bf16* __restrict__ Vt,
                                                const float* __restrict__ SufV,
                                                float* __restrict__ O,
                                                float* __restrict__ STAT) {
  extern __shared__ __bf16 lds[];
  __bf16* As = lds;
  __bf16* Bs = lds + 3 * ABUFE;
  const int lid = (int)blockIdx.z * 8 + (int)blockIdx.x;  // 0..511, x fastest
  const int slot = lid & 255;
  const int bh = slot >> 2;                                // 0..63
  const int itile = (lid < 256) ? (slot & 3) : 7 - (slot & 3);
  const int bb = bh >> 4, h = bh & 15;
  const int s0 = itile * 128;
  const int tid = threadIdx.x;
  const int wave = tid >> 6, lane = tid & 63;
  const int wr = wave >> 1, wc = wave & 1;
  const int rl = lane & 15, kq = lane >> 4;
  f32x4 acc[4][4] = {{}};
  mfma_loop128<Sc, Sc>(A + (size_t)(h * Sc + s0) * Sc,
                       Vt + (size_t)bh * HDc * Sc, (itile + 1) * 2, As, Bs,
                       wave, lane, acc);
  const float* sufr = SufV + ((size_t)bh * 9 + (itile + 1)) * HDc;
  #pragma unroll
  for (int mi = 0; mi < 4; ++mi) {
    #pragma unroll
    for (int r = 0; r < 4; ++r) {
      const int s = s0 + wr * 64 + mi * 16 + kq * 4 + r;
      const size_t orow = (size_t)(bb * Sc + s);
      float vs = 0.f, vq = 0.f;
      #pragma unroll
      for (int nj = 0; nj < 4; ++nj) {
        const int e = wc * 64 + nj * 16 + rl;
        const float v = acc[mi][nj][r] + sufr[e];
        O[orow * Dc + h * HDc + e] = v;
        vs += v;
        vq += v * v;
      }
      #pragma unroll
      for (int m = 1; m < 16; m <<= 1) {
        vs += __shfl_xor(vs, m);
        vq += __shfl_xor(vq, m);
      }
      if (rl == 0) {
        atomicAdd(&STAT[orow * 2], vs);
        atomicAdd(&STAT[orow * 2 + 1], vq);
      }
    }
  }
}

// ---------------------------------------------------------------------------
// bf16 MFMA GEMM via shared loop: C = A @ Bt^T. M=4096, N=2048, K=2048
// (NTK=32). Grid 16(N) x 32(M) = 512 WGs = 2/CU. XCD-chunked swizzle.
// mode 0: Gout = bf16(relu(acc) * groupnorm(Y; STAT, gw, bw))  (gnorm fused:
//         mu/var from STAT one-pass; O is near zero-mean per row so
//         E[x^2]-mu^2 cancellation is negligible).
// mode 1: Fout = acc (fp32).
__global__ __launch_bounds__(256, 2) void k_mgemm(const __bf16* __restrict__ Ab,
                                                  const __bf16* __restrict__ Bt,
                                                  const float* __restrict__ Y,
                                                  const float* __restrict__ gw,
                                                  const float* __restrict__ bw,
                                                  const float* __restrict__ STAT,
                                                  __bf16* __restrict__ Gout,
                                                  float* __restrict__ Fout,
                                                  int mode) {
  extern __shared__ __bf16 lds[];
  __bf16* As = lds;
  __bf16* Bs = lds + 3 * ABUFE;
  // XCD-chunked swizzle: 512 WGs, 64 consecutive work-ids per XCD ->
  // each XCD owns 4 adjacent A-panels (4 x 0.5MB) x full B sweep.
  int wid = blockIdx.y * gridDim.x + blockIdx.x;
  wid = (wid & 7) * 64 + (wid >> 3);
  const int r0 = (wid >> 4) * 128;    // M block (32)
  const int c0 = (wid & 15) * 128;    // N block (16)
  const int tid = threadIdx.x;
  const int wave = tid >> 6, lane = tid & 63;
  f32x4 acc[4][4] = {{}};
  mfma_loop128<Dc, Dc>(Ab + (size_t)r0 * Dc, Bt + (size_t)c0 * Dc, Dc / 64,
                       As, Bs, wave, lane, acc);
  const int wr = wave >> 1, wc = wave & 1;
  const int rl = lane & 15, kq = lane >> 4;
  if (mode == 0) {
    #pragma unroll
    for (int mi = 0; mi < 4; ++mi) {
      #pragma unroll
      for (int r = 0; r < 4; ++r) {
        const int row = r0 + wr * 64 + mi * 16 + kq * 4 + r;
        const float mu = STAT[(size_t)row * 2] * (1.0f / Dc);
        const float va = STAT[(size_t)row * 2 + 1] * (1.0f / Dc) - mu * mu;
        const float inv = rsqrtf(va + GN_EPS);
        #pragma unroll
        for (int nj = 0; nj < 4; ++nj) {
          const int col = c0 + wc * 64 + nj * 16 + rl;
          const size_t idx = (size_t)row * Dc + col;
          const float yv = (Y[idx] - mu) * inv * gw[col] + bw[col];
          Gout[idx] = (__bf16)(fmaxf(acc[mi][nj][r], 0.f) * yv);
        }
      }
    }
  } else {
    #pragma unroll
    for (int mi = 0; mi < 4; ++mi) {
      #pragma unroll
      for (int nj = 0; nj < 4; ++nj) {
        const int col = c0 + wc * 64 + nj * 16 + rl;
        #pragma unroll
        for (int r = 0; r < 4; ++r) {
          const int row = r0 + wr * 64 + mi * 16 + kq * 4 + r;
          Fout[(size_t)row * Dc + col] = acc[mi][nj][r];
        }
      }
    }
  }
}

// ---------------------------------------------------------------------------
extern "C" void kernel_launch(void* const* d_in, const int* in_sizes, int n_in,
                              void* d_out, int out_size, void* d_ws, size_t ws_size,
                              hipStream_t stream) {
  const float* x  = (const float*)d_in[0];
  const float* k  = (const float*)d_in[1];
  const float* v  = (const float*)d_in[2];
  const float* Wh = (const float*)d_in[3];
  const float* wg = (const float*)d_in[4];
  const float* wo = (const float*)d_in[5];
  const float* gg = (const float*)d_in[6];
  const float* gb = (const float*)d_in[7];
  float* ws = (float*)d_ws;
  __bf16* Q   = (__bf16*)(ws + OFF_Q);
  __bf16* Kp  = (__bf16*)(ws + OFF_K);
  __bf16* VB  = (__bf16*)(ws + OFF_VB);
  __bf16* Vt  = (__bf16*)(ws + OFF_VT);
  __bf16* A   = (__bf16*)(ws + OFF_A);
  float*  O   = ws + OFF_O;
  float*  CT  = ws + OFF_CT;
  float*  PN  = ws + OFF_PN;
  __bf16* XB  = (__bf16*)(ws + OFF_XB);
  __bf16* WGT = (__bf16*)(ws + OFF_WGT);
  __bf16* WOT = (__bf16*)(ws + OFF_WOT);
  float*  SUF = ws + OFF_SUF;
  float*  TP  = ws + OFF_T;
  __bf16* WHT = (__bf16*)(ws + OFF_WHT);
  float*  STAT= ws + OFF_STAT;
  __bf16* KB2 = (__bf16*)(ws + OFF_KB2);  // aliases A (dead until k_ssm)
  __bf16* VB2 = (__bf16*)(ws + OFF_VB2);  // aliases A second half
  __bf16* G   = (__bf16*)(ws + OFF_Q);    // reuse Q region (dead after k_ssm)

  // one-time opt-in for dynamic LDS (host-side, graph-capture safe)
  static bool attr_done = false;
  if (!attr_done) {
    (void)hipFuncSetAttribute((const void*)k_mgemm,
                              hipFuncAttributeMaxDynamicSharedMemorySize,
                              MG_LDS);
    (void)hipFuncSetAttribute((const void*)k_projm,
                              hipFuncAttributeMaxDynamicSharedMemorySize,
                              PJ_LDS);
    (void)hipFuncSetAttribute((const void*)k_ssm,
                              hipFuncAttributeMaxDynamicSharedMemorySize,
                              MG_LDS);
    (void)hipFuncSetAttribute((const void*)k_avm,
                              hipFuncAttributeMaxDynamicSharedMemorySize,
                              MG_LDS);
    attr_done = true;
  }

  k_tables<<<Hc * Sc / 256, 256, 0, stream>>>(CT, PN, TP, STAT);
  k_cast83<<<dim3((BSc * Dc) / (256 * 8), 3), 256, 0, stream>>>(
      x, k, v, XB, KB2, VB2);
  k_castT2<<<dim3(Dc / 32, Dc / 32, 2), 256, 0, stream>>>(wg, wo, WGT, WOT);
  k_whT<<<dim3(4, 4, Hc), 256, 0, stream>>>(Wh, WHT);
  k_projm<<<dim3(BSc / 128, Hc, 3), 256, PJ_LDS, stream>>>(XB, KB2, VB2, WHT,
                                                           Q, Kp, VB);
  k_vt<<<dim3(Sc / 32, HDc / 32, Bc * Hc), 256, 0, stream>>>(VB, Vt, TP);
  k_vscan<<<Bc * Hc, 128, 0, stream>>>(TP, SUF);
  k_ssm<<<dim3(8, 9, Hc), 256, MG_LDS, stream>>>(Q, Kp, CT, PN, A);
  k_avm<<<dim3(8, 1, Bc * Hc), 256, MG_LDS, stream>>>(A, Vt, SUF, O, STAT);
  k_mgemm<<<dim3(16, 32), 256, MG_LDS, stream>>>(XB, WGT, O, gg, gb, STAT, G,
                                                 nullptr, 0);
  k_mgemm<<<dim3(16, 32), 256, MG_LDS, stream>>>(G, WOT, nullptr, nullptr,
                                                 nullptr, nullptr, nullptr,
                                                 (float*)d_out, 1);
}